// Round 7
// baseline (705.155 us; speedup 1.0000x reference)
//
#include <hip/hip_runtime.h>
#include <cstdint>
#include <cstddef>

// ---------- bf16 helpers (OCP bf16 = upper 16 bits of f32) ----------
__device__ __forceinline__ float bf2f(unsigned short u) {
  return __uint_as_float(((unsigned)u) << 16);
}
__device__ __forceinline__ unsigned short f2bf(float f) {
  unsigned u = __float_as_uint(f);
  u = (u + 0x7FFFu + ((u >> 16) & 1u)) >> 16;  // RNE
  return (unsigned short)u;
}

typedef __attribute__((ext_vector_type(8))) short bf16x8;
typedef __attribute__((ext_vector_type(4))) float f32x4;

// ---------- edge_index layout probe ----------
__global__ void detect_kernel(const int* __restrict__ ei, int* __restrict__ flag) {
  int any = 0;
  for (int j = threadIdx.x; j < 4096; j += 256) any |= (ei[2 * j + 1] != 0);
  if (any) atomicOr(flag, 1);  // 1 => int32 layout
}

__device__ __forceinline__ int edge_src(const int* ei, int f, int e, int i) {
  return f ? ei[i] : ei[2 * (size_t)i];
}
__device__ __forceinline__ int edge_dst(const int* ei, int f, int e, int i) {
  return f ? ei[(size_t)e + i] : ei[2 * (size_t)e + 2 * (size_t)i];
}

// ---------- per-node degree histogram ----------
__global__ void hist_kernel(const int* __restrict__ ei, const int* __restrict__ flag,
                            int* __restrict__ cnt, int e) {
  int i = blockIdx.x * blockDim.x + threadIdx.x;
  if (i < e) atomicAdd(&cnt[edge_dst(ei, *flag, e, i)], 1);
}

// two-level scan for rp
__global__ void scan_block(const int* __restrict__ cnt, int* __restrict__ rp,
                           int* __restrict__ bsum, int n) {
  __shared__ int lds[256];
  const int t = threadIdx.x;
  const int base = blockIdx.x * 1024 + t * 4;
  int v0 = (base     < n) ? cnt[base]     : 0;
  int v1 = (base + 1 < n) ? cnt[base + 1] : 0;
  int v2 = (base + 2 < n) ? cnt[base + 2] : 0;
  int v3 = (base + 3 < n) ? cnt[base + 3] : 0;
  int s = v0 + v1 + v2 + v3;
  lds[t] = s;
  __syncthreads();
  for (int off = 1; off < 256; off <<= 1) {
    int y = (t >= off) ? lds[t - off] : 0;
    __syncthreads();
    lds[t] += y;
    __syncthreads();
  }
  int excl = lds[t] - s;
  if (base     < n) rp[base]     = excl;
  if (base + 1 < n) rp[base + 1] = excl + v0;
  if (base + 2 < n) rp[base + 2] = excl + v0 + v1;
  if (base + 3 < n) rp[base + 3] = excl + v0 + v1 + v2;
  if (t == 255) bsum[blockIdx.x] = lds[255];
}

__global__ void scan_tops(int* __restrict__ bsum, int* __restrict__ rp, int nb, int n) {
  __shared__ int lds[128];
  const int t = threadIdx.x;
  int v = (t < nb) ? bsum[t] : 0;
  lds[t] = v;
  __syncthreads();
  for (int off = 1; off < 128; off <<= 1) {
    int y = (t >= off) ? lds[t - off] : 0;
    __syncthreads();
    lds[t] += y;
    __syncthreads();
  }
  if (t < nb) bsum[t] = lds[t] - v;
  if (t == 127) rp[n] = lds[127];
}

__global__ void scan_add(int* __restrict__ rp, const int* __restrict__ bsum, int n) {
  const int base = blockIdx.x * 1024 + threadIdx.x * 4;
  const int add = bsum[blockIdx.x];
#pragma unroll
  for (int i = 0; i < 4; ++i)
    if (base + i < n) rp[base + i] += add;
}

// ---------- bucketed CSR fill ----------
#define NB 128

__global__ void bucket_hist(const int* __restrict__ ei, const int* __restrict__ flag,
                            int* __restrict__ bhist, int e, int W) {
  __shared__ int lh[NB];
  const int t = threadIdx.x;
  if (t < NB) lh[t] = 0;
  __syncthreads();
  const int base = blockIdx.x * 4096;
  const int f = *flag;
  for (int j = t; j < 4096; j += 256) {
    int i = base + j;
    if (i < e) atomicAdd(&lh[edge_dst(ei, f, e, i) / W], 1);
  }
  __syncthreads();
  if (t < NB && lh[t]) atomicAdd(&bhist[t], lh[t]);
}

__global__ void bucket_scan(const int* __restrict__ bhist, int* __restrict__ boffs,
                            int* __restrict__ bcur) {
  __shared__ int lds[NB];
  const int t = threadIdx.x;
  int v = bhist[t];
  lds[t] = v;
  __syncthreads();
  for (int off = 1; off < NB; off <<= 1) {
    int y = (t >= off) ? lds[t - off] : 0;
    __syncthreads();
    lds[t] += y;
    __syncthreads();
  }
  int excl = lds[t] - v;
  boffs[t] = excl;
  bcur[t] = excl;
  if (t == NB - 1) boffs[NB] = lds[NB - 1];
}

__global__ void bucket_scatter(const int* __restrict__ ei, const int* __restrict__ flag,
                               int* __restrict__ bcur, int2* __restrict__ ebuf,
                               int e, int W) {
  __shared__ int lh[NB];
  __shared__ int lbase[NB];
  const int t = threadIdx.x;
  if (t < NB) lh[t] = 0;
  __syncthreads();
  const int base = blockIdx.x * 4096;
  const int f = *flag;
  for (int j = t; j < 4096; j += 256) {
    int i = base + j;
    if (i < e) atomicAdd(&lh[edge_dst(ei, f, e, i) / W], 1);
  }
  __syncthreads();
  if (t < NB) {
    lbase[t] = lh[t] ? atomicAdd(&bcur[t], lh[t]) : 0;
    lh[t] = 0;
  }
  __syncthreads();
  for (int j = t; j < 4096; j += 256) {
    int i = base + j;
    if (i < e) {
      int d = edge_dst(ei, f, e, i);
      int s = edge_src(ei, f, e, i);
      int b = d / W;
      int off = atomicAdd(&lh[b], 1);
      ebuf[lbase[b] + off] = make_int2(s, d);
    }
  }
}

__global__ void bucket_fill(const int2* __restrict__ ebuf, const int* __restrict__ boffs,
                            const int* __restrict__ rp, int* __restrict__ col,
                            int n, int W) {
  __shared__ int cur[1024];
  const int b = blockIdx.x;
  const int lo = b * W;
  const int nn = min(W, n - lo);
  if (nn <= 0) return;
  for (int i = threadIdx.x; i < nn; i += 256) cur[i] = rp[lo + i];
  __syncthreads();
  const int beg = boffs[b], end = boffs[b + 1];
  for (int p = beg + threadIdx.x; p < end; p += 256) {
    int2 sd = ebuf[p];
    int pos = atomicAdd(&cur[sd.y - lo], 1);
    col[pos] = sd.x;
  }
}

// ---------- pack W[128][128] f32 into MFMA B-fragment order (bf16) ----------
__global__ void pack_mfma_b(const float* __restrict__ Wf, unsigned short* __restrict__ Wpk) {
  int i = blockIdx.x * 256 + threadIdx.x;  // 2048
  if (i >= 2048) return;
  int lane = i & 63, nt = (i >> 6) & 7, ks = i >> 9;
  int nn = lane & 15, q = lane >> 4;
  int k0 = ks * 32 + q * 8, col = nt * 16 + nn;
  unsigned short o[8];
#pragma unroll
  for (int j = 0; j < 8; ++j) o[j] = f2bf(Wf[(size_t)(k0 + j) * 128 + col]);
  uint4 u;
  u.x = (unsigned)o[0] | ((unsigned)o[1] << 16);
  u.y = (unsigned)o[2] | ((unsigned)o[3] << 16);
  u.z = (unsigned)o[4] | ((unsigned)o[5] << 16);
  u.w = (unsigned)o[6] | ((unsigned)o[7] << 16);
  *(uint4*)(Wpk + (size_t)i * 8) = u;
}

// hi/lo split pack for the self-linear weight: Hi = bf16(W), Lo = bf16(W - Hi)
__global__ void pack_mfma_b_hilo(const float* __restrict__ Wf,
                                 unsigned short* __restrict__ Hi,
                                 unsigned short* __restrict__ Lo) {
  int i = blockIdx.x * 256 + threadIdx.x;  // 2048
  if (i >= 2048) return;
  int lane = i & 63, nt = (i >> 6) & 7, ks = i >> 9;
  int nn = lane & 15, q = lane >> 4;
  int k0 = ks * 32 + q * 8, col = nt * 16 + nn;
  unsigned short oh[8], ol[8];
#pragma unroll
  for (int j = 0; j < 8; ++j) {
    float v = Wf[(size_t)(k0 + j) * 128 + col];
    unsigned short h = f2bf(v);
    oh[j] = h;
    ol[j] = f2bf(v - bf2f(h));
  }
  uint4 uh, ul;
  uh.x = (unsigned)oh[0] | ((unsigned)oh[1] << 16);
  uh.y = (unsigned)oh[2] | ((unsigned)oh[3] << 16);
  uh.z = (unsigned)oh[4] | ((unsigned)oh[5] << 16);
  uh.w = (unsigned)oh[6] | ((unsigned)oh[7] << 16);
  ul.x = (unsigned)ol[0] | ((unsigned)ol[1] << 16);
  ul.y = (unsigned)ol[2] | ((unsigned)ol[3] << 16);
  ul.z = (unsigned)ol[4] | ((unsigned)ol[5] << 16);
  ul.w = (unsigned)ol[6] | ((unsigned)ol[7] << 16);
  *(uint4*)(Hi + (size_t)i * 8) = uh;
  *(uint4*)(Lo + (size_t)i * 8) = ul;
}

// heads: merged [Wmu | Wlv], each [128][64] f32
__global__ void pack_mfma_head(const float* __restrict__ Wmu, const float* __restrict__ Wlv,
                               unsigned short* __restrict__ Wpk) {
  int i = blockIdx.x * 256 + threadIdx.x;  // 2048
  if (i >= 2048) return;
  int lane = i & 63, nt = (i >> 6) & 7, ks = i >> 9;
  int nn = lane & 15, q = lane >> 4;
  int k0 = ks * 32 + q * 8, col = nt * 16 + nn;
  unsigned short o[8];
#pragma unroll
  for (int j = 0; j < 8; ++j) {
    float v = (col < 64) ? Wmu[(size_t)(k0 + j) * 64 + col]
                         : Wlv[(size_t)(k0 + j) * 64 + (col - 64)];
    o[j] = f2bf(v);
  }
  uint4 u;
  u.x = (unsigned)o[0] | ((unsigned)o[1] << 16);
  u.y = (unsigned)o[2] | ((unsigned)o[3] << 16);
  u.z = (unsigned)o[4] | ((unsigned)o[5] << 16);
  u.w = (unsigned)o[6] | ((unsigned)o[7] << 16);
  *(uint4*)(Wpk + (size_t)i * 8) = u;
}

// ---------- fused layer GEMM (matrix pipe; weight tables staged in 96KB LDS) ----------
// Round-6 post-mortem: 96 per-wave L2 fragment loads were latency-serialized
// (MfmaUtil 5.7%, 84us). The three 32KB tables are block-invariant -> stage into
// LDS once; fragment reads become ds_read_b128 with fine-grained lgkmcnt.
__launch_bounds__(256)
__global__ void gemm_fused(const float* __restrict__ X, const unsigned short* __restrict__ Wpk,
                           const unsigned short* __restrict__ Sph, const unsigned short* __restrict__ Spl,
                           const float* __restrict__ a0s, const float* __restrict__ a0d,
                           const float* __restrict__ slb,
                           unsigned short* __restrict__ hg, float* __restrict__ hself,
                           float* __restrict__ als, float* __restrict__ ald, int n) {
  extern __shared__ unsigned short ldsW[];  // 3 * 16384 shorts = 96 KB
  const int t = threadIdx.x;
  const int wave = t >> 6;
  const int lane = t & 63;
  const int nidx = lane & 15, q = lane >> 4;
  const int r0 = blockIdx.x * 64 + wave * 16;
  const int arow = r0 + nidx;

  // issue X loads first (HBM latency hides under staging)
  float4 xr[8];
  if (arow < n) {
    const float* xp = X + (size_t)arow * 128 + q * 8;
#pragma unroll
    for (int ks = 0; ks < 4; ++ks) {
      xr[2 * ks]     = *(const float4*)(xp + ks * 32);
      xr[2 * ks + 1] = *(const float4*)(xp + ks * 32 + 4);
    }
  } else {
#pragma unroll
    for (int j = 0; j < 8; ++j) xr[j] = make_float4(0.f, 0.f, 0.f, 0.f);
  }

  // stage the three 32KB tables (2048 uint4 each)
  {
    const uint4* s0 = (const uint4*)Wpk;
    const uint4* s1 = (const uint4*)Sph;
    const uint4* s2 = (const uint4*)Spl;
    uint4* d = (uint4*)ldsW;
#pragma unroll
    for (int i = 0; i < 8; ++i) {
      const int idx = t + i * 256;
      d[idx]        = s0[idx];
      d[idx + 2048] = s1[idx];
      d[idx + 4096] = s2[idx];
    }
  }

  // convert X to bf16 hi/lo fragments
  union U { unsigned short u[8]; bf16x8 v; };
  U afh[4], afl[4];
#pragma unroll
  for (int ks = 0; ks < 4; ++ks) {
    float xv[8] = {xr[2 * ks].x, xr[2 * ks].y, xr[2 * ks].z, xr[2 * ks].w,
                   xr[2 * ks + 1].x, xr[2 * ks + 1].y, xr[2 * ks + 1].z, xr[2 * ks + 1].w};
#pragma unroll
    for (int j = 0; j < 8; ++j) {
      unsigned short h = f2bf(xv[j]);
      afh[ks].u[j] = h;
      afl[ks].u[j] = f2bf(xv[j] - bf2f(h));
    }
  }

  __syncthreads();

  f32x4 acc[8], accS[8];
#pragma unroll
  for (int nt = 0; nt < 8; ++nt) {
    acc[nt]  = (f32x4){0.f, 0.f, 0.f, 0.f};
    accS[nt] = (f32x4){0.f, 0.f, 0.f, 0.f};
  }

#pragma unroll
  for (int ks = 0; ks < 4; ++ks) {
    const int base = (ks * 512 + lane) * 8;
    const unsigned short* bp = ldsW + base;
    const unsigned short* ph = ldsW + 16384 + base;
    const unsigned short* pl = ldsW + 32768 + base;
#pragma unroll
    for (int nt = 0; nt < 8; ++nt) {
      bf16x8 bW = *(const bf16x8*)(bp + nt * 512);
      acc[nt] = __builtin_amdgcn_mfma_f32_16x16x32_bf16(afh[ks].v, bW, acc[nt], 0, 0, 0);
      bf16x8 bH = *(const bf16x8*)(ph + nt * 512);
      bf16x8 bL = *(const bf16x8*)(pl + nt * 512);
      accS[nt] = __builtin_amdgcn_mfma_f32_16x16x32_bf16(afh[ks].v, bH, accS[nt], 0, 0, 0);
      accS[nt] = __builtin_amdgcn_mfma_f32_16x16x32_bf16(afl[ks].v, bH, accS[nt], 0, 0, 0);
      accS[nt] = __builtin_amdgcn_mfma_f32_16x16x32_bf16(afh[ks].v, bL, accS[nt], 0, 0, 0);
    }
  }

  // epilogue 1: hg (bf16) + rounded values for logits
  float dv[8][4];
#pragma unroll
  for (int nt = 0; nt < 8; ++nt) {
#pragma unroll
    for (int r = 0; r < 4; ++r) {
      unsigned short rb = f2bf(acc[nt][r]);
      dv[nt][r] = bf2f(rb);
      int row = r0 + q * 4 + r;
      if (row < n) hg[(size_t)row * 128 + nt * 16 + nidx] = rb;
    }
  }

  // epilogue 2: hself (f32) + bias
#pragma unroll
  for (int nt = 0; nt < 8; ++nt) {
    const float sb = slb[nt * 16 + nidx];
#pragma unroll
    for (int r = 0; r < 4; ++r) {
      int row = r0 + q * 4 + r;
      if (row < n) hself[(size_t)row * 128 + nt * 16 + nidx] = accS[nt][r] + sb;
    }
  }

  // epilogue 3: logits
  float ps[4] = {0, 0, 0, 0}, pd[4] = {0, 0, 0, 0};
#pragma unroll
  for (int nt = 0; nt < 8; ++nt) {
    float as_ = a0s[nt * 16 + nidx];
    float ad_ = a0d[nt * 16 + nidx];
#pragma unroll
    for (int r = 0; r < 4; ++r) {
      ps[r] = fmaf(dv[nt][r], as_, ps[r]);
      pd[r] = fmaf(dv[nt][r], ad_, pd[r]);
    }
  }
#pragma unroll
  for (int r = 0; r < 4; ++r) {
#pragma unroll
    for (int o = 8; o > 0; o >>= 1) {
      ps[r] += __shfl_xor(ps[r], o, 64);
      pd[r] += __shfl_xor(pd[r], o, 64);
    }
    int row = r0 + q * 4 + r;
    if (nidx == 0 && row < n) { als[row] = ps[r]; ald[row] = pd[r]; }
  }
}

// ---------- head MFMA GEMM: single 32KB table staged in LDS ----------
__launch_bounds__(256)
__global__ void gemm_mfma_head(const float* __restrict__ X, const unsigned short* __restrict__ Wpk,
                               const float* __restrict__ a0s, const float* __restrict__ a0d,
                               const float* __restrict__ a1s, const float* __restrict__ a1d,
                               unsigned short* __restrict__ hg,
                               float* __restrict__ als, float* __restrict__ ald, int n) {
  extern __shared__ unsigned short ldsW[];  // 16384 shorts = 32 KB
  const int t = threadIdx.x;
  const int wave = t >> 6;
  const int lane = t & 63;
  const int nidx = lane & 15, q = lane >> 4;
  const int r0 = blockIdx.x * 64 + wave * 16;
  const int arow = r0 + nidx;

  float4 xr[8];
  if (arow < n) {
    const float* xp = X + (size_t)arow * 128 + q * 8;
#pragma unroll
    for (int ks = 0; ks < 4; ++ks) {
      xr[2 * ks]     = *(const float4*)(xp + ks * 32);
      xr[2 * ks + 1] = *(const float4*)(xp + ks * 32 + 4);
    }
  } else {
#pragma unroll
    for (int j = 0; j < 8; ++j) xr[j] = make_float4(0.f, 0.f, 0.f, 0.f);
  }

  {
    const uint4* s0 = (const uint4*)Wpk;
    uint4* d = (uint4*)ldsW;
#pragma unroll
    for (int i = 0; i < 8; ++i) {
      const int idx = t + i * 256;
      d[idx] = s0[idx];
    }
  }

  union U { unsigned short u[8]; bf16x8 v; };
  U af[4];
#pragma unroll
  for (int ks = 0; ks < 4; ++ks) {
    float xv[8] = {xr[2 * ks].x, xr[2 * ks].y, xr[2 * ks].z, xr[2 * ks].w,
                   xr[2 * ks + 1].x, xr[2 * ks + 1].y, xr[2 * ks + 1].z, xr[2 * ks + 1].w};
#pragma unroll
    for (int j = 0; j < 8; ++j) af[ks].u[j] = f2bf(xv[j]);
  }

  __syncthreads();

  f32x4 acc[8];
#pragma unroll
  for (int nt = 0; nt < 8; ++nt) acc[nt] = (f32x4){0.f, 0.f, 0.f, 0.f};

#pragma unroll
  for (int ks = 0; ks < 4; ++ks) {
    const unsigned short* bp = ldsW + (ks * 512 + lane) * 8;
#pragma unroll
    for (int nt = 0; nt < 8; ++nt) {
      bf16x8 bfm = *(const bf16x8*)(bp + nt * 512);
      acc[nt] = __builtin_amdgcn_mfma_f32_16x16x32_bf16(af[ks].v, bfm, acc[nt], 0, 0, 0);
    }
  }

  float dv[8][4];
#pragma unroll
  for (int nt = 0; nt < 8; ++nt) {
#pragma unroll
    for (int r = 0; r < 4; ++r) {
      unsigned short rb = f2bf(acc[nt][r]);
      dv[nt][r] = bf2f(rb);
      int row = r0 + q * 4 + r;
      if (row < n) hg[(size_t)row * 128 + nt * 16 + nidx] = rb;
    }
  }

  float pms[4] = {0, 0, 0, 0}, pmd[4] = {0, 0, 0, 0};
  float pls[4] = {0, 0, 0, 0}, pld[4] = {0, 0, 0, 0};
#pragma unroll
  for (int nt = 0; nt < 4; ++nt) {
    float as_ = a0s[nt * 16 + nidx];
    float ad_ = a0d[nt * 16 + nidx];
#pragma unroll
    for (int r = 0; r < 4; ++r) {
      pms[r] = fmaf(dv[nt][r], as_, pms[r]);
      pmd[r] = fmaf(dv[nt][r], ad_, pmd[r]);
    }
  }
#pragma unroll
  for (int nt = 4; nt < 8; ++nt) {
    float as_ = a1s[(nt - 4) * 16 + nidx];
    float ad_ = a1d[(nt - 4) * 16 + nidx];
#pragma unroll
    for (int r = 0; r < 4; ++r) {
      pls[r] = fmaf(dv[nt][r], as_, pls[r]);
      pld[r] = fmaf(dv[nt][r], ad_, pld[r]);
    }
  }
#pragma unroll
  for (int r = 0; r < 4; ++r) {
#pragma unroll
    for (int o = 8; o > 0; o >>= 1) {
      pms[r] += __shfl_xor(pms[r], o, 64);
      pmd[r] += __shfl_xor(pmd[r], o, 64);
      pls[r] += __shfl_xor(pls[r], o, 64);
      pld[r] += __shfl_xor(pld[r], o, 64);
    }
    int row = r0 + q * 4 + r;
    if (nidx == 0 && row < n) {
      ((float2*)als)[row] = make_float2(pms[r], pls[r]);
      ((float2*)ald)[row] = make_float2(pmd[r], pld[r]);
    }
  }
}

// ---------- layer aggregation: 16 lanes/node; chunk-pipelined; ILP-8 gathers ----------
__launch_bounds__(256)
__global__ void gat_agg3(const unsigned short* __restrict__ hg,
                         const float* __restrict__ als, const float* __restrict__ aldv,
                         const int* __restrict__ rp, const int* __restrict__ col,
                         const float* __restrict__ biasf, float* __restrict__ outv,
                         const float* base, int n, int self_loop, int act) {
  const int node = blockIdx.x * 16 + (threadIdx.x >> 4);
  if (node >= n) return;
  const int g = threadIdx.x & 15;
  const int beg = rp[node];
  const int deg = rp[node + 1] - beg;
  const int total = deg + self_loop;
  const float ad = aldv[node];

  float den = 0.f;
  float acc[8];
#pragma unroll
  for (int k = 0; k < 8; ++k) acc[k] = 0.f;

  const unsigned short* hgl = hg + g * 8;

  auto chunkw = [&](int cb, int& s) -> float {
    const int idx = cb + g;
    s = node;
    if (idx < deg) s = col[beg + idx];
    if (idx >= total) return 0.f;
    float t = als[s] + ad;
    return __expf((t > 0.f) ? t : 0.2f * t);  // LeakyReLU(0.2) then exp
  };

  int sA; float wA = chunkw(0, sA);

  for (int cb = 0; cb < total; cb += 16) {
    int sB = node; float wB = 0.f;
    if (cb + 16 < total) wB = chunkw(cb + 16, sB);

    const int cnt = (total - cb < 16) ? (total - cb) : 16;
    int j = 0;
    for (; j + 8 <= cnt; j += 8) {
      float w[8]; int ss[8]; uint4 rr[8];
#pragma unroll
      for (int u = 0; u < 8; ++u) { w[u] = __shfl(wA, j + u, 16); ss[u] = __shfl(sA, j + u, 16); }
#pragma unroll
      for (int u = 0; u < 8; ++u) rr[u] = *(const uint4*)(hgl + (size_t)ss[u] * 128);
#pragma unroll
      for (int u = 0; u < 8; ++u) {
        den += w[u];
        acc[0] = fmaf(w[u], __uint_as_float(rr[u].x << 16),        acc[0]);
        acc[1] = fmaf(w[u], __uint_as_float(rr[u].x & 0xFFFF0000u), acc[1]);
        acc[2] = fmaf(w[u], __uint_as_float(rr[u].y << 16),        acc[2]);
        acc[3] = fmaf(w[u], __uint_as_float(rr[u].y & 0xFFFF0000u), acc[3]);
        acc[4] = fmaf(w[u], __uint_as_float(rr[u].z << 16),        acc[4]);
        acc[5] = fmaf(w[u], __uint_as_float(rr[u].z & 0xFFFF0000u), acc[5]);
        acc[6] = fmaf(w[u], __uint_as_float(rr[u].w << 16),        acc[6]);
        acc[7] = fmaf(w[u], __uint_as_float(rr[u].w & 0xFFFF0000u), acc[7]);
      }
    }
    for (; j + 4 <= cnt; j += 4) {
      float w[4]; int ss[4]; uint4 rr[4];
#pragma unroll
      for (int u = 0; u < 4; ++u) { w[u] = __shfl(wA, j + u, 16); ss[u] = __shfl(sA, j + u, 16); }
#pragma unroll
      for (int u = 0; u < 4; ++u) rr[u] = *(const uint4*)(hgl + (size_t)ss[u] * 128);
#pragma unroll
      for (int u = 0; u < 4; ++u) {
        den += w[u];
        acc[0] = fmaf(w[u], __uint_as_float(rr[u].x << 16),        acc[0]);
        acc[1] = fmaf(w[u], __uint_as_float(rr[u].x & 0xFFFF0000u), acc[1]);
        acc[2] = fmaf(w[u], __uint_as_float(rr[u].y << 16),        acc[2]);
        acc[3] = fmaf(w[u], __uint_as_float(rr[u].y & 0xFFFF0000u), acc[3]);
        acc[4] = fmaf(w[u], __uint_as_float(rr[u].z << 16),        acc[4]);
        acc[5] = fmaf(w[u], __uint_as_float(rr[u].z & 0xFFFF0000u), acc[5]);
        acc[6] = fmaf(w[u], __uint_as_float(rr[u].w << 16),        acc[6]);
        acc[7] = fmaf(w[u], __uint_as_float(rr[u].w & 0xFFFF0000u), acc[7]);
      }
    }
    for (; j < cnt; ++j) {
      float wj = __shfl(wA, j, 16);
      int sj = __shfl(sA, j, 16);
      uint4 raw = *(const uint4*)(hgl + (size_t)sj * 128);
      den += wj;
      acc[0] = fmaf(wj, __uint_as_float(raw.x << 16),        acc[0]);
      acc[1] = fmaf(wj, __uint_as_float(raw.x & 0xFFFF0000u), acc[1]);
      acc[2] = fmaf(wj, __uint_as_float(raw.y << 16),        acc[2]);
      acc[3] = fmaf(wj, __uint_as_float(raw.y & 0xFFFF0000u), acc[3]);
      acc[4] = fmaf(wj, __uint_as_float(raw.z << 16),        acc[4]);
      acc[5] = fmaf(wj, __uint_as_float(raw.z & 0xFFFF0000u), acc[5]);
      acc[6] = fmaf(wj, __uint_as_float(raw.w << 16),        acc[6]);
      acc[7] = fmaf(wj, __uint_as_float(raw.w & 0xFFFF0000u), acc[7]);
    }
    sA = sB; wA = wB;
  }

  const float inv = 1.f / (den + 1e-16f);
  const size_t o = (size_t)node * 128 + g * 8;
  float4 bv0 = *(const float4*)(biasf + g * 8);
  float4 bv1 = *(const float4*)(biasf + g * 8 + 4);
  float r[8];
  r[0] = acc[0] * inv + bv0.x; r[1] = acc[1] * inv + bv0.y;
  r[2] = acc[2] * inv + bv0.z; r[3] = acc[3] * inv + bv0.w;
  r[4] = acc[4] * inv + bv1.x; r[5] = acc[5] * inv + bv1.y;
  r[6] = acc[6] * inv + bv1.z; r[7] = acc[7] * inv + bv1.w;
  if (base) {
    float4 s0 = *(const float4*)(base + o);
    float4 s1 = *(const float4*)(base + o + 4);
    r[0] += s0.x; r[1] += s0.y; r[2] += s0.z; r[3] += s0.w;
    r[4] += s1.x; r[5] += s1.y; r[6] += s1.z; r[7] += s1.w;
  }
  if (act) {
#pragma unroll
    for (int k = 0; k < 8; ++k) r[k] = (r[k] > 0.f) ? r[k] : 0.01f * r[k];
  }
  *(float4*)(outv + o)     = make_float4(r[0], r[1], r[2], r[3]);
  *(float4*)(outv + o + 4) = make_float4(r[4], r[5], r[6], r[7]);
}

// ---------- dual-head aggregation: mu + logvar in ONE gather pass; pipelined; ILP-8 ----------
__launch_bounds__(256)
__global__ void gat_agg_dual(const unsigned short* __restrict__ hg,
                             const float2* __restrict__ alsH, const float2* __restrict__ aldH,
                             const int* __restrict__ rp, const int* __restrict__ col,
                             const float* __restrict__ bmu, const float* __restrict__ blv,
                             float* __restrict__ outF, int n) {
  const int node = blockIdx.x * 16 + (threadIdx.x >> 4);
  if (node >= n) return;
  const int g = threadIdx.x & 15;
  const bool isMu = g < 8;
  const int beg = rp[node];
  const int deg = rp[node + 1] - beg;
  const int total = deg + 1;  // heads always have self loop
  const float2 ad = aldH[node];

  float den = 0.f;
  float acc[8];
#pragma unroll
  for (int k = 0; k < 8; ++k) acc[k] = 0.f;

  const unsigned short* hgl = hg + g * 8;

  auto chunkw = [&](int cb, int& s, float& eM, float& eL) {
    const int idx = cb + g;
    s = node;
    if (idx < deg) s = col[beg + idx];
    if (idx >= total) { eM = 0.f; eL = 0.f; return; }
    float2 a_ = alsH[s];
    float vm = a_.x + ad.x, vl = a_.y + ad.y;
    eM = __expf((vm > 0.f) ? vm : 0.2f * vm);
    eL = __expf((vl > 0.f) ? vl : 0.2f * vl);
  };

  int sA; float eMA, eLA;
  chunkw(0, sA, eMA, eLA);

  for (int cb = 0; cb < total; cb += 16) {
    int sB = node; float eMB = 0.f, eLB = 0.f;
    if (cb + 16 < total) chunkw(cb + 16, sB, eMB, eLB);

    const int cnt = (total - cb < 16) ? (total - cb) : 16;
    int j = 0;
    for (; j + 8 <= cnt; j += 8) {
      float w[8]; int ss[8]; uint4 rr[8];
#pragma unroll
      for (int u = 0; u < 8; ++u) {
        float wm = __shfl(eMA, j + u, 16), wl = __shfl(eLA, j + u, 16);
        w[u] = isMu ? wm : wl;
        ss[u] = __shfl(sA, j + u, 16);
      }
#pragma unroll
      for (int u = 0; u < 8; ++u) rr[u] = *(const uint4*)(hgl + (size_t)ss[u] * 128);
#pragma unroll
      for (int u = 0; u < 8; ++u) {
        den += w[u];
        acc[0] = fmaf(w[u], __uint_as_float(rr[u].x << 16),        acc[0]);
        acc[1] = fmaf(w[u], __uint_as_float(rr[u].x & 0xFFFF0000u), acc[1]);
        acc[2] = fmaf(w[u], __uint_as_float(rr[u].y << 16),        acc[2]);
        acc[3] = fmaf(w[u], __uint_as_float(rr[u].y & 0xFFFF0000u), acc[3]);
        acc[4] = fmaf(w[u], __uint_as_float(rr[u].z << 16),        acc[4]);
        acc[5] = fmaf(w[u], __uint_as_float(rr[u].z & 0xFFFF0000u), acc[5]);
        acc[6] = fmaf(w[u], __uint_as_float(rr[u].w << 16),        acc[6]);
        acc[7] = fmaf(w[u], __uint_as_float(rr[u].w & 0xFFFF0000u), acc[7]);
      }
    }
    for (; j + 4 <= cnt; j += 4) {
      float w[4]; int ss[4]; uint4 rr[4];
#pragma unroll
      for (int u = 0; u < 4; ++u) {
        float wm = __shfl(eMA, j + u, 16), wl = __shfl(eLA, j + u, 16);
        w[u] = isMu ? wm : wl;
        ss[u] = __shfl(sA, j + u, 16);
      }
#pragma unroll
      for (int u = 0; u < 4; ++u) rr[u] = *(const uint4*)(hgl + (size_t)ss[u] * 128);
#pragma unroll
      for (int u = 0; u < 4; ++u) {
        den += w[u];
        acc[0] = fmaf(w[u], __uint_as_float(rr[u].x << 16),        acc[0]);
        acc[1] = fmaf(w[u], __uint_as_float(rr[u].x & 0xFFFF0000u), acc[1]);
        acc[2] = fmaf(w[u], __uint_as_float(rr[u].y << 16),        acc[2]);
        acc[3] = fmaf(w[u], __uint_as_float(rr[u].y & 0xFFFF0000u), acc[3]);
        acc[4] = fmaf(w[u], __uint_as_float(rr[u].z << 16),        acc[4]);
        acc[5] = fmaf(w[u], __uint_as_float(rr[u].z & 0xFFFF0000u), acc[5]);
        acc[6] = fmaf(w[u], __uint_as_float(rr[u].w << 16),        acc[6]);
        acc[7] = fmaf(w[u], __uint_as_float(rr[u].w & 0xFFFF0000u), acc[7]);
      }
    }
    for (; j < cnt; ++j) {
      float wm = __shfl(eMA, j, 16), wl = __shfl(eLA, j, 16);
      float wj = isMu ? wm : wl;
      int sj = __shfl(sA, j, 16);
      uint4 raw = *(const uint4*)(hgl + (size_t)sj * 128);
      den += wj;
      acc[0] = fmaf(wj, __uint_as_float(raw.x << 16),        acc[0]);
      acc[1] = fmaf(wj, __uint_as_float(raw.x & 0xFFFF0000u), acc[1]);
      acc[2] = fmaf(wj, __uint_as_float(raw.y << 16),        acc[2]);
      acc[3] = fmaf(wj, __uint_as_float(raw.y & 0xFFFF0000u), acc[3]);
      acc[4] = fmaf(wj, __uint_as_float(raw.z << 16),        acc[4]);
      acc[5] = fmaf(wj, __uint_as_float(raw.z & 0xFFFF0000u), acc[5]);
      acc[6] = fmaf(wj, __uint_as_float(raw.w << 16),        acc[6]);
      acc[7] = fmaf(wj, __uint_as_float(raw.w & 0xFFFF0000u), acc[7]);
    }
    sA = sB; eMA = eMB; eLA = eLB;
  }

  const float inv = 1.f / (den + 1e-16f);
  const int c = (g & 7) * 8;
  const float* bb = isMu ? bmu : blv;
  float4 bv0 = *(const float4*)(bb + c);
  float4 bv1 = *(const float4*)(bb + c + 4);
  float* op = outF + (isMu ? (size_t)0 : (size_t)n * 64) + (size_t)node * 64 + c;
  *(float4*)op = make_float4(acc[0] * inv + bv0.x, acc[1] * inv + bv0.y,
                             acc[2] * inv + bv0.z, acc[3] * inv + bv0.w);
  *(float4*)(op + 4) = make_float4(acc[4] * inv + bv1.x, acc[5] * inv + bv1.y,
                                   acc[6] * inv + bv1.z, acc[7] * inv + bv1.w);
}

extern "C" void kernel_launch(void* const* d_in, const int* in_sizes, int n_in,
                              void* d_out, int out_size, void* d_ws, size_t ws_size,
                              hipStream_t stream) {
  const int N = in_sizes[0] / 128;   // 100000
  const int E = in_sizes[1] / 2;     // 1600000
  const int W = (N + NB - 1) / NB;   // nodes per bucket (<=1024)

  const float* x    = (const float*)d_in[0];
  const int*   ei   = (const int*)d_in[1];
  const float* W0   = (const float*)d_in[2];
  const float* as0  = (const float*)d_in[3];
  const float* ad0  = (const float*)d_in[4];
  const float* b0   = (const float*)d_in[5];
  const float* slW0 = (const float*)d_in[6];
  const float* slb0 = (const float*)d_in[7];
  const float* W1   = (const float*)d_in[8];
  const float* as1  = (const float*)d_in[9];
  const float* ad1  = (const float*)d_in[10];
  const float* b1   = (const float*)d_in[11];
  const float* slW1 = (const float*)d_in[12];
  const float* slb1 = (const float*)d_in[13];
  const float* Wmu  = (const float*)d_in[14];
  const float* asmu = (const float*)d_in[15];
  const float* admu = (const float*)d_in[16];
  const float* bmu  = (const float*)d_in[17];
  const float* Wlv  = (const float*)d_in[18];
  const float* aslv = (const float*)d_in[19];
  const float* adlv = (const float*)d_in[20];
  const float* blv  = (const float*)d_in[21];

  float*          outF = (float*)d_out;
  unsigned short* hgB  = (unsigned short*)d_out;  // layers' hg lives in d_out (dead before heads write)

  char* w = (char*)d_ws;
  auto carve = [&](size_t bytes) -> char* {
    char* p = w;
    w += (bytes + 255) & ~(size_t)255;
    return p;
  };
  float*          h0    = (float*)carve((size_t)N * 128 * 4);           // 51.2 MB
  unsigned short* hgHd  = (unsigned short*)carve((size_t)N * 128 * 2);  // 25.6 MB
  float*          als   = (float*)carve((size_t)N * 4);
  float*          ald   = (float*)carve((size_t)N * 4);
  float2*         alsH  = (float2*)carve((size_t)N * 8);
  float2*         aldH  = (float2*)carve((size_t)N * 8);
  int*            cnt   = (int*)carve((size_t)N * 4);
  int*            rp    = (int*)carve((size_t)(N + 1) * 4);
  int*            col   = (int*)carve((size_t)E * 4);
  int*            bsum  = (int*)carve(512);
  int*            bhist = (int*)carve(NB * 4);
  int*            boffs = (int*)carve((NB + 1) * 4);
  int*            bcur  = (int*)carve(NB * 4);
  int*            flag  = (int*)carve(4);
  unsigned short* Wpk0  = (unsigned short*)carve(2048 * 8 * 2);
  unsigned short* Wpk1  = (unsigned short*)carve(2048 * 8 * 2);
  unsigned short* Wpkh  = (unsigned short*)carve(2048 * 8 * 2);
  unsigned short* Spk0h = (unsigned short*)carve(2048 * 8 * 2);
  unsigned short* Spk0l = (unsigned short*)carve(2048 * 8 * 2);
  unsigned short* Spk1h = (unsigned short*)carve(2048 * 8 * 2);
  unsigned short* Spk1l = (unsigned short*)carve(2048 * 8 * 2);
  int2*           ebuf  = (int2*)h0;  // alias: h0 dead during CSR build

  const int gE  = (E + 255) / 256;
  const int gB4 = (E + 4095) / 4096;
  const int gG  = (N + 63) / 64;
  const int gW  = (N + 15) / 16;     // 16 nodes per 256-thread block
  const int nb  = (N + 1023) / 1024;

  // allow >64KB dynamic LDS (gfx950 supports up to 160KB/workgroup)
  static bool attr_done = false;
  if (!attr_done) {
    hipFuncSetAttribute((const void*)gemm_fused,
                        hipFuncAttributeMaxDynamicSharedMemorySize, 96 * 1024);
    hipFuncSetAttribute((const void*)gemm_mfma_head,
                        hipFuncAttributeMaxDynamicSharedMemorySize, 32 * 1024);
    attr_done = true;
  }

  // --- probe + bucketed CSR build ---
  hipMemsetAsync(flag, 0, 4, stream);
  hipMemsetAsync(cnt, 0, (size_t)N * 4, stream);
  hipMemsetAsync(bhist, 0, NB * 4, stream);
  detect_kernel<<<1, 256, 0, stream>>>(ei, flag);
  hist_kernel<<<gE, 256, 0, stream>>>(ei, flag, cnt, E);
  bucket_hist<<<gB4, 256, 0, stream>>>(ei, flag, bhist, E, W);
  scan_block<<<nb, 256, 0, stream>>>(cnt, rp, bsum, N);
  scan_tops<<<1, 128, 0, stream>>>(bsum, rp, nb, N);
  scan_add<<<nb, 256, 0, stream>>>(rp, bsum, N);
  bucket_scan<<<1, NB, 0, stream>>>(bhist, boffs, bcur);
  bucket_scatter<<<gB4, 256, 0, stream>>>(ei, flag, bcur, ebuf, E, W);
  bucket_fill<<<NB, 256, 0, stream>>>(ebuf, boffs, rp, col, N, W);

  // --- pack weights into MFMA B-fragment order (bf16; self weights hi/lo split) ---
  pack_mfma_b<<<8, 256, 0, stream>>>(W0, Wpk0);
  pack_mfma_b<<<8, 256, 0, stream>>>(W1, Wpk1);
  pack_mfma_b_hilo<<<8, 256, 0, stream>>>(slW0, Spk0h, Spk0l);
  pack_mfma_b_hilo<<<8, 256, 0, stream>>>(slW1, Spk1h, Spk1l);
  pack_mfma_head<<<8, 256, 0, stream>>>(Wmu, Wlv, Wpkh);

  // --- layer 0: one fused MFMA GEMM (hg + logits + self-linear), then fused agg ---
  gemm_fused<<<gG, 256, 96 * 1024, stream>>>(x, Wpk0, Spk0h, Spk0l, as0, ad0, slb0,
                                             hgB, h0, als, ald, N);
  gat_agg3<<<gW, 256, 0, stream>>>(hgB, als, ald, rp, col, b0, h0, h0, N, 0, 1);

  // --- layer 1 (self loops); reads h0 in its own row band, writes same band ---
  gemm_fused<<<gG, 256, 96 * 1024, stream>>>(h0, Wpk1, Spk1h, Spk1l, as1, ad1, slb1,
                                             hgB, h0, als, ald, N);
  gat_agg3<<<gW, 256, 0, stream>>>(hgB, als, ald, rp, col, b1, h0, h0, N, 1, 1);

  // --- heads: one merged MFMA GEMM (+both logit pairs), one dual gather pass ---
  gemm_mfma_head<<<gG, 256, 32 * 1024, stream>>>(h0, Wpkh, asmu, admu, aslv, adlv,
                                                 hgHd, (float*)alsH, (float*)aldH, N);
  gat_agg_dual<<<gW, 256, 0, stream>>>(hgHd, alsH, aldH, rp, col, bmu, blv, outF, N);
}

// Round 8
// 658.119 us; speedup vs baseline: 1.0715x; 1.0715x over previous
//
#include <hip/hip_runtime.h>
#include <cstdint>
#include <cstddef>

// ---------- bf16 helpers (OCP bf16 = upper 16 bits of f32) ----------
__device__ __forceinline__ float bf2f(unsigned short u) {
  return __uint_as_float(((unsigned)u) << 16);
}
__device__ __forceinline__ unsigned short f2bf(float f) {
  unsigned u = __float_as_uint(f);
  u = (u + 0x7FFFu + ((u >> 16) & 1u)) >> 16;  // RNE
  return (unsigned short)u;
}

typedef __attribute__((ext_vector_type(8))) short bf16x8;
typedef __attribute__((ext_vector_type(4))) float f32x4;

// ---------- edge_index layout probe ----------
__global__ void detect_kernel(const int* __restrict__ ei, int* __restrict__ flag) {
  int any = 0;
  for (int j = threadIdx.x; j < 4096; j += 256) any |= (ei[2 * j + 1] != 0);
  if (any) atomicOr(flag, 1);  // 1 => int32 layout
}

__device__ __forceinline__ int edge_src(const int* ei, int f, int e, int i) {
  return f ? ei[i] : ei[2 * (size_t)i];
}
__device__ __forceinline__ int edge_dst(const int* ei, int f, int e, int i) {
  return f ? ei[(size_t)e + i] : ei[2 * (size_t)e + 2 * (size_t)i];
}

// ---------- per-node degree histogram ----------
__global__ void hist_kernel(const int* __restrict__ ei, const int* __restrict__ flag,
                            int* __restrict__ cnt, int e) {
  int i = blockIdx.x * blockDim.x + threadIdx.x;
  if (i < e) atomicAdd(&cnt[edge_dst(ei, *flag, e, i)], 1);
}

// two-level scan for rp
__global__ void scan_block(const int* __restrict__ cnt, int* __restrict__ rp,
                           int* __restrict__ bsum, int n) {
  __shared__ int lds[256];
  const int t = threadIdx.x;
  const int base = blockIdx.x * 1024 + t * 4;
  int v0 = (base     < n) ? cnt[base]     : 0;
  int v1 = (base + 1 < n) ? cnt[base + 1] : 0;
  int v2 = (base + 2 < n) ? cnt[base + 2] : 0;
  int v3 = (base + 3 < n) ? cnt[base + 3] : 0;
  int s = v0 + v1 + v2 + v3;
  lds[t] = s;
  __syncthreads();
  for (int off = 1; off < 256; off <<= 1) {
    int y = (t >= off) ? lds[t - off] : 0;
    __syncthreads();
    lds[t] += y;
    __syncthreads();
  }
  int excl = lds[t] - s;
  if (base     < n) rp[base]     = excl;
  if (base + 1 < n) rp[base + 1] = excl + v0;
  if (base + 2 < n) rp[base + 2] = excl + v0 + v1;
  if (base + 3 < n) rp[base + 3] = excl + v0 + v1 + v2;
  if (t == 255) bsum[blockIdx.x] = lds[255];
}

__global__ void scan_tops(int* __restrict__ bsum, int* __restrict__ rp, int nb, int n) {
  __shared__ int lds[128];
  const int t = threadIdx.x;
  int v = (t < nb) ? bsum[t] : 0;
  lds[t] = v;
  __syncthreads();
  for (int off = 1; off < 128; off <<= 1) {
    int y = (t >= off) ? lds[t - off] : 0;
    __syncthreads();
    lds[t] += y;
    __syncthreads();
  }
  if (t < nb) bsum[t] = lds[t] - v;
  if (t == 127) rp[n] = lds[127];
}

__global__ void scan_add(int* __restrict__ rp, const int* __restrict__ bsum, int n) {
  const int base = blockIdx.x * 1024 + threadIdx.x * 4;
  const int add = bsum[blockIdx.x];
#pragma unroll
  for (int i = 0; i < 4; ++i)
    if (base + i < n) rp[base + i] += add;
}

// ---------- bucketed CSR fill ----------
#define NB 128

__global__ void bucket_hist(const int* __restrict__ ei, const int* __restrict__ flag,
                            int* __restrict__ bhist, int e, int W) {
  __shared__ int lh[NB];
  const int t = threadIdx.x;
  if (t < NB) lh[t] = 0;
  __syncthreads();
  const int base = blockIdx.x * 4096;
  const int f = *flag;
  for (int j = t; j < 4096; j += 256) {
    int i = base + j;
    if (i < e) atomicAdd(&lh[edge_dst(ei, f, e, i) / W], 1);
  }
  __syncthreads();
  if (t < NB && lh[t]) atomicAdd(&bhist[t], lh[t]);
}

__global__ void bucket_scan(const int* __restrict__ bhist, int* __restrict__ boffs,
                            int* __restrict__ bcur) {
  __shared__ int lds[NB];
  const int t = threadIdx.x;
  int v = bhist[t];
  lds[t] = v;
  __syncthreads();
  for (int off = 1; off < NB; off <<= 1) {
    int y = (t >= off) ? lds[t - off] : 0;
    __syncthreads();
    lds[t] += y;
    __syncthreads();
  }
  int excl = lds[t] - v;
  boffs[t] = excl;
  bcur[t] = excl;
  if (t == NB - 1) boffs[NB] = lds[NB - 1];
}

__global__ void bucket_scatter(const int* __restrict__ ei, const int* __restrict__ flag,
                               int* __restrict__ bcur, int2* __restrict__ ebuf,
                               int e, int W) {
  __shared__ int lh[NB];
  __shared__ int lbase[NB];
  const int t = threadIdx.x;
  if (t < NB) lh[t] = 0;
  __syncthreads();
  const int base = blockIdx.x * 4096;
  const int f = *flag;
  for (int j = t; j < 4096; j += 256) {
    int i = base + j;
    if (i < e) atomicAdd(&lh[edge_dst(ei, f, e, i) / W], 1);
  }
  __syncthreads();
  if (t < NB) {
    lbase[t] = lh[t] ? atomicAdd(&bcur[t], lh[t]) : 0;
    lh[t] = 0;
  }
  __syncthreads();
  for (int j = t; j < 4096; j += 256) {
    int i = base + j;
    if (i < e) {
      int d = edge_dst(ei, f, e, i);
      int s = edge_src(ei, f, e, i);
      int b = d / W;
      int off = atomicAdd(&lh[b], 1);
      ebuf[lbase[b] + off] = make_int2(s, d);
    }
  }
}

__global__ void bucket_fill(const int2* __restrict__ ebuf, const int* __restrict__ boffs,
                            const int* __restrict__ rp, int* __restrict__ col,
                            int n, int W) {
  __shared__ int cur[1024];
  const int b = blockIdx.x;
  const int lo = b * W;
  const int nn = min(W, n - lo);
  if (nn <= 0) return;
  for (int i = threadIdx.x; i < nn; i += 256) cur[i] = rp[lo + i];
  __syncthreads();
  const int beg = boffs[b], end = boffs[b + 1];
  for (int p = beg + threadIdx.x; p < end; p += 256) {
    int2 sd = ebuf[p];
    int pos = atomicAdd(&cur[sd.y - lo], 1);
    col[pos] = sd.x;
  }
}

// ---------- pack W[128][128] f32 into MFMA B-fragment order (bf16) ----------
__global__ void pack_mfma_b(const float* __restrict__ Wf, unsigned short* __restrict__ Wpk) {
  int i = blockIdx.x * 256 + threadIdx.x;  // 2048
  if (i >= 2048) return;
  int lane = i & 63, nt = (i >> 6) & 7, ks = i >> 9;
  int nn = lane & 15, q = lane >> 4;
  int k0 = ks * 32 + q * 8, col = nt * 16 + nn;
  unsigned short o[8];
#pragma unroll
  for (int j = 0; j < 8; ++j) o[j] = f2bf(Wf[(size_t)(k0 + j) * 128 + col]);
  uint4 u;
  u.x = (unsigned)o[0] | ((unsigned)o[1] << 16);
  u.y = (unsigned)o[2] | ((unsigned)o[3] << 16);
  u.z = (unsigned)o[4] | ((unsigned)o[5] << 16);
  u.w = (unsigned)o[6] | ((unsigned)o[7] << 16);
  *(uint4*)(Wpk + (size_t)i * 8) = u;
}

// hi/lo split pack for the self-linear weight: Hi = bf16(W), Lo = bf16(W - Hi)
__global__ void pack_mfma_b_hilo(const float* __restrict__ Wf,
                                 unsigned short* __restrict__ Hi,
                                 unsigned short* __restrict__ Lo) {
  int i = blockIdx.x * 256 + threadIdx.x;  // 2048
  if (i >= 2048) return;
  int lane = i & 63, nt = (i >> 6) & 7, ks = i >> 9;
  int nn = lane & 15, q = lane >> 4;
  int k0 = ks * 32 + q * 8, col = nt * 16 + nn;
  unsigned short oh[8], ol[8];
#pragma unroll
  for (int j = 0; j < 8; ++j) {
    float v = Wf[(size_t)(k0 + j) * 128 + col];
    unsigned short h = f2bf(v);
    oh[j] = h;
    ol[j] = f2bf(v - bf2f(h));
  }
  uint4 uh, ul;
  uh.x = (unsigned)oh[0] | ((unsigned)oh[1] << 16);
  uh.y = (unsigned)oh[2] | ((unsigned)oh[3] << 16);
  uh.z = (unsigned)oh[4] | ((unsigned)oh[5] << 16);
  uh.w = (unsigned)oh[6] | ((unsigned)oh[7] << 16);
  ul.x = (unsigned)ol[0] | ((unsigned)ol[1] << 16);
  ul.y = (unsigned)ol[2] | ((unsigned)ol[3] << 16);
  ul.z = (unsigned)ol[4] | ((unsigned)ol[5] << 16);
  ul.w = (unsigned)ol[6] | ((unsigned)ol[7] << 16);
  *(uint4*)(Hi + (size_t)i * 8) = uh;
  *(uint4*)(Lo + (size_t)i * 8) = ul;
}

// heads: merged [Wmu | Wlv], each [128][64] f32
__global__ void pack_mfma_head(const float* __restrict__ Wmu, const float* __restrict__ Wlv,
                               unsigned short* __restrict__ Wpk) {
  int i = blockIdx.x * 256 + threadIdx.x;  // 2048
  if (i >= 2048) return;
  int lane = i & 63, nt = (i >> 6) & 7, ks = i >> 9;
  int nn = lane & 15, q = lane >> 4;
  int k0 = ks * 32 + q * 8, col = nt * 16 + nn;
  unsigned short o[8];
#pragma unroll
  for (int j = 0; j < 8; ++j) {
    float v = (col < 64) ? Wmu[(size_t)(k0 + j) * 64 + col]
                         : Wlv[(size_t)(k0 + j) * 64 + (col - 64)];
    o[j] = f2bf(v);
  }
  uint4 u;
  u.x = (unsigned)o[0] | ((unsigned)o[1] << 16);
  u.y = (unsigned)o[2] | ((unsigned)o[3] << 16);
  u.z = (unsigned)o[4] | ((unsigned)o[5] << 16);
  u.w = (unsigned)o[6] | ((unsigned)o[7] << 16);
  *(uint4*)(Wpk + (size_t)i * 8) = u;
}

// ---------- fused layer GEMM (matrix pipe; BATCHED fragment loads) ----------
// Rounds 5-7 post-mortem: VGPR stayed 72-80 across all variants -> compiler kept
// ONE register for B-fragments and emitted load;wait;mfma x96 = 96 serialized L2
// round-trips/wave (~19K cy, matches 81-96us; MfmaUtil 5%). Fix: load fragments
// into explicit arrays in a dedicated loop (compile-time indices), THEN run the
// MFMA loop -> 8-16 independent loads in flight per batch.
__launch_bounds__(256)
__global__ void gemm_fused(const float* __restrict__ X, const unsigned short* __restrict__ Wpk,
                           const unsigned short* __restrict__ Sph, const unsigned short* __restrict__ Spl,
                           const float* __restrict__ a0s, const float* __restrict__ a0d,
                           const float* __restrict__ slb,
                           unsigned short* __restrict__ hg, float* __restrict__ hself,
                           float* __restrict__ als, float* __restrict__ ald, int n) {
  const int wave = threadIdx.x >> 6;
  const int lane = threadIdx.x & 63;
  const int nidx = lane & 15, q = lane >> 4;
  const int r0 = blockIdx.x * 64 + wave * 16;
  const int arow = r0 + nidx;

  // preload this lane's full 128B X segment (8 x float4), hoistable
  float4 xr[8];
  if (arow < n) {
    const float* xp = X + (size_t)arow * 128 + q * 8;
#pragma unroll
    for (int ks = 0; ks < 4; ++ks) {
      xr[2 * ks]     = *(const float4*)(xp + ks * 32);
      xr[2 * ks + 1] = *(const float4*)(xp + ks * 32 + 4);
    }
  } else {
#pragma unroll
    for (int j = 0; j < 8; ++j) xr[j] = make_float4(0.f, 0.f, 0.f, 0.f);
  }

  union U { unsigned short u[8]; bf16x8 v; };
  U afh[4], afl[4];
#pragma unroll
  for (int ks = 0; ks < 4; ++ks) {
    float xv[8] = {xr[2 * ks].x, xr[2 * ks].y, xr[2 * ks].z, xr[2 * ks].w,
                   xr[2 * ks + 1].x, xr[2 * ks + 1].y, xr[2 * ks + 1].z, xr[2 * ks + 1].w};
#pragma unroll
    for (int j = 0; j < 8; ++j) {
      unsigned short h = f2bf(xv[j]);
      afh[ks].u[j] = h;
      afl[ks].u[j] = f2bf(xv[j] - bf2f(h));
    }
  }

  f32x4 acc[8], accS[8];
#pragma unroll
  for (int nt = 0; nt < 8; ++nt) {
    acc[nt]  = (f32x4){0.f, 0.f, 0.f, 0.f};
    accS[nt] = (f32x4){0.f, 0.f, 0.f, 0.f};
  }

#pragma unroll
  for (int ks = 0; ks < 4; ++ks) {
    const size_t base = ((size_t)ks * 8 * 64 + lane) * 8;
    const unsigned short* bp = Wpk + base;
    const unsigned short* ph = Sph + base;
    const unsigned short* pl = Spl + base;

    // --- batch 1: all 8 GAT-weight fragments, then 8 MFMAs ---
    bf16x8 bW[8];
#pragma unroll
    for (int nt = 0; nt < 8; ++nt) bW[nt] = *(const bf16x8*)(bp + (size_t)nt * 512);
#pragma unroll
    for (int nt = 0; nt < 8; ++nt)
      acc[nt] = __builtin_amdgcn_mfma_f32_16x16x32_bf16(afh[ks].v, bW[nt], acc[nt], 0, 0, 0);

    // --- batch 2: all 16 self-weight fragments (hi+lo), then 24 MFMAs ---
    bf16x8 bH[8], bL[8];
#pragma unroll
    for (int nt = 0; nt < 8; ++nt) {
      bH[nt] = *(const bf16x8*)(ph + (size_t)nt * 512);
      bL[nt] = *(const bf16x8*)(pl + (size_t)nt * 512);
    }
#pragma unroll
    for (int nt = 0; nt < 8; ++nt) {
      accS[nt] = __builtin_amdgcn_mfma_f32_16x16x32_bf16(afh[ks].v, bH[nt], accS[nt], 0, 0, 0);
      accS[nt] = __builtin_amdgcn_mfma_f32_16x16x32_bf16(afl[ks].v, bH[nt], accS[nt], 0, 0, 0);
      accS[nt] = __builtin_amdgcn_mfma_f32_16x16x32_bf16(afh[ks].v, bL[nt], accS[nt], 0, 0, 0);
    }
  }

  // epilogue 1: hg (bf16) + rounded values for logits
  float dv[8][4];
#pragma unroll
  for (int nt = 0; nt < 8; ++nt) {
#pragma unroll
    for (int r = 0; r < 4; ++r) {
      unsigned short rb = f2bf(acc[nt][r]);
      dv[nt][r] = bf2f(rb);
      int row = r0 + q * 4 + r;
      if (row < n) hg[(size_t)row * 128 + nt * 16 + nidx] = rb;
    }
  }

  // epilogue 2: hself (f32) + bias
#pragma unroll
  for (int nt = 0; nt < 8; ++nt) {
    const float sb = slb[nt * 16 + nidx];
#pragma unroll
    for (int r = 0; r < 4; ++r) {
      int row = r0 + q * 4 + r;
      if (row < n) hself[(size_t)row * 128 + nt * 16 + nidx] = accS[nt][r] + sb;
    }
  }

  // epilogue 3: logits
  float ps[4] = {0, 0, 0, 0}, pd[4] = {0, 0, 0, 0};
#pragma unroll
  for (int nt = 0; nt < 8; ++nt) {
    float as_ = a0s[nt * 16 + nidx];
    float ad_ = a0d[nt * 16 + nidx];
#pragma unroll
    for (int r = 0; r < 4; ++r) {
      ps[r] = fmaf(dv[nt][r], as_, ps[r]);
      pd[r] = fmaf(dv[nt][r], ad_, pd[r]);
    }
  }
#pragma unroll
  for (int r = 0; r < 4; ++r) {
#pragma unroll
    for (int o = 8; o > 0; o >>= 1) {
      ps[r] += __shfl_xor(ps[r], o, 64);
      pd[r] += __shfl_xor(pd[r], o, 64);
    }
    int row = r0 + q * 4 + r;
    if (nidx == 0 && row < n) { als[row] = ps[r]; ald[row] = pd[r]; }
  }
}

// ---------- head MFMA GEMM: hg[n][128](bf16) = X@[Wmu|Wlv]; batched loads ----------
__launch_bounds__(256)
__global__ void gemm_mfma_head(const float* __restrict__ X, const unsigned short* __restrict__ Wpk,
                               const float* __restrict__ a0s, const float* __restrict__ a0d,
                               const float* __restrict__ a1s, const float* __restrict__ a1d,
                               unsigned short* __restrict__ hg,
                               float* __restrict__ als, float* __restrict__ ald, int n) {
  const int wave = threadIdx.x >> 6;
  const int lane = threadIdx.x & 63;
  const int nidx = lane & 15, q = lane >> 4;
  const int r0 = blockIdx.x * 64 + wave * 16;
  const int arow = r0 + nidx;

  float4 xr[8];
  if (arow < n) {
    const float* xp = X + (size_t)arow * 128 + q * 8;
#pragma unroll
    for (int ks = 0; ks < 4; ++ks) {
      xr[2 * ks]     = *(const float4*)(xp + ks * 32);
      xr[2 * ks + 1] = *(const float4*)(xp + ks * 32 + 4);
    }
  } else {
#pragma unroll
    for (int j = 0; j < 8; ++j) xr[j] = make_float4(0.f, 0.f, 0.f, 0.f);
  }

  union U { unsigned short u[8]; bf16x8 v; };
  U af[4];
#pragma unroll
  for (int ks = 0; ks < 4; ++ks) {
    float xv[8] = {xr[2 * ks].x, xr[2 * ks].y, xr[2 * ks].z, xr[2 * ks].w,
                   xr[2 * ks + 1].x, xr[2 * ks + 1].y, xr[2 * ks + 1].z, xr[2 * ks + 1].w};
#pragma unroll
    for (int j = 0; j < 8; ++j) af[ks].u[j] = f2bf(xv[j]);
  }

  f32x4 acc[8];
#pragma unroll
  for (int nt = 0; nt < 8; ++nt) acc[nt] = (f32x4){0.f, 0.f, 0.f, 0.f};

#pragma unroll
  for (int ks = 0; ks < 4; ++ks) {
    const unsigned short* bp = Wpk + ((size_t)ks * 8 * 64 + lane) * 8;
    bf16x8 bW[8];
#pragma unroll
    for (int nt = 0; nt < 8; ++nt) bW[nt] = *(const bf16x8*)(bp + (size_t)nt * 512);
#pragma unroll
    for (int nt = 0; nt < 8; ++nt)
      acc[nt] = __builtin_amdgcn_mfma_f32_16x16x32_bf16(af[ks].v, bW[nt], acc[nt], 0, 0, 0);
  }

  float dv[8][4];
#pragma unroll
  for (int nt = 0; nt < 8; ++nt) {
#pragma unroll
    for (int r = 0; r < 4; ++r) {
      unsigned short rb = f2bf(acc[nt][r]);
      dv[nt][r] = bf2f(rb);
      int row = r0 + q * 4 + r;
      if (row < n) hg[(size_t)row * 128 + nt * 16 + nidx] = rb;
    }
  }

  float pms[4] = {0, 0, 0, 0}, pmd[4] = {0, 0, 0, 0};
  float pls[4] = {0, 0, 0, 0}, pld[4] = {0, 0, 0, 0};
#pragma unroll
  for (int nt = 0; nt < 4; ++nt) {
    float as_ = a0s[nt * 16 + nidx];
    float ad_ = a0d[nt * 16 + nidx];
#pragma unroll
    for (int r = 0; r < 4; ++r) {
      pms[r] = fmaf(dv[nt][r], as_, pms[r]);
      pmd[r] = fmaf(dv[nt][r], ad_, pmd[r]);
    }
  }
#pragma unroll
  for (int nt = 4; nt < 8; ++nt) {
    float as_ = a1s[(nt - 4) * 16 + nidx];
    float ad_ = a1d[(nt - 4) * 16 + nidx];
#pragma unroll
    for (int r = 0; r < 4; ++r) {
      pls[r] = fmaf(dv[nt][r], as_, pls[r]);
      pld[r] = fmaf(dv[nt][r], ad_, pld[r]);
    }
  }
#pragma unroll
  for (int r = 0; r < 4; ++r) {
#pragma unroll
    for (int o = 8; o > 0; o >>= 1) {
      pms[r] += __shfl_xor(pms[r], o, 64);
      pmd[r] += __shfl_xor(pmd[r], o, 64);
      pls[r] += __shfl_xor(pls[r], o, 64);
      pld[r] += __shfl_xor(pld[r], o, 64);
    }
    int row = r0 + q * 4 + r;
    if (nidx == 0 && row < n) {
      ((float2*)als)[row] = make_float2(pms[r], pls[r]);
      ((float2*)ald)[row] = make_float2(pmd[r], pld[r]);
    }
  }
}

// ---------- layer aggregation: 16 lanes/node; chunk-pipelined; ILP-8 gathers ----------
__launch_bounds__(256)
__global__ void gat_agg3(const unsigned short* __restrict__ hg,
                         const float* __restrict__ als, const float* __restrict__ aldv,
                         const int* __restrict__ rp, const int* __restrict__ col,
                         const float* __restrict__ biasf, float* __restrict__ outv,
                         const float* base, int n, int self_loop, int act) {
  const int node = blockIdx.x * 16 + (threadIdx.x >> 4);
  if (node >= n) return;
  const int g = threadIdx.x & 15;
  const int beg = rp[node];
  const int deg = rp[node + 1] - beg;
  const int total = deg + self_loop;
  const float ad = aldv[node];

  float den = 0.f;
  float acc[8];
#pragma unroll
  for (int k = 0; k < 8; ++k) acc[k] = 0.f;

  const unsigned short* hgl = hg + g * 8;

  auto chunkw = [&](int cb, int& s) -> float {
    const int idx = cb + g;
    s = node;
    if (idx < deg) s = col[beg + idx];
    if (idx >= total) return 0.f;
    float t = als[s] + ad;
    return __expf((t > 0.f) ? t : 0.2f * t);  // LeakyReLU(0.2) then exp
  };

  int sA; float wA = chunkw(0, sA);

  for (int cb = 0; cb < total; cb += 16) {
    int sB = node; float wB = 0.f;
    if (cb + 16 < total) wB = chunkw(cb + 16, sB);

    const int cnt = (total - cb < 16) ? (total - cb) : 16;
    int j = 0;
    for (; j + 8 <= cnt; j += 8) {
      float w[8]; int ss[8]; uint4 rr[8];
#pragma unroll
      for (int u = 0; u < 8; ++u) { w[u] = __shfl(wA, j + u, 16); ss[u] = __shfl(sA, j + u, 16); }
#pragma unroll
      for (int u = 0; u < 8; ++u) rr[u] = *(const uint4*)(hgl + (size_t)ss[u] * 128);
#pragma unroll
      for (int u = 0; u < 8; ++u) {
        den += w[u];
        acc[0] = fmaf(w[u], __uint_as_float(rr[u].x << 16),        acc[0]);
        acc[1] = fmaf(w[u], __uint_as_float(rr[u].x & 0xFFFF0000u), acc[1]);
        acc[2] = fmaf(w[u], __uint_as_float(rr[u].y << 16),        acc[2]);
        acc[3] = fmaf(w[u], __uint_as_float(rr[u].y & 0xFFFF0000u), acc[3]);
        acc[4] = fmaf(w[u], __uint_as_float(rr[u].z << 16),        acc[4]);
        acc[5] = fmaf(w[u], __uint_as_float(rr[u].z & 0xFFFF0000u), acc[5]);
        acc[6] = fmaf(w[u], __uint_as_float(rr[u].w << 16),        acc[6]);
        acc[7] = fmaf(w[u], __uint_as_float(rr[u].w & 0xFFFF0000u), acc[7]);
      }
    }
    for (; j + 4 <= cnt; j += 4) {
      float w[4]; int ss[4]; uint4 rr[4];
#pragma unroll
      for (int u = 0; u < 4; ++u) { w[u] = __shfl(wA, j + u, 16); ss[u] = __shfl(sA, j + u, 16); }
#pragma unroll
      for (int u = 0; u < 4; ++u) rr[u] = *(const uint4*)(hgl + (size_t)ss[u] * 128);
#pragma unroll
      for (int u = 0; u < 4; ++u) {
        den += w[u];
        acc[0] = fmaf(w[u], __uint_as_float(rr[u].x << 16),        acc[0]);
        acc[1] = fmaf(w[u], __uint_as_float(rr[u].x & 0xFFFF0000u), acc[1]);
        acc[2] = fmaf(w[u], __uint_as_float(rr[u].y << 16),        acc[2]);
        acc[3] = fmaf(w[u], __uint_as_float(rr[u].y & 0xFFFF0000u), acc[3]);
        acc[4] = fmaf(w[u], __uint_as_float(rr[u].z << 16),        acc[4]);
        acc[5] = fmaf(w[u], __uint_as_float(rr[u].z & 0xFFFF0000u), acc[5]);
        acc[6] = fmaf(w[u], __uint_as_float(rr[u].w << 16),        acc[6]);
        acc[7] = fmaf(w[u], __uint_as_float(rr[u].w & 0xFFFF0000u), acc[7]);
      }
    }
    for (; j < cnt; ++j) {
      float wj = __shfl(wA, j, 16);
      int sj = __shfl(sA, j, 16);
      uint4 raw = *(const uint4*)(hgl + (size_t)sj * 128);
      den += wj;
      acc[0] = fmaf(wj, __uint_as_float(raw.x << 16),        acc[0]);
      acc[1] = fmaf(wj, __uint_as_float(raw.x & 0xFFFF0000u), acc[1]);
      acc[2] = fmaf(wj, __uint_as_float(raw.y << 16),        acc[2]);
      acc[3] = fmaf(wj, __uint_as_float(raw.y & 0xFFFF0000u), acc[3]);
      acc[4] = fmaf(wj, __uint_as_float(raw.z << 16),        acc[4]);
      acc[5] = fmaf(wj, __uint_as_float(raw.z & 0xFFFF0000u), acc[5]);
      acc[6] = fmaf(wj, __uint_as_float(raw.w << 16),        acc[6]);
      acc[7] = fmaf(wj, __uint_as_float(raw.w & 0xFFFF0000u), acc[7]);
    }
    sA = sB; wA = wB;
  }

  const float inv = 1.f / (den + 1e-16f);
  const size_t o = (size_t)node * 128 + g * 8;
  float4 bv0 = *(const float4*)(biasf + g * 8);
  float4 bv1 = *(const float4*)(biasf + g * 8 + 4);
  float r[8];
  r[0] = acc[0] * inv + bv0.x; r[1] = acc[1] * inv + bv0.y;
  r[2] = acc[2] * inv + bv0.z; r[3] = acc[3] * inv + bv0.w;
  r[4] = acc[4] * inv + bv1.x; r[5] = acc[5] * inv + bv1.y;
  r[6] = acc[6] * inv + bv1.z; r[7] = acc[7] * inv + bv1.w;
  if (base) {
    float4 s0 = *(const float4*)(base + o);
    float4 s1 = *(const float4*)(base + o + 4);
    r[0] += s0.x; r[1] += s0.y; r[2] += s0.z; r[3] += s0.w;
    r[4] += s1.x; r[5] += s1.y; r[6] += s1.z; r[7] += s1.w;
  }
  if (act) {
#pragma unroll
    for (int k = 0; k < 8; ++k) r[k] = (r[k] > 0.f) ? r[k] : 0.01f * r[k];
  }
  *(float4*)(outv + o)     = make_float4(r[0], r[1], r[2], r[3]);
  *(float4*)(outv + o + 4) = make_float4(r[4], r[5], r[6], r[7]);
}

// ---------- dual-head aggregation: mu + logvar in ONE gather pass; pipelined; ILP-8 ----------
__launch_bounds__(256)
__global__ void gat_agg_dual(const unsigned short* __restrict__ hg,
                             const float2* __restrict__ alsH, const float2* __restrict__ aldH,
                             const int* __restrict__ rp, const int* __restrict__ col,
                             const float* __restrict__ bmu, const float* __restrict__ blv,
                             float* __restrict__ outF, int n) {
  const int node = blockIdx.x * 16 + (threadIdx.x >> 4);
  if (node >= n) return;
  const int g = threadIdx.x & 15;
  const bool isMu = g < 8;
  const int beg = rp[node];
  const int deg = rp[node + 1] - beg;
  const int total = deg + 1;  // heads always have self loop
  const float2 ad = aldH[node];

  float den = 0.f;
  float acc[8];
#pragma unroll
  for (int k = 0; k < 8; ++k) acc[k] = 0.f;

  const unsigned short* hgl = hg + g * 8;

  auto chunkw = [&](int cb, int& s, float& eM, float& eL) {
    const int idx = cb + g;
    s = node;
    if (idx < deg) s = col[beg + idx];
    if (idx >= total) { eM = 0.f; eL = 0.f; return; }
    float2 a_ = alsH[s];
    float vm = a_.x + ad.x, vl = a_.y + ad.y;
    eM = __expf((vm > 0.f) ? vm : 0.2f * vm);
    eL = __expf((vl > 0.f) ? vl : 0.2f * vl);
  };

  int sA; float eMA, eLA;
  chunkw(0, sA, eMA, eLA);

  for (int cb = 0; cb < total; cb += 16) {
    int sB = node; float eMB = 0.f, eLB = 0.f;
    if (cb + 16 < total) chunkw(cb + 16, sB, eMB, eLB);

    const int cnt = (total - cb < 16) ? (total - cb) : 16;
    int j = 0;
    for (; j + 8 <= cnt; j += 8) {
      float w[8]; int ss[8]; uint4 rr[8];
#pragma unroll
      for (int u = 0; u < 8; ++u) {
        float wm = __shfl(eMA, j + u, 16), wl = __shfl(eLA, j + u, 16);
        w[u] = isMu ? wm : wl;
        ss[u] = __shfl(sA, j + u, 16);
      }
#pragma unroll
      for (int u = 0; u < 8; ++u) rr[u] = *(const uint4*)(hgl + (size_t)ss[u] * 128);
#pragma unroll
      for (int u = 0; u < 8; ++u) {
        den += w[u];
        acc[0] = fmaf(w[u], __uint_as_float(rr[u].x << 16),        acc[0]);
        acc[1] = fmaf(w[u], __uint_as_float(rr[u].x & 0xFFFF0000u), acc[1]);
        acc[2] = fmaf(w[u], __uint_as_float(rr[u].y << 16),        acc[2]);
        acc[3] = fmaf(w[u], __uint_as_float(rr[u].y & 0xFFFF0000u), acc[3]);
        acc[4] = fmaf(w[u], __uint_as_float(rr[u].z << 16),        acc[4]);
        acc[5] = fmaf(w[u], __uint_as_float(rr[u].z & 0xFFFF0000u), acc[5]);
        acc[6] = fmaf(w[u], __uint_as_float(rr[u].w << 16),        acc[6]);
        acc[7] = fmaf(w[u], __uint_as_float(rr[u].w & 0xFFFF0000u), acc[7]);
      }
    }
    for (; j + 4 <= cnt; j += 4) {
      float w[4]; int ss[4]; uint4 rr[4];
#pragma unroll
      for (int u = 0; u < 4; ++u) {
        float wm = __shfl(eMA, j + u, 16), wl = __shfl(eLA, j + u, 16);
        w[u] = isMu ? wm : wl;
        ss[u] = __shfl(sA, j + u, 16);
      }
#pragma unroll
      for (int u = 0; u < 4; ++u) rr[u] = *(const uint4*)(hgl + (size_t)ss[u] * 128);
#pragma unroll
      for (int u = 0; u < 4; ++u) {
        den += w[u];
        acc[0] = fmaf(w[u], __uint_as_float(rr[u].x << 16),        acc[0]);
        acc[1] = fmaf(w[u], __uint_as_float(rr[u].x & 0xFFFF0000u), acc[1]);
        acc[2] = fmaf(w[u], __uint_as_float(rr[u].y << 16),        acc[2]);
        acc[3] = fmaf(w[u], __uint_as_float(rr[u].y & 0xFFFF0000u), acc[3]);
        acc[4] = fmaf(w[u], __uint_as_float(rr[u].z << 16),        acc[4]);
        acc[5] = fmaf(w[u], __uint_as_float(rr[u].z & 0xFFFF0000u), acc[5]);
        acc[6] = fmaf(w[u], __uint_as_float(rr[u].w << 16),        acc[6]);
        acc[7] = fmaf(w[u], __uint_as_float(rr[u].w & 0xFFFF0000u), acc[7]);
      }
    }
    for (; j < cnt; ++j) {
      float wm = __shfl(eMA, j, 16), wl = __shfl(eLA, j, 16);
      float wj = isMu ? wm : wl;
      int sj = __shfl(sA, j, 16);
      uint4 raw = *(const uint4*)(hgl + (size_t)sj * 128);
      den += wj;
      acc[0] = fmaf(wj, __uint_as_float(raw.x << 16),        acc[0]);
      acc[1] = fmaf(wj, __uint_as_float(raw.x & 0xFFFF0000u), acc[1]);
      acc[2] = fmaf(wj, __uint_as_float(raw.y << 16),        acc[2]);
      acc[3] = fmaf(wj, __uint_as_float(raw.y & 0xFFFF0000u), acc[3]);
      acc[4] = fmaf(wj, __uint_as_float(raw.z << 16),        acc[4]);
      acc[5] = fmaf(wj, __uint_as_float(raw.z & 0xFFFF0000u), acc[5]);
      acc[6] = fmaf(wj, __uint_as_float(raw.w << 16),        acc[6]);
      acc[7] = fmaf(wj, __uint_as_float(raw.w & 0xFFFF0000u), acc[7]);
    }
    sA = sB; eMA = eMB; eLA = eLB;
  }

  const float inv = 1.f / (den + 1e-16f);
  const int c = (g & 7) * 8;
  const float* bb = isMu ? bmu : blv;
  float4 bv0 = *(const float4*)(bb + c);
  float4 bv1 = *(const float4*)(bb + c + 4);
  float* op = outF + (isMu ? (size_t)0 : (size_t)n * 64) + (size_t)node * 64 + c;
  *(float4*)op = make_float4(acc[0] * inv + bv0.x, acc[1] * inv + bv0.y,
                             acc[2] * inv + bv0.z, acc[3] * inv + bv0.w);
  *(float4*)(op + 4) = make_float4(acc[4] * inv + bv1.x, acc[5] * inv + bv1.y,
                                   acc[6] * inv + bv1.z, acc[7] * inv + bv1.w);
}

extern "C" void kernel_launch(void* const* d_in, const int* in_sizes, int n_in,
                              void* d_out, int out_size, void* d_ws, size_t ws_size,
                              hipStream_t stream) {
  const int N = in_sizes[0] / 128;   // 100000
  const int E = in_sizes[1] / 2;     // 1600000
  const int W = (N + NB - 1) / NB;   // nodes per bucket (<=1024)

  const float* x    = (const float*)d_in[0];
  const int*   ei   = (const int*)d_in[1];
  const float* W0   = (const float*)d_in[2];
  const float* as0  = (const float*)d_in[3];
  const float* ad0  = (const float*)d_in[4];
  const float* b0   = (const float*)d_in[5];
  const float* slW0 = (const float*)d_in[6];
  const float* slb0 = (const float*)d_in[7];
  const float* W1   = (const float*)d_in[8];
  const float* as1  = (const float*)d_in[9];
  const float* ad1  = (const float*)d_in[10];
  const float* b1   = (const float*)d_in[11];
  const float* slW1 = (const float*)d_in[12];
  const float* slb1 = (const float*)d_in[13];
  const float* Wmu  = (const float*)d_in[14];
  const float* asmu = (const float*)d_in[15];
  const float* admu = (const float*)d_in[16];
  const float* bmu  = (const float*)d_in[17];
  const float* Wlv  = (const float*)d_in[18];
  const float* aslv = (const float*)d_in[19];
  const float* adlv = (const float*)d_in[20];
  const float* blv  = (const float*)d_in[21];

  float*          outF = (float*)d_out;
  unsigned short* hgB  = (unsigned short*)d_out;  // layers' hg lives in d_out (dead before heads write)

  char* w = (char*)d_ws;
  auto carve = [&](size_t bytes) -> char* {
    char* p = w;
    w += (bytes + 255) & ~(size_t)255;
    return p;
  };
  float*          h0    = (float*)carve((size_t)N * 128 * 4);           // 51.2 MB
  unsigned short* hgHd  = (unsigned short*)carve((size_t)N * 128 * 2);  // 25.6 MB
  float*          als   = (float*)carve((size_t)N * 4);
  float*          ald   = (float*)carve((size_t)N * 4);
  float2*         alsH  = (float2*)carve((size_t)N * 8);
  float2*         aldH  = (float2*)carve((size_t)N * 8);
  int*            cnt   = (int*)carve((size_t)N * 4);
  int*            rp    = (int*)carve((size_t)(N + 1) * 4);
  int*            col   = (int*)carve((size_t)E * 4);
  int*            bsum  = (int*)carve(512);
  int*            bhist = (int*)carve(NB * 4);
  int*            boffs = (int*)carve((NB + 1) * 4);
  int*            bcur  = (int*)carve(NB * 4);
  int*            flag  = (int*)carve(4);
  unsigned short* Wpk0  = (unsigned short*)carve(2048 * 8 * 2);
  unsigned short* Wpk1  = (unsigned short*)carve(2048 * 8 * 2);
  unsigned short* Wpkh  = (unsigned short*)carve(2048 * 8 * 2);
  unsigned short* Spk0h = (unsigned short*)carve(2048 * 8 * 2);
  unsigned short* Spk0l = (unsigned short*)carve(2048 * 8 * 2);
  unsigned short* Spk1h = (unsigned short*)carve(2048 * 8 * 2);
  unsigned short* Spk1l = (unsigned short*)carve(2048 * 8 * 2);
  int2*           ebuf  = (int2*)h0;  // alias: h0 dead during CSR build

  const int gE  = (E + 255) / 256;
  const int gB4 = (E + 4095) / 4096;
  const int gG  = (N + 63) / 64;
  const int gW  = (N + 15) / 16;     // 16 nodes per 256-thread block
  const int nb  = (N + 1023) / 1024;

  // --- probe + bucketed CSR build ---
  hipMemsetAsync(flag, 0, 4, stream);
  hipMemsetAsync(cnt, 0, (size_t)N * 4, stream);
  hipMemsetAsync(bhist, 0, NB * 4, stream);
  detect_kernel<<<1, 256, 0, stream>>>(ei, flag);
  hist_kernel<<<gE, 256, 0, stream>>>(ei, flag, cnt, E);
  bucket_hist<<<gB4, 256, 0, stream>>>(ei, flag, bhist, E, W);
  scan_block<<<nb, 256, 0, stream>>>(cnt, rp, bsum, N);
  scan_tops<<<1, 128, 0, stream>>>(bsum, rp, nb, N);
  scan_add<<<nb, 256, 0, stream>>>(rp, bsum, N);
  bucket_scan<<<1, NB, 0, stream>>>(bhist, boffs, bcur);
  bucket_scatter<<<gB4, 256, 0, stream>>>(ei, flag, bcur, ebuf, E, W);
  bucket_fill<<<NB, 256, 0, stream>>>(ebuf, boffs, rp, col, N, W);

  // --- pack weights into MFMA B-fragment order (bf16; self weights hi/lo split) ---
  pack_mfma_b<<<8, 256, 0, stream>>>(W0, Wpk0);
  pack_mfma_b<<<8, 256, 0, stream>>>(W1, Wpk1);
  pack_mfma_b_hilo<<<8, 256, 0, stream>>>(slW0, Spk0h, Spk0l);
  pack_mfma_b_hilo<<<8, 256, 0, stream>>>(slW1, Spk1h, Spk1l);
  pack_mfma_head<<<8, 256, 0, stream>>>(Wmu, Wlv, Wpkh);

  // --- layer 0: one fused MFMA GEMM (hg + logits + self-linear), then fused agg ---
  gemm_fused<<<gG, 256, 0, stream>>>(x, Wpk0, Spk0h, Spk0l, as0, ad0, slb0,
                                     hgB, h0, als, ald, N);
  gat_agg3<<<gW, 256, 0, stream>>>(hgB, als, ald, rp, col, b0, h0, h0, N, 0, 1);

  // --- layer 1 (self loops); reads h0 in its own row band, writes same band ---
  gemm_fused<<<gG, 256, 0, stream>>>(h0, Wpk1, Spk1h, Spk1l, as1, ad1, slb1,
                                     hgB, h0, als, ald, N);
  gat_agg3<<<gW, 256, 0, stream>>>(hgB, als, ald, rp, col, b1, h0, h0, N, 1, 1);

  // --- heads: one merged MFMA GEMM (+both logit pairs), one dual gather pass ---
  gemm_mfma_head<<<gG, 256, 0, stream>>>(h0, Wpkh, asmu, admu, aslv, adlv,
                                         hgHd, (float*)alsH, (float*)aldH, N);
  gat_agg_dual<<<gW, 256, 0, stream>>>(hgHd, alsH, aldH, rp, col, bmu, blv, outF, N);
}

// Round 9
// 650.196 us; speedup vs baseline: 1.0845x; 1.0122x over previous
//
#include <hip/hip_runtime.h>
#include <cstdint>
#include <cstddef>

// ---------- bf16 helpers (OCP bf16 = upper 16 bits of f32) ----------
__device__ __forceinline__ float bf2f(unsigned short u) {
  return __uint_as_float(((unsigned)u) << 16);
}
__device__ __forceinline__ unsigned short f2bf(float f) {
  unsigned u = __float_as_uint(f);
  u = (u + 0x7FFFu + ((u >> 16) & 1u)) >> 16;  // RNE
  return (unsigned short)u;
}

typedef __attribute__((ext_vector_type(8))) short bf16x8;
typedef __attribute__((ext_vector_type(4))) float f32x4;

// ---------- edge_index layout probe ----------
__global__ void detect_kernel(const int* __restrict__ ei, int* __restrict__ flag) {
  int any = 0;
  for (int j = threadIdx.x; j < 4096; j += 256) any |= (ei[2 * j + 1] != 0);
  if (any) atomicOr(flag, 1);  // 1 => int32 layout
}

__device__ __forceinline__ int edge_src(const int* ei, int f, int e, int i) {
  return f ? ei[i] : ei[2 * (size_t)i];
}
__device__ __forceinline__ int edge_dst(const int* ei, int f, int e, int i) {
  return f ? ei[(size_t)e + i] : ei[2 * (size_t)e + 2 * (size_t)i];
}

// ---------- per-node degree histogram ----------
__global__ void hist_kernel(const int* __restrict__ ei, const int* __restrict__ flag,
                            int* __restrict__ cnt, int e) {
  int i = blockIdx.x * blockDim.x + threadIdx.x;
  if (i < e) atomicAdd(&cnt[edge_dst(ei, *flag, e, i)], 1);
}

// two-level scan for rp
__global__ void scan_block(const int* __restrict__ cnt, int* __restrict__ rp,
                           int* __restrict__ bsum, int n) {
  __shared__ int lds[256];
  const int t = threadIdx.x;
  const int base = blockIdx.x * 1024 + t * 4;
  int v0 = (base     < n) ? cnt[base]     : 0;
  int v1 = (base + 1 < n) ? cnt[base + 1] : 0;
  int v2 = (base + 2 < n) ? cnt[base + 2] : 0;
  int v3 = (base + 3 < n) ? cnt[base + 3] : 0;
  int s = v0 + v1 + v2 + v3;
  lds[t] = s;
  __syncthreads();
  for (int off = 1; off < 256; off <<= 1) {
    int y = (t >= off) ? lds[t - off] : 0;
    __syncthreads();
    lds[t] += y;
    __syncthreads();
  }
  int excl = lds[t] - s;
  if (base     < n) rp[base]     = excl;
  if (base + 1 < n) rp[base + 1] = excl + v0;
  if (base + 2 < n) rp[base + 2] = excl + v0 + v1;
  if (base + 3 < n) rp[base + 3] = excl + v0 + v1 + v2;
  if (t == 255) bsum[blockIdx.x] = lds[255];
}

__global__ void scan_tops(int* __restrict__ bsum, int* __restrict__ rp, int nb, int n) {
  __shared__ int lds[128];
  const int t = threadIdx.x;
  int v = (t < nb) ? bsum[t] : 0;
  lds[t] = v;
  __syncthreads();
  for (int off = 1; off < 128; off <<= 1) {
    int y = (t >= off) ? lds[t - off] : 0;
    __syncthreads();
    lds[t] += y;
    __syncthreads();
  }
  if (t < nb) bsum[t] = lds[t] - v;
  if (t == 127) rp[n] = lds[127];
}

__global__ void scan_add(int* __restrict__ rp, const int* __restrict__ bsum, int n) {
  const int base = blockIdx.x * 1024 + threadIdx.x * 4;
  const int add = bsum[blockIdx.x];
#pragma unroll
  for (int i = 0; i < 4; ++i)
    if (base + i < n) rp[base + i] += add;
}

// ---------- bucketed CSR fill ----------
#define NB 128

__global__ void bucket_hist(const int* __restrict__ ei, const int* __restrict__ flag,
                            int* __restrict__ bhist, int e, int W) {
  __shared__ int lh[NB];
  const int t = threadIdx.x;
  if (t < NB) lh[t] = 0;
  __syncthreads();
  const int base = blockIdx.x * 4096;
  const int f = *flag;
  for (int j = t; j < 4096; j += 256) {
    int i = base + j;
    if (i < e) atomicAdd(&lh[edge_dst(ei, f, e, i) / W], 1);
  }
  __syncthreads();
  if (t < NB && lh[t]) atomicAdd(&bhist[t], lh[t]);
}

__global__ void bucket_scan(const int* __restrict__ bhist, int* __restrict__ boffs,
                            int* __restrict__ bcur) {
  __shared__ int lds[NB];
  const int t = threadIdx.x;
  int v = bhist[t];
  lds[t] = v;
  __syncthreads();
  for (int off = 1; off < NB; off <<= 1) {
    int y = (t >= off) ? lds[t - off] : 0;
    __syncthreads();
    lds[t] += y;
    __syncthreads();
  }
  int excl = lds[t] - v;
  boffs[t] = excl;
  bcur[t] = excl;
  if (t == NB - 1) boffs[NB] = lds[NB - 1];
}

__global__ void bucket_scatter(const int* __restrict__ ei, const int* __restrict__ flag,
                               int* __restrict__ bcur, int2* __restrict__ ebuf,
                               int e, int W) {
  __shared__ int lh[NB];
  __shared__ int lbase[NB];
  const int t = threadIdx.x;
  if (t < NB) lh[t] = 0;
  __syncthreads();
  const int base = blockIdx.x * 4096;
  const int f = *flag;
  for (int j = t; j < 4096; j += 256) {
    int i = base + j;
    if (i < e) atomicAdd(&lh[edge_dst(ei, f, e, i) / W], 1);
  }
  __syncthreads();
  if (t < NB) {
    lbase[t] = lh[t] ? atomicAdd(&bcur[t], lh[t]) : 0;
    lh[t] = 0;
  }
  __syncthreads();
  for (int j = t; j < 4096; j += 256) {
    int i = base + j;
    if (i < e) {
      int d = edge_dst(ei, f, e, i);
      int s = edge_src(ei, f, e, i);
      int b = d / W;
      int off = atomicAdd(&lh[b], 1);
      ebuf[lbase[b] + off] = make_int2(s, d);
    }
  }
}

__global__ void bucket_fill(const int2* __restrict__ ebuf, const int* __restrict__ boffs,
                            const int* __restrict__ rp, int* __restrict__ col,
                            int n, int W) {
  __shared__ int cur[1024];
  const int b = blockIdx.x;
  const int lo = b * W;
  const int nn = min(W, n - lo);
  if (nn <= 0) return;
  for (int i = threadIdx.x; i < nn; i += 256) cur[i] = rp[lo + i];
  __syncthreads();
  const int beg = boffs[b], end = boffs[b + 1];
  for (int p = beg + threadIdx.x; p < end; p += 256) {
    int2 sd = ebuf[p];
    int pos = atomicAdd(&cur[sd.y - lo], 1);
    col[pos] = sd.x;
  }
}

// ---------- pack W[128][128] f32 into MFMA B-fragment order (bf16) ----------
__global__ void pack_mfma_b(const float* __restrict__ Wf, unsigned short* __restrict__ Wpk) {
  int i = blockIdx.x * 256 + threadIdx.x;  // 2048
  if (i >= 2048) return;
  int lane = i & 63, nt = (i >> 6) & 7, ks = i >> 9;
  int nn = lane & 15, q = lane >> 4;
  int k0 = ks * 32 + q * 8, col = nt * 16 + nn;
  unsigned short o[8];
#pragma unroll
  for (int j = 0; j < 8; ++j) o[j] = f2bf(Wf[(size_t)(k0 + j) * 128 + col]);
  uint4 u;
  u.x = (unsigned)o[0] | ((unsigned)o[1] << 16);
  u.y = (unsigned)o[2] | ((unsigned)o[3] << 16);
  u.z = (unsigned)o[4] | ((unsigned)o[5] << 16);
  u.w = (unsigned)o[6] | ((unsigned)o[7] << 16);
  *(uint4*)(Wpk + (size_t)i * 8) = u;
}

// hi/lo split pack for the self-linear weight: Hi = bf16(W), Lo = bf16(W - Hi)
__global__ void pack_mfma_b_hilo(const float* __restrict__ Wf,
                                 unsigned short* __restrict__ Hi,
                                 unsigned short* __restrict__ Lo) {
  int i = blockIdx.x * 256 + threadIdx.x;  // 2048
  if (i >= 2048) return;
  int lane = i & 63, nt = (i >> 6) & 7, ks = i >> 9;
  int nn = lane & 15, q = lane >> 4;
  int k0 = ks * 32 + q * 8, col = nt * 16 + nn;
  unsigned short oh[8], ol[8];
#pragma unroll
  for (int j = 0; j < 8; ++j) {
    float v = Wf[(size_t)(k0 + j) * 128 + col];
    unsigned short h = f2bf(v);
    oh[j] = h;
    ol[j] = f2bf(v - bf2f(h));
  }
  uint4 uh, ul;
  uh.x = (unsigned)oh[0] | ((unsigned)oh[1] << 16);
  uh.y = (unsigned)oh[2] | ((unsigned)oh[3] << 16);
  uh.z = (unsigned)oh[4] | ((unsigned)oh[5] << 16);
  uh.w = (unsigned)oh[6] | ((unsigned)oh[7] << 16);
  ul.x = (unsigned)ol[0] | ((unsigned)ol[1] << 16);
  ul.y = (unsigned)ol[2] | ((unsigned)ol[3] << 16);
  ul.z = (unsigned)ol[4] | ((unsigned)ol[5] << 16);
  ul.w = (unsigned)ol[6] | ((unsigned)ol[7] << 16);
  *(uint4*)(Hi + (size_t)i * 8) = uh;
  *(uint4*)(Lo + (size_t)i * 8) = ul;
}

// heads: merged [Wmu | Wlv], each [128][64] f32
__global__ void pack_mfma_head(const float* __restrict__ Wmu, const float* __restrict__ Wlv,
                               unsigned short* __restrict__ Wpk) {
  int i = blockIdx.x * 256 + threadIdx.x;  // 2048
  if (i >= 2048) return;
  int lane = i & 63, nt = (i >> 6) & 7, ks = i >> 9;
  int nn = lane & 15, q = lane >> 4;
  int k0 = ks * 32 + q * 8, col = nt * 16 + nn;
  unsigned short o[8];
#pragma unroll
  for (int j = 0; j < 8; ++j) {
    float v = (col < 64) ? Wmu[(size_t)(k0 + j) * 64 + col]
                         : Wlv[(size_t)(k0 + j) * 64 + (col - 64)];
    o[j] = f2bf(v);
  }
  uint4 u;
  u.x = (unsigned)o[0] | ((unsigned)o[1] << 16);
  u.y = (unsigned)o[2] | ((unsigned)o[3] << 16);
  u.z = (unsigned)o[4] | ((unsigned)o[5] << 16);
  u.w = (unsigned)o[6] | ((unsigned)o[7] << 16);
  *(uint4*)(Wpk + (size_t)i * 8) = u;
}

// ---------- fused layer GEMM (matrix pipe; merged per-ks load batch) ----------
// R8 post-mortem: per-wave L2 table re-read (96KB/wave, ~600MB/dispatch) is a
// ~17us L2-BW floor; split batches (8 then 16 loads) still exposed latency.
// This round: issue ALL 24 fragment loads per ks in one batch, then 32 MFMAs —
// the 8 GAT MFMAs overlap the self-table loads' return.
__launch_bounds__(256)
__global__ void gemm_fused(const float* __restrict__ X, const unsigned short* __restrict__ Wpk,
                           const unsigned short* __restrict__ Sph, const unsigned short* __restrict__ Spl,
                           const float* __restrict__ a0s, const float* __restrict__ a0d,
                           const float* __restrict__ slb,
                           unsigned short* __restrict__ hg, float* __restrict__ hself,
                           float* __restrict__ als, float* __restrict__ ald, int n) {
  const int wave = threadIdx.x >> 6;
  const int lane = threadIdx.x & 63;
  const int nidx = lane & 15, q = lane >> 4;
  const int r0 = blockIdx.x * 64 + wave * 16;
  const int arow = r0 + nidx;

  // preload this lane's full 128B X segment (8 x float4), hoistable
  float4 xr[8];
  if (arow < n) {
    const float* xp = X + (size_t)arow * 128 + q * 8;
#pragma unroll
    for (int ks = 0; ks < 4; ++ks) {
      xr[2 * ks]     = *(const float4*)(xp + ks * 32);
      xr[2 * ks + 1] = *(const float4*)(xp + ks * 32 + 4);
    }
  } else {
#pragma unroll
    for (int j = 0; j < 8; ++j) xr[j] = make_float4(0.f, 0.f, 0.f, 0.f);
  }

  union U { unsigned short u[8]; bf16x8 v; };
  U afh[4], afl[4];
#pragma unroll
  for (int ks = 0; ks < 4; ++ks) {
    float xv[8] = {xr[2 * ks].x, xr[2 * ks].y, xr[2 * ks].z, xr[2 * ks].w,
                   xr[2 * ks + 1].x, xr[2 * ks + 1].y, xr[2 * ks + 1].z, xr[2 * ks + 1].w};
#pragma unroll
    for (int j = 0; j < 8; ++j) {
      unsigned short h = f2bf(xv[j]);
      afh[ks].u[j] = h;
      afl[ks].u[j] = f2bf(xv[j] - bf2f(h));
    }
  }

  f32x4 acc[8], accS[8];
#pragma unroll
  for (int nt = 0; nt < 8; ++nt) {
    acc[nt]  = (f32x4){0.f, 0.f, 0.f, 0.f};
    accS[nt] = (f32x4){0.f, 0.f, 0.f, 0.f};
  }

#pragma unroll
  for (int ks = 0; ks < 4; ++ks) {
    const size_t base = ((size_t)ks * 8 * 64 + lane) * 8;
    const unsigned short* bp = Wpk + base;
    const unsigned short* ph = Sph + base;
    const unsigned short* pl = Spl + base;

    // merged batch: all 24 fragment loads in flight together
    bf16x8 bW[8], bH[8], bL[8];
#pragma unroll
    for (int nt = 0; nt < 8; ++nt) {
      bW[nt] = *(const bf16x8*)(bp + (size_t)nt * 512);
      bH[nt] = *(const bf16x8*)(ph + (size_t)nt * 512);
      bL[nt] = *(const bf16x8*)(pl + (size_t)nt * 512);
    }
    // GAT MFMAs first (only need bW) — overlap bH/bL load returns
#pragma unroll
    for (int nt = 0; nt < 8; ++nt)
      acc[nt] = __builtin_amdgcn_mfma_f32_16x16x32_bf16(afh[ks].v, bW[nt], acc[nt], 0, 0, 0);
#pragma unroll
    for (int nt = 0; nt < 8; ++nt) {
      accS[nt] = __builtin_amdgcn_mfma_f32_16x16x32_bf16(afh[ks].v, bH[nt], accS[nt], 0, 0, 0);
      accS[nt] = __builtin_amdgcn_mfma_f32_16x16x32_bf16(afl[ks].v, bH[nt], accS[nt], 0, 0, 0);
      accS[nt] = __builtin_amdgcn_mfma_f32_16x16x32_bf16(afh[ks].v, bL[nt], accS[nt], 0, 0, 0);
    }
  }

  // epilogue 1: hg (bf16) + rounded values for logits
  float dv[8][4];
#pragma unroll
  for (int nt = 0; nt < 8; ++nt) {
#pragma unroll
    for (int r = 0; r < 4; ++r) {
      unsigned short rb = f2bf(acc[nt][r]);
      dv[nt][r] = bf2f(rb);
      int row = r0 + q * 4 + r;
      if (row < n) hg[(size_t)row * 128 + nt * 16 + nidx] = rb;
    }
  }

  // epilogue 2: hself (f32) + bias
#pragma unroll
  for (int nt = 0; nt < 8; ++nt) {
    const float sb = slb[nt * 16 + nidx];
#pragma unroll
    for (int r = 0; r < 4; ++r) {
      int row = r0 + q * 4 + r;
      if (row < n) hself[(size_t)row * 128 + nt * 16 + nidx] = accS[nt][r] + sb;
    }
  }

  // epilogue 3: logits
  float ps[4] = {0, 0, 0, 0}, pd[4] = {0, 0, 0, 0};
#pragma unroll
  for (int nt = 0; nt < 8; ++nt) {
    float as_ = a0s[nt * 16 + nidx];
    float ad_ = a0d[nt * 16 + nidx];
#pragma unroll
    for (int r = 0; r < 4; ++r) {
      ps[r] = fmaf(dv[nt][r], as_, ps[r]);
      pd[r] = fmaf(dv[nt][r], ad_, pd[r]);
    }
  }
#pragma unroll
  for (int r = 0; r < 4; ++r) {
#pragma unroll
    for (int o = 8; o > 0; o >>= 1) {
      ps[r] += __shfl_xor(ps[r], o, 64);
      pd[r] += __shfl_xor(pd[r], o, 64);
    }
    int row = r0 + q * 4 + r;
    if (nidx == 0 && row < n) { als[row] = ps[r]; ald[row] = pd[r]; }
  }
}

// ---------- head MFMA GEMM: hg[n][128](bf16) = X@[Wmu|Wlv]; batched loads ----------
__launch_bounds__(256)
__global__ void gemm_mfma_head(const float* __restrict__ X, const unsigned short* __restrict__ Wpk,
                               const float* __restrict__ a0s, const float* __restrict__ a0d,
                               const float* __restrict__ a1s, const float* __restrict__ a1d,
                               unsigned short* __restrict__ hg,
                               float* __restrict__ als, float* __restrict__ ald, int n) {
  const int wave = threadIdx.x >> 6;
  const int lane = threadIdx.x & 63;
  const int nidx = lane & 15, q = lane >> 4;
  const int r0 = blockIdx.x * 64 + wave * 16;
  const int arow = r0 + nidx;

  float4 xr[8];
  if (arow < n) {
    const float* xp = X + (size_t)arow * 128 + q * 8;
#pragma unroll
    for (int ks = 0; ks < 4; ++ks) {
      xr[2 * ks]     = *(const float4*)(xp + ks * 32);
      xr[2 * ks + 1] = *(const float4*)(xp + ks * 32 + 4);
    }
  } else {
#pragma unroll
    for (int j = 0; j < 8; ++j) xr[j] = make_float4(0.f, 0.f, 0.f, 0.f);
  }

  union U { unsigned short u[8]; bf16x8 v; };
  U af[4];
#pragma unroll
  for (int ks = 0; ks < 4; ++ks) {
    float xv[8] = {xr[2 * ks].x, xr[2 * ks].y, xr[2 * ks].z, xr[2 * ks].w,
                   xr[2 * ks + 1].x, xr[2 * ks + 1].y, xr[2 * ks + 1].z, xr[2 * ks + 1].w};
#pragma unroll
    for (int j = 0; j < 8; ++j) af[ks].u[j] = f2bf(xv[j]);
  }

  f32x4 acc[8];
#pragma unroll
  for (int nt = 0; nt < 8; ++nt) acc[nt] = (f32x4){0.f, 0.f, 0.f, 0.f};

#pragma unroll
  for (int ks = 0; ks < 4; ++ks) {
    const unsigned short* bp = Wpk + ((size_t)ks * 8 * 64 + lane) * 8;
    bf16x8 bW[8];
#pragma unroll
    for (int nt = 0; nt < 8; ++nt) bW[nt] = *(const bf16x8*)(bp + (size_t)nt * 512);
#pragma unroll
    for (int nt = 0; nt < 8; ++nt)
      acc[nt] = __builtin_amdgcn_mfma_f32_16x16x32_bf16(af[ks].v, bW[nt], acc[nt], 0, 0, 0);
  }

  float dv[8][4];
#pragma unroll
  for (int nt = 0; nt < 8; ++nt) {
#pragma unroll
    for (int r = 0; r < 4; ++r) {
      unsigned short rb = f2bf(acc[nt][r]);
      dv[nt][r] = bf2f(rb);
      int row = r0 + q * 4 + r;
      if (row < n) hg[(size_t)row * 128 + nt * 16 + nidx] = rb;
    }
  }

  float pms[4] = {0, 0, 0, 0}, pmd[4] = {0, 0, 0, 0};
  float pls[4] = {0, 0, 0, 0}, pld[4] = {0, 0, 0, 0};
#pragma unroll
  for (int nt = 0; nt < 4; ++nt) {
    float as_ = a0s[nt * 16 + nidx];
    float ad_ = a0d[nt * 16 + nidx];
#pragma unroll
    for (int r = 0; r < 4; ++r) {
      pms[r] = fmaf(dv[nt][r], as_, pms[r]);
      pmd[r] = fmaf(dv[nt][r], ad_, pmd[r]);
    }
  }
#pragma unroll
  for (int nt = 4; nt < 8; ++nt) {
    float as_ = a1s[(nt - 4) * 16 + nidx];
    float ad_ = a1d[(nt - 4) * 16 + nidx];
#pragma unroll
    for (int r = 0; r < 4; ++r) {
      pls[r] = fmaf(dv[nt][r], as_, pls[r]);
      pld[r] = fmaf(dv[nt][r], ad_, pld[r]);
    }
  }
#pragma unroll
  for (int r = 0; r < 4; ++r) {
#pragma unroll
    for (int o = 8; o > 0; o >>= 1) {
      pms[r] += __shfl_xor(pms[r], o, 64);
      pmd[r] += __shfl_xor(pmd[r], o, 64);
      pls[r] += __shfl_xor(pls[r], o, 64);
      pld[r] += __shfl_xor(pld[r], o, 64);
    }
    int row = r0 + q * 4 + r;
    if (nidx == 0 && row < n) {
      ((float2*)als)[row] = make_float2(pms[r], pls[r]);
      ((float2*)ald)[row] = make_float2(pmd[r], pld[r]);
    }
  }
}

// ---------- layer aggregation (Round-1 structure: best measured 73.5us, occ 72%) ----------
// 16 lanes per node; lane g owns cols g*8..g*8+7; direct exp; ILP-4 gathers.
__launch_bounds__(256)
__global__ void gat_agg3(const unsigned short* __restrict__ hg,
                         const float* __restrict__ als, const float* __restrict__ aldv,
                         const int* __restrict__ rp, const int* __restrict__ col,
                         const float* __restrict__ biasf, float* __restrict__ outv,
                         const float* base, int n, int self_loop, int act) {
  const int node = blockIdx.x * 16 + (threadIdx.x >> 4);
  if (node >= n) return;
  const int g = threadIdx.x & 15;
  const int beg = rp[node];
  const int deg = rp[node + 1] - beg;
  const int total = deg + self_loop;
  const float ad = aldv[node];

  float den = 0.f;
  float acc[8];
#pragma unroll
  for (int k = 0; k < 8; ++k) acc[k] = 0.f;

  const unsigned short* hgl = hg + g * 8;

  for (int cb = 0; cb < total; cb += 16) {
    const int idx = cb + g;
    const bool valid = idx < total;
    int s = node;
    if (valid && idx < deg) s = col[beg + idx];
    float e = 0.f;
    if (valid) {
      float v = als[s] + ad;
      float l = (v > 0.f) ? v : 0.2f * v;  // LeakyReLU(0.2)
      e = __expf(l);
    }

    const int cnt = (total - cb < 16) ? (total - cb) : 16;
    int j = 0;
    for (; j + 4 <= cnt; j += 4) {
      float w[4]; int ss[4]; uint4 rr[4];
#pragma unroll
      for (int u = 0; u < 4; ++u) { w[u] = __shfl(e, j + u, 16); ss[u] = __shfl(s, j + u, 16); }
#pragma unroll
      for (int u = 0; u < 4; ++u) rr[u] = *(const uint4*)(hgl + (size_t)ss[u] * 128);
#pragma unroll
      for (int u = 0; u < 4; ++u) {
        den += w[u];
        acc[0] = fmaf(w[u], __uint_as_float(rr[u].x << 16),        acc[0]);
        acc[1] = fmaf(w[u], __uint_as_float(rr[u].x & 0xFFFF0000u), acc[1]);
        acc[2] = fmaf(w[u], __uint_as_float(rr[u].y << 16),        acc[2]);
        acc[3] = fmaf(w[u], __uint_as_float(rr[u].y & 0xFFFF0000u), acc[3]);
        acc[4] = fmaf(w[u], __uint_as_float(rr[u].z << 16),        acc[4]);
        acc[5] = fmaf(w[u], __uint_as_float(rr[u].z & 0xFFFF0000u), acc[5]);
        acc[6] = fmaf(w[u], __uint_as_float(rr[u].w << 16),        acc[6]);
        acc[7] = fmaf(w[u], __uint_as_float(rr[u].w & 0xFFFF0000u), acc[7]);
      }
    }
    for (; j < cnt; ++j) {
      float wj = __shfl(e, j, 16);
      int sj = __shfl(s, j, 16);
      uint4 raw = *(const uint4*)(hgl + (size_t)sj * 128);
      den += wj;
      acc[0] = fmaf(wj, __uint_as_float(raw.x << 16),        acc[0]);
      acc[1] = fmaf(wj, __uint_as_float(raw.x & 0xFFFF0000u), acc[1]);
      acc[2] = fmaf(wj, __uint_as_float(raw.y << 16),        acc[2]);
      acc[3] = fmaf(wj, __uint_as_float(raw.y & 0xFFFF0000u), acc[3]);
      acc[4] = fmaf(wj, __uint_as_float(raw.z << 16),        acc[4]);
      acc[5] = fmaf(wj, __uint_as_float(raw.z & 0xFFFF0000u), acc[5]);
      acc[6] = fmaf(wj, __uint_as_float(raw.w << 16),        acc[6]);
      acc[7] = fmaf(wj, __uint_as_float(raw.w & 0xFFFF0000u), acc[7]);
    }
  }

  const float inv = 1.f / (den + 1e-16f);
  const size_t o = (size_t)node * 128 + g * 8;
  float4 bv0 = *(const float4*)(biasf + g * 8);
  float4 bv1 = *(const float4*)(biasf + g * 8 + 4);
  float r[8];
  r[0] = acc[0] * inv + bv0.x; r[1] = acc[1] * inv + bv0.y;
  r[2] = acc[2] * inv + bv0.z; r[3] = acc[3] * inv + bv0.w;
  r[4] = acc[4] * inv + bv1.x; r[5] = acc[5] * inv + bv1.y;
  r[6] = acc[6] * inv + bv1.z; r[7] = acc[7] * inv + bv1.w;
  if (base) {
    float4 s0 = *(const float4*)(base + o);
    float4 s1 = *(const float4*)(base + o + 4);
    r[0] += s0.x; r[1] += s0.y; r[2] += s0.z; r[3] += s0.w;
    r[4] += s1.x; r[5] += s1.y; r[6] += s1.z; r[7] += s1.w;
  }
  if (act) {
#pragma unroll
    for (int k = 0; k < 8; ++k) r[k] = (r[k] > 0.f) ? r[k] : 0.01f * r[k];
  }
  *(float4*)(outv + o)     = make_float4(r[0], r[1], r[2], r[3]);
  *(float4*)(outv + o + 4) = make_float4(r[4], r[5], r[6], r[7]);
}

// ---------- dual-head aggregation (Round-1 structure): mu + logvar in ONE pass ----------
__launch_bounds__(256)
__global__ void gat_agg_dual(const unsigned short* __restrict__ hg,
                             const float2* __restrict__ alsH, const float2* __restrict__ aldH,
                             const int* __restrict__ rp, const int* __restrict__ col,
                             const float* __restrict__ bmu, const float* __restrict__ blv,
                             float* __restrict__ outF, int n) {
  const int node = blockIdx.x * 16 + (threadIdx.x >> 4);
  if (node >= n) return;
  const int g = threadIdx.x & 15;
  const bool isMu = g < 8;
  const int beg = rp[node];
  const int deg = rp[node + 1] - beg;
  const int total = deg + 1;  // heads always have self loop
  const float2 ad = aldH[node];

  float den = 0.f;
  float acc[8];
#pragma unroll
  for (int k = 0; k < 8; ++k) acc[k] = 0.f;

  const unsigned short* hgl = hg + g * 8;

  for (int cb = 0; cb < total; cb += 16) {
    const int idx = cb + g;
    const bool valid = idx < total;
    int s = node;
    if (valid && idx < deg) s = col[beg + idx];
    float eM = 0.f, eL = 0.f;
    if (valid) {
      float2 as_ = alsH[s];
      float vm = as_.x + ad.x;
      float vl = as_.y + ad.y;
      eM = __expf((vm > 0.f) ? vm : 0.2f * vm);
      eL = __expf((vl > 0.f) ? vl : 0.2f * vl);
    }

    const int cnt = (total - cb < 16) ? (total - cb) : 16;
    int j = 0;
    for (; j + 4 <= cnt; j += 4) {
      float w[4]; int ss[4]; uint4 rr[4];
#pragma unroll
      for (int u = 0; u < 4; ++u) {
        float wm = __shfl(eM, j + u, 16), wl = __shfl(eL, j + u, 16);
        w[u] = isMu ? wm : wl;
        ss[u] = __shfl(s, j + u, 16);
      }
#pragma unroll
      for (int u = 0; u < 4; ++u) rr[u] = *(const uint4*)(hgl + (size_t)ss[u] * 128);
#pragma unroll
      for (int u = 0; u < 4; ++u) {
        den += w[u];
        acc[0] = fmaf(w[u], __uint_as_float(rr[u].x << 16),        acc[0]);
        acc[1] = fmaf(w[u], __uint_as_float(rr[u].x & 0xFFFF0000u), acc[1]);
        acc[2] = fmaf(w[u], __uint_as_float(rr[u].y << 16),        acc[2]);
        acc[3] = fmaf(w[u], __uint_as_float(rr[u].y & 0xFFFF0000u), acc[3]);
        acc[4] = fmaf(w[u], __uint_as_float(rr[u].z << 16),        acc[4]);
        acc[5] = fmaf(w[u], __uint_as_float(rr[u].z & 0xFFFF0000u), acc[5]);
        acc[6] = fmaf(w[u], __uint_as_float(rr[u].w << 16),        acc[6]);
        acc[7] = fmaf(w[u], __uint_as_float(rr[u].w & 0xFFFF0000u), acc[7]);
      }
    }
    for (; j < cnt; ++j) {
      float wm = __shfl(eM, j, 16), wl = __shfl(eL, j, 16);
      float wj = isMu ? wm : wl;
      int sj = __shfl(s, j, 16);
      uint4 raw = *(const uint4*)(hgl + (size_t)sj * 128);
      den += wj;
      acc[0] = fmaf(wj, __uint_as_float(raw.x << 16),        acc[0]);
      acc[1] = fmaf(wj, __uint_as_float(raw.x & 0xFFFF0000u), acc[1]);
      acc[2] = fmaf(wj, __uint_as_float(raw.y << 16),        acc[2]);
      acc[3] = fmaf(wj, __uint_as_float(raw.y & 0xFFFF0000u), acc[3]);
      acc[4] = fmaf(wj, __uint_as_float(raw.z << 16),        acc[4]);
      acc[5] = fmaf(wj, __uint_as_float(raw.z & 0xFFFF0000u), acc[5]);
      acc[6] = fmaf(wj, __uint_as_float(raw.w << 16),        acc[6]);
      acc[7] = fmaf(wj, __uint_as_float(raw.w & 0xFFFF0000u), acc[7]);
    }
  }

  const float inv = 1.f / (den + 1e-16f);
  const int c = (g & 7) * 8;
  const float* bb = isMu ? bmu : blv;
  float4 bv0 = *(const float4*)(bb + c);
  float4 bv1 = *(const float4*)(bb + c + 4);
  float* op = outF + (isMu ? (size_t)0 : (size_t)n * 64) + (size_t)node * 64 + c;
  *(float4*)op = make_float4(acc[0] * inv + bv0.x, acc[1] * inv + bv0.y,
                             acc[2] * inv + bv0.z, acc[3] * inv + bv0.w);
  *(float4*)(op + 4) = make_float4(acc[4] * inv + bv1.x, acc[5] * inv + bv1.y,
                                   acc[6] * inv + bv1.z, acc[7] * inv + bv1.w);
}

extern "C" void kernel_launch(void* const* d_in, const int* in_sizes, int n_in,
                              void* d_out, int out_size, void* d_ws, size_t ws_size,
                              hipStream_t stream) {
  const int N = in_sizes[0] / 128;   // 100000
  const int E = in_sizes[1] / 2;     // 1600000
  const int W = (N + NB - 1) / NB;   // nodes per bucket (<=1024)

  const float* x    = (const float*)d_in[0];
  const int*   ei   = (const int*)d_in[1];
  const float* W0   = (const float*)d_in[2];
  const float* as0  = (const float*)d_in[3];
  const float* ad0  = (const float*)d_in[4];
  const float* b0   = (const float*)d_in[5];
  const float* slW0 = (const float*)d_in[6];
  const float* slb0 = (const float*)d_in[7];
  const float* W1   = (const float*)d_in[8];
  const float* as1  = (const float*)d_in[9];
  const float* ad1  = (const float*)d_in[10];
  const float* b1   = (const float*)d_in[11];
  const float* slW1 = (const float*)d_in[12];
  const float* slb1 = (const float*)d_in[13];
  const float* Wmu  = (const float*)d_in[14];
  const float* asmu = (const float*)d_in[15];
  const float* admu = (const float*)d_in[16];
  const float* bmu  = (const float*)d_in[17];
  const float* Wlv  = (const float*)d_in[18];
  const float* aslv = (const float*)d_in[19];
  const float* adlv = (const float*)d_in[20];
  const float* blv  = (const float*)d_in[21];

  float*          outF = (float*)d_out;
  unsigned short* hgB  = (unsigned short*)d_out;  // layers' hg lives in d_out (dead before heads write)

  char* w = (char*)d_ws;
  auto carve = [&](size_t bytes) -> char* {
    char* p = w;
    w += (bytes + 255) & ~(size_t)255;
    return p;
  };
  float*          h0    = (float*)carve((size_t)N * 128 * 4);           // 51.2 MB
  unsigned short* hgHd  = (unsigned short*)carve((size_t)N * 128 * 2);  // 25.6 MB
  float*          als   = (float*)carve((size_t)N * 4);
  float*          ald   = (float*)carve((size_t)N * 4);
  float2*         alsH  = (float2*)carve((size_t)N * 8);
  float2*         aldH  = (float2*)carve((size_t)N * 8);
  int*            cnt   = (int*)carve((size_t)N * 4);
  int*            rp    = (int*)carve((size_t)(N + 1) * 4);
  int*            col   = (int*)carve((size_t)E * 4);
  int*            bsum  = (int*)carve(512);
  int*            bhist = (int*)carve(NB * 4);
  int*            boffs = (int*)carve((NB + 1) * 4);
  int*            bcur  = (int*)carve(NB * 4);
  int*            flag  = (int*)carve(4);
  unsigned short* Wpk0  = (unsigned short*)carve(2048 * 8 * 2);
  unsigned short* Wpk1  = (unsigned short*)carve(2048 * 8 * 2);
  unsigned short* Wpkh  = (unsigned short*)carve(2048 * 8 * 2);
  unsigned short* Spk0h = (unsigned short*)carve(2048 * 8 * 2);
  unsigned short* Spk0l = (unsigned short*)carve(2048 * 8 * 2);
  unsigned short* Spk1h = (unsigned short*)carve(2048 * 8 * 2);
  unsigned short* Spk1l = (unsigned short*)carve(2048 * 8 * 2);
  int2*           ebuf  = (int2*)h0;  // alias: h0 dead during CSR build

  const int gE  = (E + 255) / 256;
  const int gB4 = (E + 4095) / 4096;
  const int gG  = (N + 63) / 64;
  const int gW  = (N + 15) / 16;     // 16 nodes per 256-thread block
  const int nb  = (N + 1023) / 1024;

  // --- probe + bucketed CSR build ---
  hipMemsetAsync(flag, 0, 4, stream);
  hipMemsetAsync(cnt, 0, (size_t)N * 4, stream);
  hipMemsetAsync(bhist, 0, NB * 4, stream);
  detect_kernel<<<1, 256, 0, stream>>>(ei, flag);
  hist_kernel<<<gE, 256, 0, stream>>>(ei, flag, cnt, E);
  bucket_hist<<<gB4, 256, 0, stream>>>(ei, flag, bhist, E, W);
  scan_block<<<nb, 256, 0, stream>>>(cnt, rp, bsum, N);
  scan_tops<<<1, 128, 0, stream>>>(bsum, rp, nb, N);
  scan_add<<<nb, 256, 0, stream>>>(rp, bsum, N);
  bucket_scan<<<1, NB, 0, stream>>>(bhist, boffs, bcur);
  bucket_scatter<<<gB4, 256, 0, stream>>>(ei, flag, bcur, ebuf, E, W);
  bucket_fill<<<NB, 256, 0, stream>>>(ebuf, boffs, rp, col, N, W);

  // --- pack weights into MFMA B-fragment order (bf16; self weights hi/lo split) ---
  pack_mfma_b<<<8, 256, 0, stream>>>(W0, Wpk0);
  pack_mfma_b<<<8, 256, 0, stream>>>(W1, Wpk1);
  pack_mfma_b_hilo<<<8, 256, 0, stream>>>(slW0, Spk0h, Spk0l);
  pack_mfma_b_hilo<<<8, 256, 0, stream>>>(slW1, Spk1h, Spk1l);
  pack_mfma_head<<<8, 256, 0, stream>>>(Wmu, Wlv, Wpkh);

  // --- layer 0: one fused MFMA GEMM (hg + logits + self-linear), then fused agg ---
  gemm_fused<<<gG, 256, 0, stream>>>(x, Wpk0, Spk0h, Spk0l, as0, ad0, slb0,
                                     hgB, h0, als, ald, N);
  gat_agg3<<<gW, 256, 0, stream>>>(hgB, als, ald, rp, col, b0, h0, h0, N, 0, 1);

  // --- layer 1 (self loops); reads h0 in its own row band, writes same band ---
  gemm_fused<<<gG, 256, 0, stream>>>(h0, Wpk1, Spk1h, Spk1l, as1, ad1, slb1,
                                     hgB, h0, als, ald, N);
  gat_agg3<<<gW, 256, 0, stream>>>(hgB, als, ald, rp, col, b1, h0, h0, N, 1, 1);

  // --- heads: one merged MFMA GEMM (+both logit pairs), one dual gather pass ---
  gemm_mfma_head<<<gG, 256, 0, stream>>>(h0, Wpkh, asmu, admu, aslv, adlv,
                                         hgHd, (float*)alsH, (float*)aldH, N);
  gat_agg_dual<<<gW, 256, 0, stream>>>(hgHd, alsH, aldH, rp, col, bmu, blv, outF, N);
}

// Round 10
// 645.418 us; speedup vs baseline: 1.0926x; 1.0074x over previous
//
#include <hip/hip_runtime.h>
#include <cstdint>
#include <cstddef>

// ---------- bf16 helpers (OCP bf16 = upper 16 bits of f32) ----------
__device__ __forceinline__ float bf2f(unsigned short u) {
  return __uint_as_float(((unsigned)u) << 16);
}
__device__ __forceinline__ unsigned short f2bf(float f) {
  unsigned u = __float_as_uint(f);
  u = (u + 0x7FFFu + ((u >> 16) & 1u)) >> 16;  // RNE
  return (unsigned short)u;
}

typedef __attribute__((ext_vector_type(8))) short bf16x8;
typedef __attribute__((ext_vector_type(4))) float f32x4;

#define TBL 16384  // shorts per 32KB table copy

// ---------- edge_index layout probe ----------
__global__ void detect_kernel(const int* __restrict__ ei, int* __restrict__ flag) {
  int any = 0;
  for (int j = threadIdx.x; j < 4096; j += 256) any |= (ei[2 * j + 1] != 0);
  if (any) atomicOr(flag, 1);  // 1 => int32 layout
}

__device__ __forceinline__ int edge_src(const int* ei, int f, int e, int i) {
  return f ? ei[i] : ei[2 * (size_t)i];
}
__device__ __forceinline__ int edge_dst(const int* ei, int f, int e, int i) {
  return f ? ei[(size_t)e + i] : ei[2 * (size_t)e + 2 * (size_t)i];
}

// ---------- per-node degree histogram ----------
__global__ void hist_kernel(const int* __restrict__ ei, const int* __restrict__ flag,
                            int* __restrict__ cnt, int e) {
  int i = blockIdx.x * blockDim.x + threadIdx.x;
  if (i < e) atomicAdd(&cnt[edge_dst(ei, *flag, e, i)], 1);
}

// two-level scan for rp
__global__ void scan_block(const int* __restrict__ cnt, int* __restrict__ rp,
                           int* __restrict__ bsum, int n) {
  __shared__ int lds[256];
  const int t = threadIdx.x;
  const int base = blockIdx.x * 1024 + t * 4;
  int v0 = (base     < n) ? cnt[base]     : 0;
  int v1 = (base + 1 < n) ? cnt[base + 1] : 0;
  int v2 = (base + 2 < n) ? cnt[base + 2] : 0;
  int v3 = (base + 3 < n) ? cnt[base + 3] : 0;
  int s = v0 + v1 + v2 + v3;
  lds[t] = s;
  __syncthreads();
  for (int off = 1; off < 256; off <<= 1) {
    int y = (t >= off) ? lds[t - off] : 0;
    __syncthreads();
    lds[t] += y;
    __syncthreads();
  }
  int excl = lds[t] - s;
  if (base     < n) rp[base]     = excl;
  if (base + 1 < n) rp[base + 1] = excl + v0;
  if (base + 2 < n) rp[base + 2] = excl + v0 + v1;
  if (base + 3 < n) rp[base + 3] = excl + v0 + v1 + v2;
  if (t == 255) bsum[blockIdx.x] = lds[255];
}

__global__ void scan_tops(int* __restrict__ bsum, int* __restrict__ rp, int nb, int n) {
  __shared__ int lds[128];
  const int t = threadIdx.x;
  int v = (t < nb) ? bsum[t] : 0;
  lds[t] = v;
  __syncthreads();
  for (int off = 1; off < 128; off <<= 1) {
    int y = (t >= off) ? lds[t - off] : 0;
    __syncthreads();
    lds[t] += y;
    __syncthreads();
  }
  if (t < nb) bsum[t] = lds[t] - v;
  if (t == 127) rp[n] = lds[127];
}

__global__ void scan_add(int* __restrict__ rp, const int* __restrict__ bsum, int n) {
  const int base = blockIdx.x * 1024 + threadIdx.x * 4;
  const int add = bsum[blockIdx.x];
#pragma unroll
  for (int i = 0; i < 4; ++i)
    if (base + i < n) rp[base + i] += add;
}

// ---------- bucketed CSR fill ----------
#define NB 128

__global__ void bucket_hist(const int* __restrict__ ei, const int* __restrict__ flag,
                            int* __restrict__ bhist, int e, int W) {
  __shared__ int lh[NB];
  const int t = threadIdx.x;
  if (t < NB) lh[t] = 0;
  __syncthreads();
  const int base = blockIdx.x * 4096;
  const int f = *flag;
  for (int j = t; j < 4096; j += 256) {
    int i = base + j;
    if (i < e) atomicAdd(&lh[edge_dst(ei, f, e, i) / W], 1);
  }
  __syncthreads();
  if (t < NB && lh[t]) atomicAdd(&bhist[t], lh[t]);
}

__global__ void bucket_scan(const int* __restrict__ bhist, int* __restrict__ boffs,
                            int* __restrict__ bcur) {
  __shared__ int lds[NB];
  const int t = threadIdx.x;
  int v = bhist[t];
  lds[t] = v;
  __syncthreads();
  for (int off = 1; off < NB; off <<= 1) {
    int y = (t >= off) ? lds[t - off] : 0;
    __syncthreads();
    lds[t] += y;
    __syncthreads();
  }
  int excl = lds[t] - v;
  boffs[t] = excl;
  bcur[t] = excl;
  if (t == NB - 1) boffs[NB] = lds[NB - 1];
}

__global__ void bucket_scatter(const int* __restrict__ ei, const int* __restrict__ flag,
                               int* __restrict__ bcur, int2* __restrict__ ebuf,
                               int e, int W) {
  __shared__ int lh[NB];
  __shared__ int lbase[NB];
  const int t = threadIdx.x;
  if (t < NB) lh[t] = 0;
  __syncthreads();
  const int base = blockIdx.x * 4096;
  const int f = *flag;
  for (int j = t; j < 4096; j += 256) {
    int i = base + j;
    if (i < e) atomicAdd(&lh[edge_dst(ei, f, e, i) / W], 1);
  }
  __syncthreads();
  if (t < NB) {
    lbase[t] = lh[t] ? atomicAdd(&bcur[t], lh[t]) : 0;
    lh[t] = 0;
  }
  __syncthreads();
  for (int j = t; j < 4096; j += 256) {
    int i = base + j;
    if (i < e) {
      int d = edge_dst(ei, f, e, i);
      int s = edge_src(ei, f, e, i);
      int b = d / W;
      int off = atomicAdd(&lh[b], 1);
      ebuf[lbase[b] + off] = make_int2(s, d);
    }
  }
}

__global__ void bucket_fill(const int2* __restrict__ ebuf, const int* __restrict__ boffs,
                            const int* __restrict__ rp, int* __restrict__ col,
                            int n, int W) {
  __shared__ int cur[1024];
  const int b = blockIdx.x;
  const int lo = b * W;
  const int nn = min(W, n - lo);
  if (nn <= 0) return;
  for (int i = threadIdx.x; i < nn; i += 256) cur[i] = rp[lo + i];
  __syncthreads();
  const int beg = boffs[b], end = boffs[b + 1];
  for (int p = beg + threadIdx.x; p < end; p += 256) {
    int2 sd = ebuf[p];
    int pos = atomicAdd(&cur[sd.y - lo], 1);
    col[pos] = sd.x;
  }
}

// ---------- pack W[128][128] f32 into MFMA B-fragment order (bf16), x8 replicated ----------
// 8 copies: gemm blocks index copy (blockIdx&7) ~= XCD id (round-robin dispatch),
// so each XCD's CUs read a private copy from their own L2 (kills hot-line contention).
__global__ void pack_mfma_b(const float* __restrict__ Wf, unsigned short* __restrict__ Wpk) {
  int i = blockIdx.x * 256 + threadIdx.x;  // 2048
  if (i >= 2048) return;
  int lane = i & 63, nt = (i >> 6) & 7, ks = i >> 9;
  int nn = lane & 15, q = lane >> 4;
  int k0 = ks * 32 + q * 8, col = nt * 16 + nn;
  unsigned short o[8];
#pragma unroll
  for (int j = 0; j < 8; ++j) o[j] = f2bf(Wf[(size_t)(k0 + j) * 128 + col]);
  uint4 u;
  u.x = (unsigned)o[0] | ((unsigned)o[1] << 16);
  u.y = (unsigned)o[2] | ((unsigned)o[3] << 16);
  u.z = (unsigned)o[4] | ((unsigned)o[5] << 16);
  u.w = (unsigned)o[6] | ((unsigned)o[7] << 16);
#pragma unroll
  for (int c = 0; c < 8; ++c)
    *(uint4*)(Wpk + (size_t)c * TBL + (size_t)i * 8) = u;
}

// hi/lo split pack for the self-linear weight: Hi = bf16(W), Lo = bf16(W - Hi); x8 replicated
__global__ void pack_mfma_b_hilo(const float* __restrict__ Wf,
                                 unsigned short* __restrict__ Hi,
                                 unsigned short* __restrict__ Lo) {
  int i = blockIdx.x * 256 + threadIdx.x;  // 2048
  if (i >= 2048) return;
  int lane = i & 63, nt = (i >> 6) & 7, ks = i >> 9;
  int nn = lane & 15, q = lane >> 4;
  int k0 = ks * 32 + q * 8, col = nt * 16 + nn;
  unsigned short oh[8], ol[8];
#pragma unroll
  for (int j = 0; j < 8; ++j) {
    float v = Wf[(size_t)(k0 + j) * 128 + col];
    unsigned short h = f2bf(v);
    oh[j] = h;
    ol[j] = f2bf(v - bf2f(h));
  }
  uint4 uh, ul;
  uh.x = (unsigned)oh[0] | ((unsigned)oh[1] << 16);
  uh.y = (unsigned)oh[2] | ((unsigned)oh[3] << 16);
  uh.z = (unsigned)oh[4] | ((unsigned)oh[5] << 16);
  uh.w = (unsigned)oh[6] | ((unsigned)oh[7] << 16);
  ul.x = (unsigned)ol[0] | ((unsigned)ol[1] << 16);
  ul.y = (unsigned)ol[2] | ((unsigned)ol[3] << 16);
  ul.z = (unsigned)ol[4] | ((unsigned)ol[5] << 16);
  ul.w = (unsigned)ol[6] | ((unsigned)ol[7] << 16);
#pragma unroll
  for (int c = 0; c < 8; ++c) {
    *(uint4*)(Hi + (size_t)c * TBL + (size_t)i * 8) = uh;
    *(uint4*)(Lo + (size_t)c * TBL + (size_t)i * 8) = ul;
  }
}

// heads: merged [Wmu | Wlv], each [128][64] f32; x8 replicated
__global__ void pack_mfma_head(const float* __restrict__ Wmu, const float* __restrict__ Wlv,
                               unsigned short* __restrict__ Wpk) {
  int i = blockIdx.x * 256 + threadIdx.x;  // 2048
  if (i >= 2048) return;
  int lane = i & 63, nt = (i >> 6) & 7, ks = i >> 9;
  int nn = lane & 15, q = lane >> 4;
  int k0 = ks * 32 + q * 8, col = nt * 16 + nn;
  unsigned short o[8];
#pragma unroll
  for (int j = 0; j < 8; ++j) {
    float v = (col < 64) ? Wmu[(size_t)(k0 + j) * 64 + col]
                         : Wlv[(size_t)(k0 + j) * 64 + (col - 64)];
    o[j] = f2bf(v);
  }
  uint4 u;
  u.x = (unsigned)o[0] | ((unsigned)o[1] << 16);
  u.y = (unsigned)o[2] | ((unsigned)o[3] << 16);
  u.z = (unsigned)o[4] | ((unsigned)o[5] << 16);
  u.w = (unsigned)o[6] | ((unsigned)o[7] << 16);
#pragma unroll
  for (int c = 0; c < 8; ++c)
    *(uint4*)(Wpk + (size_t)c * TBL + (size_t)i * 8) = u;
}

// ---------- fused layer GEMM (matrix pipe; per-XCD table copy) ----------
// hg[n][128](bf16) = X@W ; hself[n][128](f32) = X@slW + slb (hi/lo split);
// als/ald logits from rounded hg values. Table copy chosen by blockIdx&7.
__launch_bounds__(256)
__global__ void gemm_fused(const float* __restrict__ X, const unsigned short* __restrict__ Wpk,
                           const unsigned short* __restrict__ Sph, const unsigned short* __restrict__ Spl,
                           const float* __restrict__ a0s, const float* __restrict__ a0d,
                           const float* __restrict__ slb,
                           unsigned short* __restrict__ hg, float* __restrict__ hself,
                           float* __restrict__ als, float* __restrict__ ald, int n) {
  const int wave = threadIdx.x >> 6;
  const int lane = threadIdx.x & 63;
  const int nidx = lane & 15, q = lane >> 4;
  const int r0 = blockIdx.x * 64 + wave * 16;
  const int arow = r0 + nidx;
  const size_t rep = (size_t)(blockIdx.x & 7) * TBL;

  // preload this lane's full 128B X segment (8 x float4), hoistable
  float4 xr[8];
  if (arow < n) {
    const float* xp = X + (size_t)arow * 128 + q * 8;
#pragma unroll
    for (int ks = 0; ks < 4; ++ks) {
      xr[2 * ks]     = *(const float4*)(xp + ks * 32);
      xr[2 * ks + 1] = *(const float4*)(xp + ks * 32 + 4);
    }
  } else {
#pragma unroll
    for (int j = 0; j < 8; ++j) xr[j] = make_float4(0.f, 0.f, 0.f, 0.f);
  }

  union U { unsigned short u[8]; bf16x8 v; };
  U afh[4], afl[4];
#pragma unroll
  for (int ks = 0; ks < 4; ++ks) {
    float xv[8] = {xr[2 * ks].x, xr[2 * ks].y, xr[2 * ks].z, xr[2 * ks].w,
                   xr[2 * ks + 1].x, xr[2 * ks + 1].y, xr[2 * ks + 1].z, xr[2 * ks + 1].w};
#pragma unroll
    for (int j = 0; j < 8; ++j) {
      unsigned short h = f2bf(xv[j]);
      afh[ks].u[j] = h;
      afl[ks].u[j] = f2bf(xv[j] - bf2f(h));
    }
  }

  f32x4 acc[8], accS[8];
#pragma unroll
  for (int nt = 0; nt < 8; ++nt) {
    acc[nt]  = (f32x4){0.f, 0.f, 0.f, 0.f};
    accS[nt] = (f32x4){0.f, 0.f, 0.f, 0.f};
  }

#pragma unroll
  for (int ks = 0; ks < 4; ++ks) {
    const size_t base = rep + ((size_t)ks * 8 * 64 + lane) * 8;
    const unsigned short* bp = Wpk + base;
    const unsigned short* ph = Sph + base;
    const unsigned short* pl = Spl + base;

    // merged batch: all 24 fragment loads issued together
    bf16x8 bW[8], bH[8], bL[8];
#pragma unroll
    for (int nt = 0; nt < 8; ++nt) {
      bW[nt] = *(const bf16x8*)(bp + (size_t)nt * 512);
      bH[nt] = *(const bf16x8*)(ph + (size_t)nt * 512);
      bL[nt] = *(const bf16x8*)(pl + (size_t)nt * 512);
    }
    // GAT MFMAs first (only need bW) — overlap bH/bL load returns
#pragma unroll
    for (int nt = 0; nt < 8; ++nt)
      acc[nt] = __builtin_amdgcn_mfma_f32_16x16x32_bf16(afh[ks].v, bW[nt], acc[nt], 0, 0, 0);
#pragma unroll
    for (int nt = 0; nt < 8; ++nt) {
      accS[nt] = __builtin_amdgcn_mfma_f32_16x16x32_bf16(afh[ks].v, bH[nt], accS[nt], 0, 0, 0);
      accS[nt] = __builtin_amdgcn_mfma_f32_16x16x32_bf16(afl[ks].v, bH[nt], accS[nt], 0, 0, 0);
      accS[nt] = __builtin_amdgcn_mfma_f32_16x16x32_bf16(afh[ks].v, bL[nt], accS[nt], 0, 0, 0);
    }
  }

  // epilogue 1: hg (bf16) + rounded values for logits
  float dv[8][4];
#pragma unroll
  for (int nt = 0; nt < 8; ++nt) {
#pragma unroll
    for (int r = 0; r < 4; ++r) {
      unsigned short rb = f2bf(acc[nt][r]);
      dv[nt][r] = bf2f(rb);
      int row = r0 + q * 4 + r;
      if (row < n) hg[(size_t)row * 128 + nt * 16 + nidx] = rb;
    }
  }

  // epilogue 2: hself (f32) + bias
#pragma unroll
  for (int nt = 0; nt < 8; ++nt) {
    const float sb = slb[nt * 16 + nidx];
#pragma unroll
    for (int r = 0; r < 4; ++r) {
      int row = r0 + q * 4 + r;
      if (row < n) hself[(size_t)row * 128 + nt * 16 + nidx] = accS[nt][r] + sb;
    }
  }

  // epilogue 3: logits
  float ps[4] = {0, 0, 0, 0}, pd[4] = {0, 0, 0, 0};
#pragma unroll
  for (int nt = 0; nt < 8; ++nt) {
    float as_ = a0s[nt * 16 + nidx];
    float ad_ = a0d[nt * 16 + nidx];
#pragma unroll
    for (int r = 0; r < 4; ++r) {
      ps[r] = fmaf(dv[nt][r], as_, ps[r]);
      pd[r] = fmaf(dv[nt][r], ad_, pd[r]);
    }
  }
#pragma unroll
  for (int r = 0; r < 4; ++r) {
#pragma unroll
    for (int o = 8; o > 0; o >>= 1) {
      ps[r] += __shfl_xor(ps[r], o, 64);
      pd[r] += __shfl_xor(pd[r], o, 64);
    }
    int row = r0 + q * 4 + r;
    if (nidx == 0 && row < n) { als[row] = ps[r]; ald[row] = pd[r]; }
  }
}

// ---------- head MFMA GEMM: hg[n][128](bf16) = X@[Wmu|Wlv]; per-XCD table copy ----------
__launch_bounds__(256)
__global__ void gemm_mfma_head(const float* __restrict__ X, const unsigned short* __restrict__ Wpk,
                               const float* __restrict__ a0s, const float* __restrict__ a0d,
                               const float* __restrict__ a1s, const float* __restrict__ a1d,
                               unsigned short* __restrict__ hg,
                               float* __restrict__ als, float* __restrict__ ald, int n) {
  const int wave = threadIdx.x >> 6;
  const int lane = threadIdx.x & 63;
  const int nidx = lane & 15, q = lane >> 4;
  const int r0 = blockIdx.x * 64 + wave * 16;
  const int arow = r0 + nidx;
  const size_t rep = (size_t)(blockIdx.x & 7) * TBL;

  float4 xr[8];
  if (arow < n) {
    const float* xp = X + (size_t)arow * 128 + q * 8;
#pragma unroll
    for (int ks = 0; ks < 4; ++ks) {
      xr[2 * ks]     = *(const float4*)(xp + ks * 32);
      xr[2 * ks + 1] = *(const float4*)(xp + ks * 32 + 4);
    }
  } else {
#pragma unroll
    for (int j = 0; j < 8; ++j) xr[j] = make_float4(0.f, 0.f, 0.f, 0.f);
  }

  union U { unsigned short u[8]; bf16x8 v; };
  U af[4];
#pragma unroll
  for (int ks = 0; ks < 4; ++ks) {
    float xv[8] = {xr[2 * ks].x, xr[2 * ks].y, xr[2 * ks].z, xr[2 * ks].w,
                   xr[2 * ks + 1].x, xr[2 * ks + 1].y, xr[2 * ks + 1].z, xr[2 * ks + 1].w};
#pragma unroll
    for (int j = 0; j < 8; ++j) af[ks].u[j] = f2bf(xv[j]);
  }

  f32x4 acc[8];
#pragma unroll
  for (int nt = 0; nt < 8; ++nt) acc[nt] = (f32x4){0.f, 0.f, 0.f, 0.f};

#pragma unroll
  for (int ks = 0; ks < 4; ++ks) {
    const unsigned short* bp = Wpk + rep + ((size_t)ks * 8 * 64 + lane) * 8;
    bf16x8 bW[8];
#pragma unroll
    for (int nt = 0; nt < 8; ++nt) bW[nt] = *(const bf16x8*)(bp + (size_t)nt * 512);
#pragma unroll
    for (int nt = 0; nt < 8; ++nt)
      acc[nt] = __builtin_amdgcn_mfma_f32_16x16x32_bf16(af[ks].v, bW[nt], acc[nt], 0, 0, 0);
  }

  float dv[8][4];
#pragma unroll
  for (int nt = 0; nt < 8; ++nt) {
#pragma unroll
    for (int r = 0; r < 4; ++r) {
      unsigned short rb = f2bf(acc[nt][r]);
      dv[nt][r] = bf2f(rb);
      int row = r0 + q * 4 + r;
      if (row < n) hg[(size_t)row * 128 + nt * 16 + nidx] = rb;
    }
  }

  float pms[4] = {0, 0, 0, 0}, pmd[4] = {0, 0, 0, 0};
  float pls[4] = {0, 0, 0, 0}, pld[4] = {0, 0, 0, 0};
#pragma unroll
  for (int nt = 0; nt < 4; ++nt) {
    float as_ = a0s[nt * 16 + nidx];
    float ad_ = a0d[nt * 16 + nidx];
#pragma unroll
    for (int r = 0; r < 4; ++r) {
      pms[r] = fmaf(dv[nt][r], as_, pms[r]);
      pmd[r] = fmaf(dv[nt][r], ad_, pmd[r]);
    }
  }
#pragma unroll
  for (int nt = 4; nt < 8; ++nt) {
    float as_ = a1s[(nt - 4) * 16 + nidx];
    float ad_ = a1d[(nt - 4) * 16 + nidx];
#pragma unroll
    for (int r = 0; r < 4; ++r) {
      pls[r] = fmaf(dv[nt][r], as_, pls[r]);
      pld[r] = fmaf(dv[nt][r], ad_, pld[r]);
    }
  }
#pragma unroll
  for (int r = 0; r < 4; ++r) {
#pragma unroll
    for (int o = 8; o > 0; o >>= 1) {
      pms[r] += __shfl_xor(pms[r], o, 64);
      pmd[r] += __shfl_xor(pmd[r], o, 64);
      pls[r] += __shfl_xor(pls[r], o, 64);
      pld[r] += __shfl_xor(pld[r], o, 64);
    }
    int row = r0 + q * 4 + r;
    if (nidx == 0 && row < n) {
      ((float2*)als)[row] = make_float2(pms[r], pls[r]);
      ((float2*)ald)[row] = make_float2(pmd[r], pld[r]);
    }
  }
}

// ---------- layer aggregation (Round-1 structure: 73.5us, occ 70%) ----------
// 16 lanes per node; lane g owns cols g*8..g*8+7; direct exp; ILP-4 gathers.
__launch_bounds__(256)
__global__ void gat_agg3(const unsigned short* __restrict__ hg,
                         const float* __restrict__ als, const float* __restrict__ aldv,
                         const int* __restrict__ rp, const int* __restrict__ col,
                         const float* __restrict__ biasf, float* __restrict__ outv,
                         const float* base, int n, int self_loop, int act) {
  const int node = blockIdx.x * 16 + (threadIdx.x >> 4);
  if (node >= n) return;
  const int g = threadIdx.x & 15;
  const int beg = rp[node];
  const int deg = rp[node + 1] - beg;
  const int total = deg + self_loop;
  const float ad = aldv[node];

  float den = 0.f;
  float acc[8];
#pragma unroll
  for (int k = 0; k < 8; ++k) acc[k] = 0.f;

  const unsigned short* hgl = hg + g * 8;

  for (int cb = 0; cb < total; cb += 16) {
    const int idx = cb + g;
    const bool valid = idx < total;
    int s = node;
    if (valid && idx < deg) s = col[beg + idx];
    float e = 0.f;
    if (valid) {
      float v = als[s] + ad;
      float l = (v > 0.f) ? v : 0.2f * v;  // LeakyReLU(0.2)
      e = __expf(l);
    }

    const int cnt = (total - cb < 16) ? (total - cb) : 16;
    int j = 0;
    for (; j + 4 <= cnt; j += 4) {
      float w[4]; int ss[4]; uint4 rr[4];
#pragma unroll
      for (int u = 0; u < 4; ++u) { w[u] = __shfl(e, j + u, 16); ss[u] = __shfl(s, j + u, 16); }
#pragma unroll
      for (int u = 0; u < 4; ++u) rr[u] = *(const uint4*)(hgl + (size_t)ss[u] * 128);
#pragma unroll
      for (int u = 0; u < 4; ++u) {
        den += w[u];
        acc[0] = fmaf(w[u], __uint_as_float(rr[u].x << 16),        acc[0]);
        acc[1] = fmaf(w[u], __uint_as_float(rr[u].x & 0xFFFF0000u), acc[1]);
        acc[2] = fmaf(w[u], __uint_as_float(rr[u].y << 16),        acc[2]);
        acc[3] = fmaf(w[u], __uint_as_float(rr[u].y & 0xFFFF0000u), acc[3]);
        acc[4] = fmaf(w[u], __uint_as_float(rr[u].z << 16),        acc[4]);
        acc[5] = fmaf(w[u], __uint_as_float(rr[u].z & 0xFFFF0000u), acc[5]);
        acc[6] = fmaf(w[u], __uint_as_float(rr[u].w << 16),        acc[6]);
        acc[7] = fmaf(w[u], __uint_as_float(rr[u].w & 0xFFFF0000u), acc[7]);
      }
    }
    for (; j < cnt; ++j) {
      float wj = __shfl(e, j, 16);
      int sj = __shfl(s, j, 16);
      uint4 raw = *(const uint4*)(hgl + (size_t)sj * 128);
      den += wj;
      acc[0] = fmaf(wj, __uint_as_float(raw.x << 16),        acc[0]);
      acc[1] = fmaf(wj, __uint_as_float(raw.x & 0xFFFF0000u), acc[1]);
      acc[2] = fmaf(wj, __uint_as_float(raw.y << 16),        acc[2]);
      acc[3] = fmaf(wj, __uint_as_float(raw.y & 0xFFFF0000u), acc[3]);
      acc[4] = fmaf(wj, __uint_as_float(raw.z << 16),        acc[4]);
      acc[5] = fmaf(wj, __uint_as_float(raw.z & 0xFFFF0000u), acc[5]);
      acc[6] = fmaf(wj, __uint_as_float(raw.w << 16),        acc[6]);
      acc[7] = fmaf(wj, __uint_as_float(raw.w & 0xFFFF0000u), acc[7]);
    }
  }

  const float inv = 1.f / (den + 1e-16f);
  const size_t o = (size_t)node * 128 + g * 8;
  float4 bv0 = *(const float4*)(biasf + g * 8);
  float4 bv1 = *(const float4*)(biasf + g * 8 + 4);
  float r[8];
  r[0] = acc[0] * inv + bv0.x; r[1] = acc[1] * inv + bv0.y;
  r[2] = acc[2] * inv + bv0.z; r[3] = acc[3] * inv + bv0.w;
  r[4] = acc[4] * inv + bv1.x; r[5] = acc[5] * inv + bv1.y;
  r[6] = acc[6] * inv + bv1.z; r[7] = acc[7] * inv + bv1.w;
  if (base) {
    float4 s0 = *(const float4*)(base + o);
    float4 s1 = *(const float4*)(base + o + 4);
    r[0] += s0.x; r[1] += s0.y; r[2] += s0.z; r[3] += s0.w;
    r[4] += s1.x; r[5] += s1.y; r[6] += s1.z; r[7] += s1.w;
  }
  if (act) {
#pragma unroll
    for (int k = 0; k < 8; ++k) r[k] = (r[k] > 0.f) ? r[k] : 0.01f * r[k];
  }
  *(float4*)(outv + o)     = make_float4(r[0], r[1], r[2], r[3]);
  *(float4*)(outv + o + 4) = make_float4(r[4], r[5], r[6], r[7]);
}

// ---------- dual-head aggregation (Round-1 structure): mu + logvar in ONE pass ----------
__launch_bounds__(256)
__global__ void gat_agg_dual(const unsigned short* __restrict__ hg,
                             const float2* __restrict__ alsH, const float2* __restrict__ aldH,
                             const int* __restrict__ rp, const int* __restrict__ col,
                             const float* __restrict__ bmu, const float* __restrict__ blv,
                             float* __restrict__ outF, int n) {
  const int node = blockIdx.x * 16 + (threadIdx.x >> 4);
  if (node >= n) return;
  const int g = threadIdx.x & 15;
  const bool isMu = g < 8;
  const int beg = rp[node];
  const int deg = rp[node + 1] - beg;
  const int total = deg + 1;  // heads always have self loop
  const float2 ad = aldH[node];

  float den = 0.f;
  float acc[8];
#pragma unroll
  for (int k = 0; k < 8; ++k) acc[k] = 0.f;

  const unsigned short* hgl = hg + g * 8;

  for (int cb = 0; cb < total; cb += 16) {
    const int idx = cb + g;
    const bool valid = idx < total;
    int s = node;
    if (valid && idx < deg) s = col[beg + idx];
    float eM = 0.f, eL = 0.f;
    if (valid) {
      float2 as_ = alsH[s];
      float vm = as_.x + ad.x;
      float vl = as_.y + ad.y;
      eM = __expf((vm > 0.f) ? vm : 0.2f * vm);
      eL = __expf((vl > 0.f) ? vl : 0.2f * vl);
    }

    const int cnt = (total - cb < 16) ? (total - cb) : 16;
    int j = 0;
    for (; j + 4 <= cnt; j += 4) {
      float w[4]; int ss[4]; uint4 rr[4];
#pragma unroll
      for (int u = 0; u < 4; ++u) {
        float wm = __shfl(eM, j + u, 16), wl = __shfl(eL, j + u, 16);
        w[u] = isMu ? wm : wl;
        ss[u] = __shfl(s, j + u, 16);
      }
#pragma unroll
      for (int u = 0; u < 4; ++u) rr[u] = *(const uint4*)(hgl + (size_t)ss[u] * 128);
#pragma unroll
      for (int u = 0; u < 4; ++u) {
        den += w[u];
        acc[0] = fmaf(w[u], __uint_as_float(rr[u].x << 16),        acc[0]);
        acc[1] = fmaf(w[u], __uint_as_float(rr[u].x & 0xFFFF0000u), acc[1]);
        acc[2] = fmaf(w[u], __uint_as_float(rr[u].y << 16),        acc[2]);
        acc[3] = fmaf(w[u], __uint_as_float(rr[u].y & 0xFFFF0000u), acc[3]);
        acc[4] = fmaf(w[u], __uint_as_float(rr[u].z << 16),        acc[4]);
        acc[5] = fmaf(w[u], __uint_as_float(rr[u].z & 0xFFFF0000u), acc[5]);
        acc[6] = fmaf(w[u], __uint_as_float(rr[u].w << 16),        acc[6]);
        acc[7] = fmaf(w[u], __uint_as_float(rr[u].w & 0xFFFF0000u), acc[7]);
      }
    }
    for (; j < cnt; ++j) {
      float wm = __shfl(eM, j, 16), wl = __shfl(eL, j, 16);
      float wj = isMu ? wm : wl;
      int sj = __shfl(s, j, 16);
      uint4 raw = *(const uint4*)(hgl + (size_t)sj * 128);
      den += wj;
      acc[0] = fmaf(wj, __uint_as_float(raw.x << 16),        acc[0]);
      acc[1] = fmaf(wj, __uint_as_float(raw.x & 0xFFFF0000u), acc[1]);
      acc[2] = fmaf(wj, __uint_as_float(raw.y << 16),        acc[2]);
      acc[3] = fmaf(wj, __uint_as_float(raw.y & 0xFFFF0000u), acc[3]);
      acc[4] = fmaf(wj, __uint_as_float(raw.z << 16),        acc[4]);
      acc[5] = fmaf(wj, __uint_as_float(raw.z & 0xFFFF0000u), acc[5]);
      acc[6] = fmaf(wj, __uint_as_float(raw.w << 16),        acc[6]);
      acc[7] = fmaf(wj, __uint_as_float(raw.w & 0xFFFF0000u), acc[7]);
    }
  }

  const float inv = 1.f / (den + 1e-16f);
  const int c = (g & 7) * 8;
  const float* bb = isMu ? bmu : blv;
  float4 bv0 = *(const float4*)(bb + c);
  float4 bv1 = *(const float4*)(bb + c + 4);
  float* op = outF + (isMu ? (size_t)0 : (size_t)n * 64) + (size_t)node * 64 + c;
  *(float4*)op = make_float4(acc[0] * inv + bv0.x, acc[1] * inv + bv0.y,
                             acc[2] * inv + bv0.z, acc[3] * inv + bv0.w);
  *(float4*)(op + 4) = make_float4(acc[4] * inv + bv1.x, acc[5] * inv + bv1.y,
                                   acc[6] * inv + bv1.z, acc[7] * inv + bv1.w);
}

extern "C" void kernel_launch(void* const* d_in, const int* in_sizes, int n_in,
                              void* d_out, int out_size, void* d_ws, size_t ws_size,
                              hipStream_t stream) {
  const int N = in_sizes[0] / 128;   // 100000
  const int E = in_sizes[1] / 2;     // 1600000
  const int W = (N + NB - 1) / NB;   // nodes per bucket (<=1024)

  const float* x    = (const float*)d_in[0];
  const int*   ei   = (const int*)d_in[1];
  const float* W0   = (const float*)d_in[2];
  const float* as0  = (const float*)d_in[3];
  const float* ad0  = (const float*)d_in[4];
  const float* b0   = (const float*)d_in[5];
  const float* slW0 = (const float*)d_in[6];
  const float* slb0 = (const float*)d_in[7];
  const float* W1   = (const float*)d_in[8];
  const float* as1  = (const float*)d_in[9];
  const float* ad1  = (const float*)d_in[10];
  const float* b1   = (const float*)d_in[11];
  const float* slW1 = (const float*)d_in[12];
  const float* slb1 = (const float*)d_in[13];
  const float* Wmu  = (const float*)d_in[14];
  const float* asmu = (const float*)d_in[15];
  const float* admu = (const float*)d_in[16];
  const float* bmu  = (const float*)d_in[17];
  const float* Wlv  = (const float*)d_in[18];
  const float* aslv = (const float*)d_in[19];
  const float* adlv = (const float*)d_in[20];
  const float* blv  = (const float*)d_in[21];

  float*          outF = (float*)d_out;
  unsigned short* hgB  = (unsigned short*)d_out;  // layers' hg lives in d_out (dead before heads write)

  char* w = (char*)d_ws;
  auto carve = [&](size_t bytes) -> char* {
    char* p = w;
    w += (bytes + 255) & ~(size_t)255;
    return p;
  };
  float*          h0    = (float*)carve((size_t)N * 128 * 4);           // 51.2 MB
  unsigned short* hgHd  = (unsigned short*)carve((size_t)N * 128 * 2);  // 25.6 MB
  float*          als   = (float*)carve((size_t)N * 4);
  float*          ald   = (float*)carve((size_t)N * 4);
  float2*         alsH  = (float2*)carve((size_t)N * 8);
  float2*         aldH  = (float2*)carve((size_t)N * 8);
  int*            cnt   = (int*)carve((size_t)N * 4);
  int*            rp    = (int*)carve((size_t)(N + 1) * 4);
  int*            col   = (int*)carve((size_t)E * 4);
  int*            bsum  = (int*)carve(512);
  int*            bhist = (int*)carve(NB * 4);
  int*            boffs = (int*)carve((NB + 1) * 4);
  int*            bcur  = (int*)carve(NB * 4);
  int*            flag  = (int*)carve(4);
  unsigned short* Wpk0  = (unsigned short*)carve((size_t)8 * TBL * 2);  // x8 copies
  unsigned short* Wpk1  = (unsigned short*)carve((size_t)8 * TBL * 2);
  unsigned short* Wpkh  = (unsigned short*)carve((size_t)8 * TBL * 2);
  unsigned short* Spk0h = (unsigned short*)carve((size_t)8 * TBL * 2);
  unsigned short* Spk0l = (unsigned short*)carve((size_t)8 * TBL * 2);
  unsigned short* Spk1h = (unsigned short*)carve((size_t)8 * TBL * 2);
  unsigned short* Spk1l = (unsigned short*)carve((size_t)8 * TBL * 2);
  int2*           ebuf  = (int2*)h0;  // alias: h0 dead during CSR build

  const int gE  = (E + 255) / 256;
  const int gB4 = (E + 4095) / 4096;
  const int gG  = (N + 63) / 64;
  const int gW  = (N + 15) / 16;     // 16 nodes per 256-thread block
  const int nb  = (N + 1023) / 1024;

  // --- probe + bucketed CSR build ---
  hipMemsetAsync(flag, 0, 4, stream);
  hipMemsetAsync(cnt, 0, (size_t)N * 4, stream);
  hipMemsetAsync(bhist, 0, NB * 4, stream);
  detect_kernel<<<1, 256, 0, stream>>>(ei, flag);
  hist_kernel<<<gE, 256, 0, stream>>>(ei, flag, cnt, E);
  bucket_hist<<<gB4, 256, 0, stream>>>(ei, flag, bhist, E, W);
  scan_block<<<nb, 256, 0, stream>>>(cnt, rp, bsum, N);
  scan_tops<<<1, 128, 0, stream>>>(bsum, rp, nb, N);
  scan_add<<<nb, 256, 0, stream>>>(rp, bsum, N);
  bucket_scan<<<1, NB, 0, stream>>>(bhist, boffs, bcur);
  bucket_scatter<<<gB4, 256, 0, stream>>>(ei, flag, bcur, ebuf, E, W);
  bucket_fill<<<NB, 256, 0, stream>>>(ebuf, boffs, rp, col, N, W);

  // --- pack weights into MFMA B-fragment order (bf16; x8 replicated; self hi/lo) ---
  pack_mfma_b<<<8, 256, 0, stream>>>(W0, Wpk0);
  pack_mfma_b<<<8, 256, 0, stream>>>(W1, Wpk1);
  pack_mfma_b_hilo<<<8, 256, 0, stream>>>(slW0, Spk0h, Spk0l);
  pack_mfma_b_hilo<<<8, 256, 0, stream>>>(slW1, Spk1h, Spk1l);
  pack_mfma_head<<<8, 256, 0, stream>>>(Wmu, Wlv, Wpkh);

  // --- layer 0: one fused MFMA GEMM (hg + logits + self-linear), then fused agg ---
  gemm_fused<<<gG, 256, 0, stream>>>(x, Wpk0, Spk0h, Spk0l, as0, ad0, slb0,
                                     hgB, h0, als, ald, N);
  gat_agg3<<<gW, 256, 0, stream>>>(hgB, als, ald, rp, col, b0, h0, h0, N, 0, 1);

  // --- layer 1 (self loops); reads h0 in its own row band, writes same band ---
  gemm_fused<<<gG, 256, 0, stream>>>(h0, Wpk1, Spk1h, Spk1l, as1, ad1, slb1,
                                     hgB, h0, als, ald, N);
  gat_agg3<<<gW, 256, 0, stream>>>(hgB, als, ald, rp, col, b1, h0, h0, N, 1, 1);

  // --- heads: one merged MFMA GEMM (+both logit pairs), one dual gather pass ---
  gemm_mfma_head<<<gG, 256, 0, stream>>>(h0, Wpkh, asmu, admu, aslv, adlv,
                                         hgHd, (float*)alsH, (float*)aldH, N);
  gat_agg_dual<<<gW, 256, 0, stream>>>(hgHd, alsH, aldH, rp, col, bmu, blv, outF, N);
}

// Round 11
// 601.188 us; speedup vs baseline: 1.1729x; 1.0736x over previous
//
#include <hip/hip_runtime.h>
#include <cstdint>
#include <cstddef>

// ---------- bf16 helpers (OCP bf16 = upper 16 bits of f32) ----------
__device__ __forceinline__ float bf2f(unsigned short u) {
  return __uint_as_float(((unsigned)u) << 16);
}
__device__ __forceinline__ unsigned short f2bf(float f) {
  unsigned u = __float_as_uint(f);
  u = (u + 0x7FFFu + ((u >> 16) & 1u)) >> 16;  // RNE
  return (unsigned short)u;
}

typedef __attribute__((ext_vector_type(8))) short bf16x8;
typedef __attribute__((ext_vector_type(4))) float f32x4;

#define TBL 16384  // shorts per 32KB table copy

// ---------- edge_index layout probe ----------
__global__ void detect_kernel(const int* __restrict__ ei, int* __restrict__ flag) {
  int any = 0;
  for (int j = threadIdx.x; j < 4096; j += 256) any |= (ei[2 * j + 1] != 0);
  if (any) atomicOr(flag, 1);  // 1 => int32 layout
}

__device__ __forceinline__ int edge_src(const int* ei, int f, int e, int i) {
  return f ? ei[i] : ei[2 * (size_t)i];
}
__device__ __forceinline__ int edge_dst(const int* ei, int f, int e, int i) {
  return f ? ei[(size_t)e + i] : ei[2 * (size_t)e + 2 * (size_t)i];
}

// ---------- per-node degree histogram ----------
__global__ void hist_kernel(const int* __restrict__ ei, const int* __restrict__ flag,
                            int* __restrict__ cnt, int e) {
  int i = blockIdx.x * blockDim.x + threadIdx.x;
  if (i < e) atomicAdd(&cnt[edge_dst(ei, *flag, e, i)], 1);
}

// two-level scan for rp
__global__ void scan_block(const int* __restrict__ cnt, int* __restrict__ rp,
                           int* __restrict__ bsum, int n) {
  __shared__ int lds[256];
  const int t = threadIdx.x;
  const int base = blockIdx.x * 1024 + t * 4;
  int v0 = (base     < n) ? cnt[base]     : 0;
  int v1 = (base + 1 < n) ? cnt[base + 1] : 0;
  int v2 = (base + 2 < n) ? cnt[base + 2] : 0;
  int v3 = (base + 3 < n) ? cnt[base + 3] : 0;
  int s = v0 + v1 + v2 + v3;
  lds[t] = s;
  __syncthreads();
  for (int off = 1; off < 256; off <<= 1) {
    int y = (t >= off) ? lds[t - off] : 0;
    __syncthreads();
    lds[t] += y;
    __syncthreads();
  }
  int excl = lds[t] - s;
  if (base     < n) rp[base]     = excl;
  if (base + 1 < n) rp[base + 1] = excl + v0;
  if (base + 2 < n) rp[base + 2] = excl + v0 + v1;
  if (base + 3 < n) rp[base + 3] = excl + v0 + v1 + v2;
  if (t == 255) bsum[blockIdx.x] = lds[255];
}

__global__ void scan_tops(int* __restrict__ bsum, int* __restrict__ rp, int nb, int n) {
  __shared__ int lds[128];
  const int t = threadIdx.x;
  int v = (t < nb) ? bsum[t] : 0;
  lds[t] = v;
  __syncthreads();
  for (int off = 1; off < 128; off <<= 1) {
    int y = (t >= off) ? lds[t - off] : 0;
    __syncthreads();
    lds[t] += y;
    __syncthreads();
  }
  if (t < nb) bsum[t] = lds[t] - v;
  if (t == 127) rp[n] = lds[127];
}

__global__ void scan_add(int* __restrict__ rp, const int* __restrict__ bsum, int n) {
  const int base = blockIdx.x * 1024 + threadIdx.x * 4;
  const int add = bsum[blockIdx.x];
#pragma unroll
  for (int i = 0; i < 4; ++i)
    if (base + i < n) rp[base + i] += add;
}

// ---------- bucketed CSR fill ----------
#define NB 128

__global__ void bucket_hist(const int* __restrict__ ei, const int* __restrict__ flag,
                            int* __restrict__ bhist, int e, int W) {
  __shared__ int lh[NB];
  const int t = threadIdx.x;
  if (t < NB) lh[t] = 0;
  __syncthreads();
  const int base = blockIdx.x * 4096;
  const int f = *flag;
  for (int j = t; j < 4096; j += 256) {
    int i = base + j;
    if (i < e) atomicAdd(&lh[edge_dst(ei, f, e, i) / W], 1);
  }
  __syncthreads();
  if (t < NB && lh[t]) atomicAdd(&bhist[t], lh[t]);
}

__global__ void bucket_scan(const int* __restrict__ bhist, int* __restrict__ boffs,
                            int* __restrict__ bcur) {
  __shared__ int lds[NB];
  const int t = threadIdx.x;
  int v = bhist[t];
  lds[t] = v;
  __syncthreads();
  for (int off = 1; off < NB; off <<= 1) {
    int y = (t >= off) ? lds[t - off] : 0;
    __syncthreads();
    lds[t] += y;
    __syncthreads();
  }
  int excl = lds[t] - v;
  boffs[t] = excl;
  bcur[t] = excl;
  if (t == NB - 1) boffs[NB] = lds[NB - 1];
}

__global__ void bucket_scatter(const int* __restrict__ ei, const int* __restrict__ flag,
                               int* __restrict__ bcur, int2* __restrict__ ebuf,
                               int e, int W) {
  __shared__ int lh[NB];
  __shared__ int lbase[NB];
  const int t = threadIdx.x;
  if (t < NB) lh[t] = 0;
  __syncthreads();
  const int base = blockIdx.x * 4096;
  const int f = *flag;
  for (int j = t; j < 4096; j += 256) {
    int i = base + j;
    if (i < e) atomicAdd(&lh[edge_dst(ei, f, e, i) / W], 1);
  }
  __syncthreads();
  if (t < NB) {
    lbase[t] = lh[t] ? atomicAdd(&bcur[t], lh[t]) : 0;
    lh[t] = 0;
  }
  __syncthreads();
  for (int j = t; j < 4096; j += 256) {
    int i = base + j;
    if (i < e) {
      int d = edge_dst(ei, f, e, i);
      int s = edge_src(ei, f, e, i);
      int b = d / W;
      int off = atomicAdd(&lh[b], 1);
      ebuf[lbase[b] + off] = make_int2(s, d);
    }
  }
}

__global__ void bucket_fill(const int2* __restrict__ ebuf, const int* __restrict__ boffs,
                            const int* __restrict__ rp, int* __restrict__ col,
                            int n, int W) {
  __shared__ int cur[1024];
  const int b = blockIdx.x;
  const int lo = b * W;
  const int nn = min(W, n - lo);
  if (nn <= 0) return;
  for (int i = threadIdx.x; i < nn; i += 256) cur[i] = rp[lo + i];
  __syncthreads();
  const int beg = boffs[b], end = boffs[b + 1];
  for (int p = beg + threadIdx.x; p < end; p += 256) {
    int2 sd = ebuf[p];
    int pos = atomicAdd(&cur[sd.y - lo], 1);
    col[pos] = sd.x;
  }
}

// ---------- pack W[128][128] f32 into MFMA B-fragment order (bf16), x8 replicated ----------
__global__ void pack_mfma_b(const float* __restrict__ Wf, unsigned short* __restrict__ Wpk) {
  int i = blockIdx.x * 256 + threadIdx.x;  // 2048
  if (i >= 2048) return;
  int lane = i & 63, nt = (i >> 6) & 7, ks = i >> 9;
  int nn = lane & 15, q = lane >> 4;
  int k0 = ks * 32 + q * 8, col = nt * 16 + nn;
  unsigned short o[8];
#pragma unroll
  for (int j = 0; j < 8; ++j) o[j] = f2bf(Wf[(size_t)(k0 + j) * 128 + col]);
  uint4 u;
  u.x = (unsigned)o[0] | ((unsigned)o[1] << 16);
  u.y = (unsigned)o[2] | ((unsigned)o[3] << 16);
  u.z = (unsigned)o[4] | ((unsigned)o[5] << 16);
  u.w = (unsigned)o[6] | ((unsigned)o[7] << 16);
#pragma unroll
  for (int c = 0; c < 8; ++c)
    *(uint4*)(Wpk + (size_t)c * TBL + (size_t)i * 8) = u;
}

// hi/lo split pack for the self-linear weight: Hi = bf16(W), Lo = bf16(W - Hi); x8 replicated
__global__ void pack_mfma_b_hilo(const float* __restrict__ Wf,
                                 unsigned short* __restrict__ Hi,
                                 unsigned short* __restrict__ Lo) {
  int i = blockIdx.x * 256 + threadIdx.x;  // 2048
  if (i >= 2048) return;
  int lane = i & 63, nt = (i >> 6) & 7, ks = i >> 9;
  int nn = lane & 15, q = lane >> 4;
  int k0 = ks * 32 + q * 8, col = nt * 16 + nn;
  unsigned short oh[8], ol[8];
#pragma unroll
  for (int j = 0; j < 8; ++j) {
    float v = Wf[(size_t)(k0 + j) * 128 + col];
    unsigned short h = f2bf(v);
    oh[j] = h;
    ol[j] = f2bf(v - bf2f(h));
  }
  uint4 uh, ul;
  uh.x = (unsigned)oh[0] | ((unsigned)oh[1] << 16);
  uh.y = (unsigned)oh[2] | ((unsigned)oh[3] << 16);
  uh.z = (unsigned)oh[4] | ((unsigned)oh[5] << 16);
  uh.w = (unsigned)oh[6] | ((unsigned)oh[7] << 16);
  ul.x = (unsigned)ol[0] | ((unsigned)ol[1] << 16);
  ul.y = (unsigned)ol[2] | ((unsigned)ol[3] << 16);
  ul.z = (unsigned)ol[4] | ((unsigned)ol[5] << 16);
  ul.w = (unsigned)ol[6] | ((unsigned)ol[7] << 16);
#pragma unroll
  for (int c = 0; c < 8; ++c) {
    *(uint4*)(Hi + (size_t)c * TBL + (size_t)i * 8) = uh;
    *(uint4*)(Lo + (size_t)c * TBL + (size_t)i * 8) = ul;
  }
}

// heads: merged [Wmu | Wlv], each [128][64] f32; x8 replicated
__global__ void pack_mfma_head(const float* __restrict__ Wmu, const float* __restrict__ Wlv,
                               unsigned short* __restrict__ Wpk) {
  int i = blockIdx.x * 256 + threadIdx.x;  // 2048
  if (i >= 2048) return;
  int lane = i & 63, nt = (i >> 6) & 7, ks = i >> 9;
  int nn = lane & 15, q = lane >> 4;
  int k0 = ks * 32 + q * 8, col = nt * 16 + nn;
  unsigned short o[8];
#pragma unroll
  for (int j = 0; j < 8; ++j) {
    float v = (col < 64) ? Wmu[(size_t)(k0 + j) * 64 + col]
                         : Wlv[(size_t)(k0 + j) * 64 + (col - 64)];
    o[j] = f2bf(v);
  }
  uint4 u;
  u.x = (unsigned)o[0] | ((unsigned)o[1] << 16);
  u.y = (unsigned)o[2] | ((unsigned)o[3] << 16);
  u.z = (unsigned)o[4] | ((unsigned)o[5] << 16);
  u.w = (unsigned)o[6] | ((unsigned)o[7] << 16);
#pragma unroll
  for (int c = 0; c < 8; ++c)
    *(uint4*)(Wpk + (size_t)c * TBL + (size_t)i * 8) = u;
}

// ---------- fused layer GEMM (matrix pipe; per-XCD table copy; LDS-transposed epilogue) ----------
// R10 post-mortem: 6 load-side variants all ~70-96us. The constant was the epilogue:
// 64 scalar stores/thread (32x store_short + 32x store_dword, 32-64B scatter).
// Fix: per-wave LDS transpose -> 12 fully-coalesced dwordx4 stores/thread.
// Wave-private LDS regions: no __syncthreads (same-wave DS ordering).
__launch_bounds__(256)
__global__ void gemm_fused(const float* __restrict__ X, const unsigned short* __restrict__ Wpk,
                           const unsigned short* __restrict__ Sph, const unsigned short* __restrict__ Spl,
                           const float* __restrict__ a0s, const float* __restrict__ a0d,
                           const float* __restrict__ slb,
                           unsigned short* __restrict__ hg, float* __restrict__ hself,
                           float* __restrict__ als, float* __restrict__ ald, int n) {
  __shared__ float          selfLds[4][16][132];  // 132: 16B-aligned rows, mild bank spread
  __shared__ unsigned short hgLds[4][16][136];    // 136 shorts = 272B rows, 16B-aligned

  const int wave = threadIdx.x >> 6;
  const int lane = threadIdx.x & 63;
  const int nidx = lane & 15, q = lane >> 4;
  const int r0 = blockIdx.x * 64 + wave * 16;
  const int arow = r0 + nidx;
  const size_t rep = (size_t)(blockIdx.x & 7) * TBL;

  // preload this lane's full 128B X segment (8 x float4), hoistable
  float4 xr[8];
  if (arow < n) {
    const float* xp = X + (size_t)arow * 128 + q * 8;
#pragma unroll
    for (int ks = 0; ks < 4; ++ks) {
      xr[2 * ks]     = *(const float4*)(xp + ks * 32);
      xr[2 * ks + 1] = *(const float4*)(xp + ks * 32 + 4);
    }
  } else {
#pragma unroll
    for (int j = 0; j < 8; ++j) xr[j] = make_float4(0.f, 0.f, 0.f, 0.f);
  }

  union U { unsigned short u[8]; bf16x8 v; };
  U afh[4], afl[4];
#pragma unroll
  for (int ks = 0; ks < 4; ++ks) {
    float xv[8] = {xr[2 * ks].x, xr[2 * ks].y, xr[2 * ks].z, xr[2 * ks].w,
                   xr[2 * ks + 1].x, xr[2 * ks + 1].y, xr[2 * ks + 1].z, xr[2 * ks + 1].w};
#pragma unroll
    for (int j = 0; j < 8; ++j) {
      unsigned short h = f2bf(xv[j]);
      afh[ks].u[j] = h;
      afl[ks].u[j] = f2bf(xv[j] - bf2f(h));
    }
  }

  f32x4 acc[8], accS[8];
#pragma unroll
  for (int nt = 0; nt < 8; ++nt) {
    acc[nt]  = (f32x4){0.f, 0.f, 0.f, 0.f};
    accS[nt] = (f32x4){0.f, 0.f, 0.f, 0.f};
  }

#pragma unroll
  for (int ks = 0; ks < 4; ++ks) {
    const size_t base = rep + ((size_t)ks * 8 * 64 + lane) * 8;
    const unsigned short* bp = Wpk + base;
    const unsigned short* ph = Sph + base;
    const unsigned short* pl = Spl + base;

    bf16x8 bW[8], bH[8], bL[8];
#pragma unroll
    for (int nt = 0; nt < 8; ++nt) {
      bW[nt] = *(const bf16x8*)(bp + (size_t)nt * 512);
      bH[nt] = *(const bf16x8*)(ph + (size_t)nt * 512);
      bL[nt] = *(const bf16x8*)(pl + (size_t)nt * 512);
    }
#pragma unroll
    for (int nt = 0; nt < 8; ++nt)
      acc[nt] = __builtin_amdgcn_mfma_f32_16x16x32_bf16(afh[ks].v, bW[nt], acc[nt], 0, 0, 0);
#pragma unroll
    for (int nt = 0; nt < 8; ++nt) {
      accS[nt] = __builtin_amdgcn_mfma_f32_16x16x32_bf16(afh[ks].v, bH[nt], accS[nt], 0, 0, 0);
      accS[nt] = __builtin_amdgcn_mfma_f32_16x16x32_bf16(afl[ks].v, bH[nt], accS[nt], 0, 0, 0);
      accS[nt] = __builtin_amdgcn_mfma_f32_16x16x32_bf16(afh[ks].v, bL[nt], accS[nt], 0, 0, 0);
    }
  }

  // stage outputs into LDS (original MFMA lane layout), keep dv for logits
  float dv[8][4];
#pragma unroll
  for (int nt = 0; nt < 8; ++nt) {
    const float sb = slb[nt * 16 + nidx];
#pragma unroll
    for (int r = 0; r < 4; ++r) {
      unsigned short rb = f2bf(acc[nt][r]);
      dv[nt][r] = bf2f(rb);
      hgLds[wave][q * 4 + r][nt * 16 + nidx]   = rb;
      selfLds[wave][q * 4 + r][nt * 16 + nidx] = accS[nt][r] + sb;
    }
  }

  // logits (original lane layout, unchanged math)
  float ps[4] = {0, 0, 0, 0}, pd[4] = {0, 0, 0, 0};
#pragma unroll
  for (int nt = 0; nt < 8; ++nt) {
    float as_ = a0s[nt * 16 + nidx];
    float ad_ = a0d[nt * 16 + nidx];
#pragma unroll
    for (int r = 0; r < 4; ++r) {
      ps[r] = fmaf(dv[nt][r], as_, ps[r]);
      pd[r] = fmaf(dv[nt][r], ad_, pd[r]);
    }
  }
#pragma unroll
  for (int r = 0; r < 4; ++r) {
#pragma unroll
    for (int o = 8; o > 0; o >>= 1) {
      ps[r] += __shfl_xor(ps[r], o, 64);
      pd[r] += __shfl_xor(pd[r], o, 64);
    }
    int row = r0 + q * 4 + r;
    if (nidx == 0 && row < n) { als[row] = ps[r]; ald[row] = pd[r]; }
  }

  // coalesced stores: hg (4 iters, each 16-lane group writes one full 256B row)
#pragma unroll
  for (int j = 0; j < 4; ++j) {
    const int id = j * 64 + lane;
    const int row = id >> 4, ch = id & 15;
    const int gr = r0 + row;
    uint4 v = *(const uint4*)&hgLds[wave][row][ch * 8];
    if (gr < n) *(uint4*)(hg + (size_t)gr * 128 + ch * 8) = v;
  }
  // hself (8 iters, each 32-lane group writes one full 512B row)
#pragma unroll
  for (int j = 0; j < 8; ++j) {
    const int id = j * 64 + lane;
    const int row = id >> 5, ch = id & 31;
    const int gr = r0 + row;
    float4 v = *(const float4*)&selfLds[wave][row][ch * 4];
    if (gr < n) *(float4*)(hself + (size_t)gr * 128 + ch * 4) = v;
  }
}

// ---------- head MFMA GEMM: per-XCD table copy; LDS-transposed hg stores ----------
__launch_bounds__(256)
__global__ void gemm_mfma_head(const float* __restrict__ X, const unsigned short* __restrict__ Wpk,
                               const float* __restrict__ a0s, const float* __restrict__ a0d,
                               const float* __restrict__ a1s, const float* __restrict__ a1d,
                               unsigned short* __restrict__ hg,
                               float* __restrict__ als, float* __restrict__ ald, int n) {
  __shared__ unsigned short hgLds[4][16][136];

  const int wave = threadIdx.x >> 6;
  const int lane = threadIdx.x & 63;
  const int nidx = lane & 15, q = lane >> 4;
  const int r0 = blockIdx.x * 64 + wave * 16;
  const int arow = r0 + nidx;
  const size_t rep = (size_t)(blockIdx.x & 7) * TBL;

  float4 xr[8];
  if (arow < n) {
    const float* xp = X + (size_t)arow * 128 + q * 8;
#pragma unroll
    for (int ks = 0; ks < 4; ++ks) {
      xr[2 * ks]     = *(const float4*)(xp + ks * 32);
      xr[2 * ks + 1] = *(const float4*)(xp + ks * 32 + 4);
    }
  } else {
#pragma unroll
    for (int j = 0; j < 8; ++j) xr[j] = make_float4(0.f, 0.f, 0.f, 0.f);
  }

  union U { unsigned short u[8]; bf16x8 v; };
  U af[4];
#pragma unroll
  for (int ks = 0; ks < 4; ++ks) {
    float xv[8] = {xr[2 * ks].x, xr[2 * ks].y, xr[2 * ks].z, xr[2 * ks].w,
                   xr[2 * ks + 1].x, xr[2 * ks + 1].y, xr[2 * ks + 1].z, xr[2 * ks + 1].w};
#pragma unroll
    for (int j = 0; j < 8; ++j) af[ks].u[j] = f2bf(xv[j]);
  }

  f32x4 acc[8];
#pragma unroll
  for (int nt = 0; nt < 8; ++nt) acc[nt] = (f32x4){0.f, 0.f, 0.f, 0.f};

#pragma unroll
  for (int ks = 0; ks < 4; ++ks) {
    const unsigned short* bp = Wpk + rep + ((size_t)ks * 8 * 64 + lane) * 8;
    bf16x8 bW[8];
#pragma unroll
    for (int nt = 0; nt < 8; ++nt) bW[nt] = *(const bf16x8*)(bp + (size_t)nt * 512);
#pragma unroll
    for (int nt = 0; nt < 8; ++nt)
      acc[nt] = __builtin_amdgcn_mfma_f32_16x16x32_bf16(af[ks].v, bW[nt], acc[nt], 0, 0, 0);
  }

  float dv[8][4];
#pragma unroll
  for (int nt = 0; nt < 8; ++nt) {
#pragma unroll
    for (int r = 0; r < 4; ++r) {
      unsigned short rb = f2bf(acc[nt][r]);
      dv[nt][r] = bf2f(rb);
      hgLds[wave][q * 4 + r][nt * 16 + nidx] = rb;
    }
  }

  float pms[4] = {0, 0, 0, 0}, pmd[4] = {0, 0, 0, 0};
  float pls[4] = {0, 0, 0, 0}, pld[4] = {0, 0, 0, 0};
#pragma unroll
  for (int nt = 0; nt < 4; ++nt) {
    float as_ = a0s[nt * 16 + nidx];
    float ad_ = a0d[nt * 16 + nidx];
#pragma unroll
    for (int r = 0; r < 4; ++r) {
      pms[r] = fmaf(dv[nt][r], as_, pms[r]);
      pmd[r] = fmaf(dv[nt][r], ad_, pmd[r]);
    }
  }
#pragma unroll
  for (int nt = 4; nt < 8; ++nt) {
    float as_ = a1s[(nt - 4) * 16 + nidx];
    float ad_ = a1d[(nt - 4) * 16 + nidx];
#pragma unroll
    for (int r = 0; r < 4; ++r) {
      pls[r] = fmaf(dv[nt][r], as_, pls[r]);
      pld[r] = fmaf(dv[nt][r], ad_, pld[r]);
    }
  }
#pragma unroll
  for (int r = 0; r < 4; ++r) {
#pragma unroll
    for (int o = 8; o > 0; o >>= 1) {
      pms[r] += __shfl_xor(pms[r], o, 64);
      pmd[r] += __shfl_xor(pmd[r], o, 64);
      pls[r] += __shfl_xor(pls[r], o, 64);
      pld[r] += __shfl_xor(pld[r], o, 64);
    }
    int row = r0 + q * 4 + r;
    if (nidx == 0 && row < n) {
      ((float2*)als)[row] = make_float2(pms[r], pls[r]);
      ((float2*)ald)[row] = make_float2(pmd[r], pld[r]);
    }
  }

  // coalesced hg stores (each 16-lane group writes one full 256B row)
#pragma unroll
  for (int j = 0; j < 4; ++j) {
    const int id = j * 64 + lane;
    const int row = id >> 4, ch = id & 15;
    const int gr = r0 + row;
    uint4 v = *(const uint4*)&hgLds[wave][row][ch * 8];
    if (gr < n) *(uint4*)(hg + (size_t)gr * 128 + ch * 8) = v;
  }
}

// ---------- layer aggregation (Round-1 structure: 73.5us, occ 70%) ----------
__launch_bounds__(256)
__global__ void gat_agg3(const unsigned short* __restrict__ hg,
                         const float* __restrict__ als, const float* __restrict__ aldv,
                         const int* __restrict__ rp, const int* __restrict__ col,
                         const float* __restrict__ biasf, float* __restrict__ outv,
                         const float* base, int n, int self_loop, int act) {
  const int node = blockIdx.x * 16 + (threadIdx.x >> 4);
  if (node >= n) return;
  const int g = threadIdx.x & 15;
  const int beg = rp[node];
  const int deg = rp[node + 1] - beg;
  const int total = deg + self_loop;
  const float ad = aldv[node];

  float den = 0.f;
  float acc[8];
#pragma unroll
  for (int k = 0; k < 8; ++k) acc[k] = 0.f;

  const unsigned short* hgl = hg + g * 8;

  for (int cb = 0; cb < total; cb += 16) {
    const int idx = cb + g;
    const bool valid = idx < total;
    int s = node;
    if (valid && idx < deg) s = col[beg + idx];
    float e = 0.f;
    if (valid) {
      float v = als[s] + ad;
      float l = (v > 0.f) ? v : 0.2f * v;  // LeakyReLU(0.2)
      e = __expf(l);
    }

    const int cnt = (total - cb < 16) ? (total - cb) : 16;
    int j = 0;
    for (; j + 4 <= cnt; j += 4) {
      float w[4]; int ss[4]; uint4 rr[4];
#pragma unroll
      for (int u = 0; u < 4; ++u) { w[u] = __shfl(e, j + u, 16); ss[u] = __shfl(s, j + u, 16); }
#pragma unroll
      for (int u = 0; u < 4; ++u) rr[u] = *(const uint4*)(hgl + (size_t)ss[u] * 128);
#pragma unroll
      for (int u = 0; u < 4; ++u) {
        den += w[u];
        acc[0] = fmaf(w[u], __uint_as_float(rr[u].x << 16),        acc[0]);
        acc[1] = fmaf(w[u], __uint_as_float(rr[u].x & 0xFFFF0000u), acc[1]);
        acc[2] = fmaf(w[u], __uint_as_float(rr[u].y << 16),        acc[2]);
        acc[3] = fmaf(w[u], __uint_as_float(rr[u].y & 0xFFFF0000u), acc[3]);
        acc[4] = fmaf(w[u], __uint_as_float(rr[u].z << 16),        acc[4]);
        acc[5] = fmaf(w[u], __uint_as_float(rr[u].z & 0xFFFF0000u), acc[5]);
        acc[6] = fmaf(w[u], __uint_as_float(rr[u].w << 16),        acc[6]);
        acc[7] = fmaf(w[u], __uint_as_float(rr[u].w & 0xFFFF0000u), acc[7]);
      }
    }
    for (; j < cnt; ++j) {
      float wj = __shfl(e, j, 16);
      int sj = __shfl(s, j, 16);
      uint4 raw = *(const uint4*)(hgl + (size_t)sj * 128);
      den += wj;
      acc[0] = fmaf(wj, __uint_as_float(raw.x << 16),        acc[0]);
      acc[1] = fmaf(wj, __uint_as_float(raw.x & 0xFFFF0000u), acc[1]);
      acc[2] = fmaf(wj, __uint_as_float(raw.y << 16),        acc[2]);
      acc[3] = fmaf(wj, __uint_as_float(raw.y & 0xFFFF0000u), acc[3]);
      acc[4] = fmaf(wj, __uint_as_float(raw.z << 16),        acc[4]);
      acc[5] = fmaf(wj, __uint_as_float(raw.z & 0xFFFF0000u), acc[5]);
      acc[6] = fmaf(wj, __uint_as_float(raw.w << 16),        acc[6]);
      acc[7] = fmaf(wj, __uint_as_float(raw.w & 0xFFFF0000u), acc[7]);
    }
  }

  const float inv = 1.f / (den + 1e-16f);
  const size_t o = (size_t)node * 128 + g * 8;
  float4 bv0 = *(const float4*)(biasf + g * 8);
  float4 bv1 = *(const float4*)(biasf + g * 8 + 4);
  float r[8];
  r[0] = acc[0] * inv + bv0.x; r[1] = acc[1] * inv + bv0.y;
  r[2] = acc[2] * inv + bv0.z; r[3] = acc[3] * inv + bv0.w;
  r[4] = acc[4] * inv + bv1.x; r[5] = acc[5] * inv + bv1.y;
  r[6] = acc[6] * inv + bv1.z; r[7] = acc[7] * inv + bv1.w;
  if (base) {
    float4 s0 = *(const float4*)(base + o);
    float4 s1 = *(const float4*)(base + o + 4);
    r[0] += s0.x; r[1] += s0.y; r[2] += s0.z; r[3] += s0.w;
    r[4] += s1.x; r[5] += s1.y; r[6] += s1.z; r[7] += s1.w;
  }
  if (act) {
#pragma unroll
    for (int k = 0; k < 8; ++k) r[k] = (r[k] > 0.f) ? r[k] : 0.01f * r[k];
  }
  *(float4*)(outv + o)     = make_float4(r[0], r[1], r[2], r[3]);
  *(float4*)(outv + o + 4) = make_float4(r[4], r[5], r[6], r[7]);
}

// ---------- dual-head aggregation (Round-1 structure): mu + logvar in ONE pass ----------
__launch_bounds__(256)
__global__ void gat_agg_dual(const unsigned short* __restrict__ hg,
                             const float2* __restrict__ alsH, const float2* __restrict__ aldH,
                             const int* __restrict__ rp, const int* __restrict__ col,
                             const float* __restrict__ bmu, const float* __restrict__ blv,
                             float* __restrict__ outF, int n) {
  const int node = blockIdx.x * 16 + (threadIdx.x >> 4);
  if (node >= n) return;
  const int g = threadIdx.x & 15;
  const bool isMu = g < 8;
  const int beg = rp[node];
  const int deg = rp[node + 1] - beg;
  const int total = deg + 1;  // heads always have self loop
  const float2 ad = aldH[node];

  float den = 0.f;
  float acc[8];
#pragma unroll
  for (int k = 0; k < 8; ++k) acc[k] = 0.f;

  const unsigned short* hgl = hg + g * 8;

  for (int cb = 0; cb < total; cb += 16) {
    const int idx = cb + g;
    const bool valid = idx < total;
    int s = node;
    if (valid && idx < deg) s = col[beg + idx];
    float eM = 0.f, eL = 0.f;
    if (valid) {
      float2 as_ = alsH[s];
      float vm = as_.x + ad.x;
      float vl = as_.y + ad.y;
      eM = __expf((vm > 0.f) ? vm : 0.2f * vm);
      eL = __expf((vl > 0.f) ? vl : 0.2f * vl);
    }

    const int cnt = (total - cb < 16) ? (total - cb) : 16;
    int j = 0;
    for (; j + 4 <= cnt; j += 4) {
      float w[4]; int ss[4]; uint4 rr[4];
#pragma unroll
      for (int u = 0; u < 4; ++u) {
        float wm = __shfl(eM, j + u, 16), wl = __shfl(eL, j + u, 16);
        w[u] = isMu ? wm : wl;
        ss[u] = __shfl(s, j + u, 16);
      }
#pragma unroll
      for (int u = 0; u < 4; ++u) rr[u] = *(const uint4*)(hgl + (size_t)ss[u] * 128);
#pragma unroll
      for (int u = 0; u < 4; ++u) {
        den += w[u];
        acc[0] = fmaf(w[u], __uint_as_float(rr[u].x << 16),        acc[0]);
        acc[1] = fmaf(w[u], __uint_as_float(rr[u].x & 0xFFFF0000u), acc[1]);
        acc[2] = fmaf(w[u], __uint_as_float(rr[u].y << 16),        acc[2]);
        acc[3] = fmaf(w[u], __uint_as_float(rr[u].y & 0xFFFF0000u), acc[3]);
        acc[4] = fmaf(w[u], __uint_as_float(rr[u].z << 16),        acc[4]);
        acc[5] = fmaf(w[u], __uint_as_float(rr[u].z & 0xFFFF0000u), acc[5]);
        acc[6] = fmaf(w[u], __uint_as_float(rr[u].w << 16),        acc[6]);
        acc[7] = fmaf(w[u], __uint_as_float(rr[u].w & 0xFFFF0000u), acc[7]);
      }
    }
    for (; j < cnt; ++j) {
      float wm = __shfl(eM, j, 16), wl = __shfl(eL, j, 16);
      float wj = isMu ? wm : wl;
      int sj = __shfl(s, j, 16);
      uint4 raw = *(const uint4*)(hgl + (size_t)sj * 128);
      den += wj;
      acc[0] = fmaf(wj, __uint_as_float(raw.x << 16),        acc[0]);
      acc[1] = fmaf(wj, __uint_as_float(raw.x & 0xFFFF0000u), acc[1]);
      acc[2] = fmaf(wj, __uint_as_float(raw.y << 16),        acc[2]);
      acc[3] = fmaf(wj, __uint_as_float(raw.y & 0xFFFF0000u), acc[3]);
      acc[4] = fmaf(wj, __uint_as_float(raw.z << 16),        acc[4]);
      acc[5] = fmaf(wj, __uint_as_float(raw.z & 0xFFFF0000u), acc[5]);
      acc[6] = fmaf(wj, __uint_as_float(raw.w << 16),        acc[6]);
      acc[7] = fmaf(wj, __uint_as_float(raw.w & 0xFFFF0000u), acc[7]);
    }
  }

  const float inv = 1.f / (den + 1e-16f);
  const int c = (g & 7) * 8;
  const float* bb = isMu ? bmu : blv;
  float4 bv0 = *(const float4*)(bb + c);
  float4 bv1 = *(const float4*)(bb + c + 4);
  float* op = outF + (isMu ? (size_t)0 : (size_t)n * 64) + (size_t)node * 64 + c;
  *(float4*)op = make_float4(acc[0] * inv + bv0.x, acc[1] * inv + bv0.y,
                             acc[2] * inv + bv0.z, acc[3] * inv + bv0.w);
  *(float4*)(op + 4) = make_float4(acc[4] * inv + bv1.x, acc[5] * inv + bv1.y,
                                   acc[6] * inv + bv1.z, acc[7] * inv + bv1.w);
}

extern "C" void kernel_launch(void* const* d_in, const int* in_sizes, int n_in,
                              void* d_out, int out_size, void* d_ws, size_t ws_size,
                              hipStream_t stream) {
  const int N = in_sizes[0] / 128;   // 100000
  const int E = in_sizes[1] / 2;     // 1600000
  const int W = (N + NB - 1) / NB;   // nodes per bucket (<=1024)

  const float* x    = (const float*)d_in[0];
  const int*   ei   = (const int*)d_in[1];
  const float* W0   = (const float*)d_in[2];
  const float* as0  = (const float*)d_in[3];
  const float* ad0  = (const float*)d_in[4];
  const float* b0   = (const float*)d_in[5];
  const float* slW0 = (const float*)d_in[6];
  const float* slb0 = (const float*)d_in[7];
  const float* W1   = (const float*)d_in[8];
  const float* as1  = (const float*)d_in[9];
  const float* ad1  = (const float*)d_in[10];
  const float* b1   = (const float*)d_in[11];
  const float* slW1 = (const float*)d_in[12];
  const float* slb1 = (const float*)d_in[13];
  const float* Wmu  = (const float*)d_in[14];
  const float* asmu = (const float*)d_in[15];
  const float* admu = (const float*)d_in[16];
  const float* bmu  = (const float*)d_in[17];
  const float* Wlv  = (const float*)d_in[18];
  const float* aslv = (const float*)d_in[19];
  const float* adlv = (const float*)d_in[20];
  const float* blv  = (const float*)d_in[21];

  float*          outF = (float*)d_out;
  unsigned short* hgB  = (unsigned short*)d_out;  // layers' hg lives in d_out (dead before heads write)

  char* w = (char*)d_ws;
  auto carve = [&](size_t bytes) -> char* {
    char* p = w;
    w += (bytes + 255) & ~(size_t)255;
    return p;
  };
  float*          h0    = (float*)carve((size_t)N * 128 * 4);           // 51.2 MB
  unsigned short* hgHd  = (unsigned short*)carve((size_t)N * 128 * 2);  // 25.6 MB
  float*          als   = (float*)carve((size_t)N * 4);
  float*          ald   = (float*)carve((size_t)N * 4);
  float2*         alsH  = (float2*)carve((size_t)N * 8);
  float2*         aldH  = (float2*)carve((size_t)N * 8);
  int*            cnt   = (int*)carve((size_t)N * 4);
  int*            rp    = (int*)carve((size_t)(N + 1) * 4);
  int*            col   = (int*)carve((size_t)E * 4);
  int*            bsum  = (int*)carve(512);
  int*            bhist = (int*)carve(NB * 4);
  int*            boffs = (int*)carve((NB + 1) * 4);
  int*            bcur  = (int*)carve(NB * 4);
  int*            flag  = (int*)carve(4);
  unsigned short* Wpk0  = (unsigned short*)carve((size_t)8 * TBL * 2);  // x8 copies
  unsigned short* Wpk1  = (unsigned short*)carve((size_t)8 * TBL * 2);
  unsigned short* Wpkh  = (unsigned short*)carve((size_t)8 * TBL * 2);
  unsigned short* Spk0h = (unsigned short*)carve((size_t)8 * TBL * 2);
  unsigned short* Spk0l = (unsigned short*)carve((size_t)8 * TBL * 2);
  unsigned short* Spk1h = (unsigned short*)carve((size_t)8 * TBL * 2);
  unsigned short* Spk1l = (unsigned short*)carve((size_t)8 * TBL * 2);
  int2*           ebuf  = (int2*)h0;  // alias: h0 dead during CSR build

  const int gE  = (E + 255) / 256;
  const int gB4 = (E + 4095) / 4096;
  const int gG  = (N + 63) / 64;
  const int gW  = (N + 15) / 16;     // 16 nodes per 256-thread block
  const int nb  = (N + 1023) / 1024;

  // --- probe + bucketed CSR build ---
  hipMemsetAsync(flag, 0, 4, stream);
  hipMemsetAsync(cnt, 0, (size_t)N * 4, stream);
  hipMemsetAsync(bhist, 0, NB * 4, stream);
  detect_kernel<<<1, 256, 0, stream>>>(ei, flag);
  hist_kernel<<<gE, 256, 0, stream>>>(ei, flag, cnt, E);
  bucket_hist<<<gB4, 256, 0, stream>>>(ei, flag, bhist, E, W);
  scan_block<<<nb, 256, 0, stream>>>(cnt, rp, bsum, N);
  scan_tops<<<1, 128, 0, stream>>>(bsum, rp, nb, N);
  scan_add<<<nb, 256, 0, stream>>>(rp, bsum, N);
  bucket_scan<<<1, NB, 0, stream>>>(bhist, boffs, bcur);
  bucket_scatter<<<gB4, 256, 0, stream>>>(ei, flag, bcur, ebuf, E, W);
  bucket_fill<<<NB, 256, 0, stream>>>(ebuf, boffs, rp, col, N, W);

  // --- pack weights into MFMA B-fragment order (bf16; x8 replicated; self hi/lo) ---
  pack_mfma_b<<<8, 256, 0, stream>>>(W0, Wpk0);
  pack_mfma_b<<<8, 256, 0, stream>>>(W1, Wpk1);
  pack_mfma_b_hilo<<<8, 256, 0, stream>>>(slW0, Spk0h, Spk0l);
  pack_mfma_b_hilo<<<8, 256, 0, stream>>>(slW1, Spk1h, Spk1l);
  pack_mfma_head<<<8, 256, 0, stream>>>(Wmu, Wlv, Wpkh);

  // --- layer 0: one fused MFMA GEMM (hg + logits + self-linear), then fused agg ---
  gemm_fused<<<gG, 256, 0, stream>>>(x, Wpk0, Spk0h, Spk0l, as0, ad0, slb0,
                                     hgB, h0, als, ald, N);
  gat_agg3<<<gW, 256, 0, stream>>>(hgB, als, ald, rp, col, b0, h0, h0, N, 0, 1);

  // --- layer 1 (self loops); reads h0 in its own row band, writes same band ---
  gemm_fused<<<gG, 256, 0, stream>>>(h0, Wpk1, Spk1h, Spk1l, as1, ad1, slb1,
                                     hgB, h0, als, ald, N);
  gat_agg3<<<gW, 256, 0, stream>>>(hgB, als, ald, rp, col, b1, h0, h0, N, 1, 1);

  // --- heads: one merged MFMA GEMM (+both logit pairs), one dual gather pass ---
  gemm_mfma_head<<<gG, 256, 0, stream>>>(h0, Wpkh, asmu, admu, aslv, adlv,
                                         hgHd, (float*)alsH, (float*)aldH, N);
  gat_agg_dual<<<gW, 256, 0, stream>>>(hgHd, alsH, aldH, rp, col, bmu, blv, outF, N);
}